// Round 10
// baseline (908.832 us; speedup 1.0000x reference)
//
#include <hip/hip_runtime.h>
#include <hip/hip_bf16.h>

#define N_NODES 50000
#define M_EDGES 800000
#define LEAKY_F 0.2f
#define BN_EPS 1e-5f
#define NEBLK (M_EDGES / 64)

__device__ __forceinline__ float leaky(float x) { return x >= 0.f ? x : LEAKY_F * x; }

// round-to-nearest-even f32 -> bf16 (finite inputs)
__device__ __forceinline__ unsigned f2bf(float f) {
  unsigned u = __float_as_uint(f);
  return (u + 0x7fffu + ((u >> 16) & 1u)) >> 16;
}
__device__ __forceinline__ unsigned packbf(float a, float b) {
  return (f2bf(b) << 16) | f2bf(a);
}
__device__ __forceinline__ float bflo(unsigned u) { return __uint_as_float(u << 16); }
__device__ __forceinline__ float bfhi(unsigned u) { return __uint_as_float(u & 0xffff0000u); }

// ================= CSR build =================
__global__ __launch_bounds__(256) void hist_k(const int* __restrict__ dst,
                                              int* __restrict__ counts) {
  int e = blockIdx.x * 256 + threadIdx.x;
  if (e < M_EDGES) atomicAdd(&counts[dst[e]], 1);
}

__global__ __launch_bounds__(256) void scan_k(const int* __restrict__ counts,
                                              int* __restrict__ offs,
                                              int* __restrict__ cursor) {
  __shared__ int chunk[256];
  const int CH = (N_NODES + 255) / 256;
  int tid = threadIdx.x;
  int beg = tid * CH, end = min(beg + CH, N_NODES);
  int s = 0;
  for (int i = beg; i < end; ++i) s += counts[i];
  chunk[tid] = s;
  __syncthreads();
  if (tid == 0) {
    int run = 0;
    for (int i = 0; i < 256; ++i) { int c = chunk[i]; chunk[i] = run; run += c; }
  }
  __syncthreads();
  int base = chunk[tid];
  for (int i = beg; i < end; ++i) {
    offs[i] = base;
    cursor[i] = base;
    base += counts[i];
  }
  if (tid == 0) offs[N_NODES] = M_EDGES;
}

__global__ __launch_bounds__(256) void fill_k(const int* __restrict__ src,
                                              const int* __restrict__ dst,
                                              int* __restrict__ cursor,
                                              int* __restrict__ ssrc) {
  int e = blockIdx.x * 256 + threadIdx.x;
  if (e >= M_EDGES) return;
  int p = atomicAdd(&cursor[dst[e]], 1);
  ssrc[p] = src[e];
}

// ---- f32 rows -> packed bf16 rows (uint4 per thread = 8 floats) ----
__global__ __launch_bounds__(256) void convbf_k(const float* __restrict__ X,
                                                unsigned* __restrict__ Xb, int n4) {
  int i = blockIdx.x * 256 + threadIdx.x;
  if (i >= n4) return;
  const float4* s4 = reinterpret_cast<const float4*>(X) + (size_t)i * 2;
  float4 a = s4[0], b = s4[1];
  uint4 o;
  o.x = packbf(a.x, a.y);
  o.y = packbf(a.z, a.w);
  o.z = packbf(b.x, b.y);
  o.w = packbf(b.z, b.w);
  reinterpret_cast<uint4*>(Xb)[i] = o;
}

// ---- segment gather-sum over packed-bf16 rows; wave per node, half-wave per edge ----
__global__ __launch_bounds__(256) void gatherb_k(const unsigned* __restrict__ Xb,
                                                 const int* __restrict__ offs,
                                                 const int* __restrict__ ssrc,
                                                 unsigned* __restrict__ Ob) {
  int n = blockIdx.x * 4 + (threadIdx.x >> 6);
  int lane = threadIdx.x & 63;
  int half = lane >> 5, col = lane & 31;
  int beg = offs[n], end = offs[n + 1];
  float a0 = 0.f, a1 = 0.f;
  for (int i = beg + half; i < end; i += 2) {
    unsigned u = Xb[(size_t)ssrc[i] * 32 + col];
    a0 += bflo(u);
    a1 += bfhi(u);
  }
  a0 += __shfl_xor(a0, 32);
  a1 += __shfl_xor(a1, 32);
  if (half == 0) Ob[(size_t)n * 32 + col] = packbf(a0, a1);
}

// ================= weight-prep (algebraic collapse) =================
__global__ __launch_bounds__(256) void prep1_k(const float* __restrict__ W_ops,
                                               const float* __restrict__ W_cat,
                                               float* __restrict__ W12g,
                                               float* __restrict__ Wc12g) {
  __shared__ float Wa[4096], Wb[4096];
  int tid = threadIdx.x;
  const float *Am, *Bm, *Add;
  float* Out;
  if (blockIdx.x == 0) { Am = W_ops; Bm = W_ops + 8192; Add = W_ops + 4096; Out = W12g; }
  else { Am = W_ops + 16384; Bm = W_cat + 8192; Add = W_cat + 4096; Out = Wc12g; }
  for (int i = tid; i < 4096; i += 256) { Wa[i] = Am[i]; Wb[i] = Bm[i]; }
  __syncthreads();
  for (int t = 0; t < 16; ++t) {
    int o = tid + t * 256;
    int r = o >> 6, j = o & 63;
    float acc = Add[o];
#pragma unroll
    for (int k = 0; k < 64; ++k) acc = fmaf(Wa[r * 64 + k], Wb[k * 64 + j], acc);
    Out[o] = acc;
  }
}

__global__ __launch_bounds__(256) void prep2_k(const float* __restrict__ W_ops,
                                               const float* __restrict__ b_ops,
                                               const float* __restrict__ W_cat,
                                               const float* __restrict__ b_cat,
                                               const float* __restrict__ W12g,
                                               const float* __restrict__ Wc12g,
                                               float* __restrict__ WAg,
                                               float* __restrict__ WBg,
                                               float* __restrict__ cg) {
  __shared__ float M0[4096], M1[4096], M2[4096], M3[4096], M4[4096];
  __shared__ float bb[64];
  int tid = threadIdx.x;
  if (blockIdx.x == 0) {
    for (int i = tid; i < 4096; i += 256) {
      M0[i] = W_ops[i];
      M1[i] = W_cat[i];
      M2[i] = W12g[i];
      M3[i] = Wc12g[i];
    }
    __syncthreads();
    for (int t = 0; t < 16; ++t) {
      int o = tid + t * 256;
      int r = o >> 6, j = o & 63;
      float acc = 0.f;
#pragma unroll
      for (int k = 0; k < 64; ++k) {
        acc = fmaf(M0[r * 64 + k], M1[k * 64 + j], acc);
        acc = fmaf(M2[r * 64 + k], M3[k * 64 + j], acc);
      }
      WAg[o] = acc;
    }
  } else {
    for (int i = tid; i < 4096; i += 256) {
      M0[i] = W_ops[3 * 4096 + i];
      M1[i] = W_cat[8192 + i];
      M2[i] = W_ops[2 * 4096 + i];
      M3[i] = W_cat[i];
      M4[i] = Wc12g[i];
    }
    __syncthreads();
    for (int t = 0; t < 16; ++t) {
      int o = tid + t * 256;
      int r = o >> 6, j = o & 63;
      float acc = 0.f;
#pragma unroll
      for (int k = 0; k < 64; ++k) acc = fmaf(M0[r * 64 + k], M1[k * 64 + j], acc);
      WBg[o] = acc;
    }
    if (tid < 64) {
      int j = tid;
      float acc = b_ops[64 + j] + b_ops[128 + j];
#pragma unroll
      for (int k = 0; k < 64; ++k) acc = fmaf(b_ops[k], M2[k * 64 + j], acc);
      bb[j] = acc;
    }
    __syncthreads();
    if (tid < 64) {
      int j = tid;
      float acc = b_cat[j];
#pragma unroll
      for (int k = 0; k < 64; ++k) {
        acc = fmaf(b_ops[k], M3[k * 64 + j], acc);
        acc = fmaf(bb[k], M4[k * 64 + j], acc);
        acc = fmaf(b_ops[192 + k] + b_ops[256 + k], M1[k * 64 + j], acc);
      }
      cg[j] = acc;
    }
  }
}

// prep3: W0B = W0@WB ; b0B = b0@WB   (B = C@W0 + deg*b0 substitution)
__global__ __launch_bounds__(256) void prep3_k(const float* __restrict__ W_ops,
                                               const float* __restrict__ b_ops,
                                               const float* __restrict__ WBg,
                                               float* __restrict__ W0Bg,
                                               float* __restrict__ b0Bg) {
  __shared__ float Wa[4096], Wb[4096];
  int tid = threadIdx.x;
  for (int i = tid; i < 4096; i += 256) { Wa[i] = W_ops[i]; Wb[i] = WBg[i]; }
  __syncthreads();
  for (int t = 0; t < 16; ++t) {
    int o = tid + t * 256;
    int r = o >> 6, j = o & 63;
    float acc = 0.f;
#pragma unroll
    for (int k = 0; k < 64; ++k) acc = fmaf(Wa[r * 64 + k], Wb[k * 64 + j], acc);
    W0Bg[o] = acc;
  }
  if (tid < 64) {
    float acc = 0.f;
#pragma unroll
    for (int k = 0; k < 64; ++k) acc = fmaf(b_ops[k], Wb[k * 64 + tid], acc);
    b0Bg[tid] = acc;
  }
}

// Vnew = A@WA + C@W0B + deg*b0B + c   (A, C packed bf16)
__global__ __launch_bounds__(256) void vnew_k(const unsigned* __restrict__ Ab,
                                              const unsigned* __restrict__ Cb,
                                              const int* __restrict__ counts,
                                              const float* __restrict__ WAg,
                                              const float* __restrict__ W0Bg,
                                              const float* __restrict__ cg,
                                              const float* __restrict__ b0Bg,
                                              float* __restrict__ Vnew) {
  __shared__ float WA[4096], WB[4096];
  __shared__ float cb[64], b0v[64];
  int tid = threadIdx.x;
  for (int i = tid; i < 4096; i += 256) { WA[i] = WAg[i]; WB[i] = W0Bg[i]; }
  if (tid < 64) { cb[tid] = cg[tid]; b0v[tid] = b0Bg[tid]; }
  __syncthreads();
  int r = blockIdx.x * 256 + tid;
  if (r >= N_NODES) return;
  float xa[64], xc[64];
  const uint4* Ar = reinterpret_cast<const uint4*>(Ab + (size_t)r * 32);
  const uint4* Cr = reinterpret_cast<const uint4*>(Cb + (size_t)r * 32);
#pragma unroll
  for (int q = 0; q < 8; ++q) {
    uint4 ua = Ar[q];
    xa[q * 8 + 0] = bflo(ua.x); xa[q * 8 + 1] = bfhi(ua.x);
    xa[q * 8 + 2] = bflo(ua.y); xa[q * 8 + 3] = bfhi(ua.y);
    xa[q * 8 + 4] = bflo(ua.z); xa[q * 8 + 5] = bfhi(ua.z);
    xa[q * 8 + 6] = bflo(ua.w); xa[q * 8 + 7] = bfhi(ua.w);
    uint4 uc = Cr[q];
    xc[q * 8 + 0] = bflo(uc.x); xc[q * 8 + 1] = bfhi(uc.x);
    xc[q * 8 + 2] = bflo(uc.y); xc[q * 8 + 3] = bfhi(uc.y);
    xc[q * 8 + 4] = bflo(uc.z); xc[q * 8 + 5] = bfhi(uc.z);
    xc[q * 8 + 6] = bflo(uc.w); xc[q * 8 + 7] = bfhi(uc.w);
  }
  float deg = (float)counts[r];
  float4* Or = reinterpret_cast<float4*>(Vnew + (size_t)r * 64);
  for (int j0 = 0; j0 < 64; j0 += 4) {
    float a0 = fmaf(deg, b0v[j0], cb[j0]);
    float a1 = fmaf(deg, b0v[j0 + 1], cb[j0 + 1]);
    float a2 = fmaf(deg, b0v[j0 + 2], cb[j0 + 2]);
    float a3 = fmaf(deg, b0v[j0 + 3], cb[j0 + 3]);
#pragma unroll
    for (int k = 0; k < 64; ++k) {
      float4 wa = *reinterpret_cast<const float4*>(&WA[k * 64 + j0]);
      a0 = fmaf(xa[k], wa.x, a0);
      a1 = fmaf(xa[k], wa.y, a1);
      a2 = fmaf(xa[k], wa.z, a2);
      a3 = fmaf(xa[k], wa.w, a3);
      float4 wb = *reinterpret_cast<const float4*>(&WB[k * 64 + j0]);
      a0 = fmaf(xc[k], wb.x, a0);
      a1 = fmaf(xc[k], wb.y, a1);
      a2 = fmaf(xc[k], wb.z, a2);
      a3 = fmaf(xc[k], wb.w, a3);
    }
    Or[j0 >> 2] = make_float4(a0, a1, a2, a3);
  }
}

// Ps/Pd written as packed bf16 pairs (row = 32 uints = 128 B)
__global__ __launch_bounds__(256) void proj_k(const float* __restrict__ Vnew,
                                              const float* __restrict__ W_S,
                                              const float* __restrict__ b_S,
                                              unsigned* __restrict__ PsP,
                                              unsigned* __restrict__ PdP) {
  __shared__ float W0s[4096], W2s[4096];
  __shared__ float bias[64];
  int tid = threadIdx.x;
  for (int i = tid; i < 4096; i += 256) { W0s[i] = W_S[i]; W2s[i] = W_S[8192 + i]; }
  if (tid < 64) bias[tid] = b_S[tid];
  __syncthreads();
  int r = blockIdx.x * 256 + tid;
  if (r >= N_NODES) return;
  float x[64];
  const float4* Xr = reinterpret_cast<const float4*>(Vnew + (size_t)r * 64);
#pragma unroll
  for (int q = 0; q < 16; ++q) {
    float4 v = Xr[q];
    x[q * 4] = v.x; x[q * 4 + 1] = v.y; x[q * 4 + 2] = v.z; x[q * 4 + 3] = v.w;
  }
  for (int j0 = 0; j0 < 64; j0 += 4) {
    float a0 = bias[j0], a1 = bias[j0 + 1], a2 = bias[j0 + 2], a3 = bias[j0 + 3];
    float d0 = 0.f, d1 = 0.f, d2 = 0.f, d3 = 0.f;
#pragma unroll
    for (int k = 0; k < 64; ++k) {
      float xk = x[k];
      float4 w = *reinterpret_cast<const float4*>(&W0s[k * 64 + j0]);
      a0 = fmaf(xk, w.x, a0);
      a1 = fmaf(xk, w.y, a1);
      a2 = fmaf(xk, w.z, a2);
      a3 = fmaf(xk, w.w, a3);
      float4 u = *reinterpret_cast<const float4*>(&W2s[k * 64 + j0]);
      d0 = fmaf(xk, u.x, d0);
      d1 = fmaf(xk, u.y, d1);
      d2 = fmaf(xk, u.z, d2);
      d3 = fmaf(xk, u.w, d3);
    }
    uint2 ps = make_uint2(packbf(a0, a1), packbf(a2, a3));
    uint2 pd = make_uint2(packbf(d0, d1), packbf(d2, d3));
    *reinterpret_cast<uint2*>(&PsP[(size_t)r * 32 + (j0 >> 1)]) = ps;
    *reinterpret_cast<uint2*>(&PdP[(size_t)r * 32 + (j0 >> 1)]) = pd;
  }
}

// ---- edge, original order; f32 W in LDS (fewer unpacks), bf16 Ea/Spd;
// E_new written packed-bf16 into low 128B of each 256B d_out slot ----
__global__ __launch_bounds__(256) void edge_k(
    const float* __restrict__ Eg, const int* __restrict__ src, const int* __restrict__ dst,
    const unsigned* __restrict__ PsP, const unsigned* __restrict__ PdP,
    const float* __restrict__ W_S, unsigned* __restrict__ EoutSlots,
    float* __restrict__ partials) {
  __shared__ float Wm[4096];
  __shared__ unsigned Ea[64][33];
  __shared__ unsigned Spd[64][34];
  __shared__ float ls[128];
  int tid = threadIdx.x;
  int e0 = blockIdx.x * 64;
  int l16 = tid & 15, g16 = tid >> 4;

  // phase A: issue gather row-loads into regs (latency overlaps staging)
  uint2 pa[4], pb[4];
#pragma unroll
  for (int rr = 0; rr < 4; ++rr) {
    int p = e0 + rr * 16 + g16;
    int s = src[p], d = dst[p];
    pa[rr] = *reinterpret_cast<const uint2*>(&PsP[(size_t)s * 32 + 2 * l16]);
    pb[rr] = *reinterpret_cast<const uint2*>(&PdP[(size_t)d * 32 + 2 * l16]);
  }
  for (int i = tid; i < 4096; i += 256) Wm[i] = W_S[4096 + i];
  if (tid < 128) ls[tid] = 0.f;
  for (int q = tid; q < 1024; q += 256) {
    int e = q >> 4, kq = q & 15;
    float4 vv = reinterpret_cast<const float4*>(Eg)[(size_t)(e0 + e) * 16 + kq];
    Ea[e][kq * 2]     = packbf(leaky(vv.x), leaky(vv.y));
    Ea[e][kq * 2 + 1] = packbf(leaky(vv.z), leaky(vv.w));
  }
#pragma unroll
  for (int rr = 0; rr < 4; ++rr) {
    int r = rr * 16 + g16;
    float fx = bflo(pa[rr].x) + bflo(pb[rr].x);
    float fy = bfhi(pa[rr].x) + bfhi(pb[rr].x);
    float fz = bflo(pa[rr].y) + bflo(pb[rr].y);
    float fw = bfhi(pa[rr].y) + bfhi(pb[rr].y);
    *reinterpret_cast<uint2*>(&Spd[r][l16 * 2]) = make_uint2(packbf(fx, fy), packbf(fz, fw));
  }
  __syncthreads();

  int eq = tid & 15, cq = tid >> 4;
  int eb = eq * 4;
  float acc[4][4];
#pragma unroll
  for (int i = 0; i < 4; ++i) {
    uint2 sp = *reinterpret_cast<const uint2*>(&Spd[eb + i][cq * 2]);
    acc[i][0] = bflo(sp.x);
    acc[i][1] = bfhi(sp.x);
    acc[i][2] = bflo(sp.y);
    acc[i][3] = bfhi(sp.y);
  }

#pragma unroll 4
  for (int k2 = 0; k2 < 32; ++k2) {
    float4 w0 = *reinterpret_cast<const float4*>(&Wm[(2 * k2) * 64 + cq * 4]);
    float4 w1 = *reinterpret_cast<const float4*>(&Wm[(2 * k2 + 1) * 64 + cq * 4]);
#pragma unroll
    for (int i = 0; i < 4; ++i) {
      unsigned ue = Ea[eb + i][k2];
      float ev0 = bflo(ue), ev1 = bfhi(ue);
      acc[i][0] = fmaf(ev0, w0.x, acc[i][0]);
      acc[i][1] = fmaf(ev0, w0.y, acc[i][1]);
      acc[i][2] = fmaf(ev0, w0.z, acc[i][2]);
      acc[i][3] = fmaf(ev0, w0.w, acc[i][3]);
      acc[i][0] = fmaf(ev1, w1.x, acc[i][0]);
      acc[i][1] = fmaf(ev1, w1.y, acc[i][1]);
      acc[i][2] = fmaf(ev1, w1.z, acc[i][2]);
      acc[i][3] = fmaf(ev1, w1.w, acc[i][3]);
    }
  }

  float s4[4] = {0.f, 0.f, 0.f, 0.f}, q4[4] = {0.f, 0.f, 0.f, 0.f};
#pragma unroll
  for (int i = 0; i < 4; ++i) {
    uint2 st = make_uint2(packbf(acc[i][0], acc[i][1]), packbf(acc[i][2], acc[i][3]));
    *reinterpret_cast<uint2*>(&EoutSlots[(size_t)(e0 + eb + i) * 64 + cq * 2]) = st;
#pragma unroll
    for (int c = 0; c < 4; ++c) {
      s4[c] += acc[i][c];
      q4[c] = fmaf(acc[i][c], acc[i][c], q4[c]);
    }
  }
#pragma unroll
  for (int off = 8; off; off >>= 1) {
#pragma unroll
    for (int c = 0; c < 4; ++c) {
      s4[c] += __shfl_xor(s4[c], off, 16);
      q4[c] += __shfl_xor(q4[c], off, 16);
    }
  }
  if (eq == 0) {
#pragma unroll
    for (int c = 0; c < 4; ++c) {
      atomicAdd(&ls[cq * 4 + c], s4[c]);
      atomicAdd(&ls[64 + cq * 4 + c], q4[c]);
    }
  }
  __syncthreads();
  if (tid < 128) partials[(size_t)blockIdx.x * 128 + tid] = ls[tid];
}

// ---- reduce per-block partials [NEBLK][128] -> stats[128] ----
__global__ __launch_bounds__(256) void reduce_stats_k(const float* __restrict__ partials,
                                                      float* __restrict__ stats) {
  __shared__ float ls[128];
  int tid = threadIdx.x;
  if (tid < 128) ls[tid] = 0.f;
  __syncthreads();
  int c = tid & 127;
  int half = tid >> 7;
  float s = 0.f;
  for (int r = blockIdx.x * 2 + half; r < NEBLK; r += 2 * gridDim.x) {
    s += partials[(size_t)r * 128 + c];
  }
  atomicAdd(&ls[c], s);
  __syncthreads();
  if (tid < 128) atomicAdd(&stats[tid], ls[tid]);
}

// ---- per-column sum / sumsq (for V side) ----
__global__ __launch_bounds__(256) void col_stats_k(
    const float* __restrict__ X, size_t nelem, float* __restrict__ sums) {
  __shared__ float ls[128];
  int tid = threadIdx.x;
  if (tid < 128) ls[tid] = 0.f;
  __syncthreads();
  int j = tid & 63;
  float s = 0.f, ss = 0.f;
  size_t stride = (size_t)gridDim.x * blockDim.x;
  for (size_t i = (size_t)blockIdx.x * blockDim.x + tid; i < nelem; i += stride) {
    float x = X[i];
    s += x;
    ss = fmaf(x, x, ss);
  }
  atomicAdd(&ls[j], s);
  atomicAdd(&ls[64 + j], ss);
  __syncthreads();
  if (tid < 128) atomicAdd(&sums[tid], ls[tid]);
}

__global__ void finalize_k(const float* __restrict__ sums, float inv_n,
                           const float* __restrict__ gamma, const float* __restrict__ beta,
                           float* __restrict__ sc_shift) {
  int j = threadIdx.x;
  float mu = sums[j] * inv_n;
  float var = sums[64 + j] * inv_n - mu * mu;
  float sc = gamma[j] * rsqrtf(var + BN_EPS);
  sc_shift[j] = sc;
  sc_shift[64 + j] = beta[j] - mu * sc;
}

// ---- V side: in-place f32 bn+leaky+residual ----
__global__ __launch_bounds__(256) void bn_apply_k(
    float* __restrict__ X, const float* __restrict__ resid,
    const float* __restrict__ sc_shift, int n4) {
  int i = blockIdx.x * blockDim.x + threadIdx.x;
  if (i >= n4) return;
  int jq = i & 15;
  float4 x = reinterpret_cast<float4*>(X)[i];
  float4 r = reinterpret_cast<const float4*>(resid)[i];
  float4 sc = reinterpret_cast<const float4*>(sc_shift)[jq];
  float4 sh = reinterpret_cast<const float4*>(sc_shift + 64)[jq];
  float4 y;
  y.x = leaky(fmaf(x.x, sc.x, sh.x)) + r.x;
  y.y = leaky(fmaf(x.y, sc.y, sh.y)) + r.y;
  y.z = leaky(fmaf(x.z, sc.z, sh.z)) + r.z;
  y.w = leaky(fmaf(x.w, sc.w, sh.w)) + r.w;
  reinterpret_cast<float4*>(X)[i] = y;
}

// ---- E side: thread-per-row slot expansion: read own bf16 (low 128B),
// write f32 (256B). Race-free: each row's f32 covers only its own slot. ----
__global__ __launch_bounds__(256) void bn_applyE_k(
    float* __restrict__ EoutF, const float* __restrict__ Eg,
    const float* __restrict__ sc_shift) {
  __shared__ float scs[128];
  int tid = threadIdx.x;
  if (tid < 128) scs[tid] = sc_shift[tid];
  __syncthreads();
  int e = blockIdx.x * 256 + tid;   // grid exactly M/256
  float4* slot = reinterpret_cast<float4*>(EoutF) + (size_t)e * 16;
  const float4* eg = reinterpret_cast<const float4*>(Eg) + (size_t)e * 16;
  float4 braw[8];
#pragma unroll
  for (int q = 0; q < 8; ++q) braw[q] = slot[q];
#pragma unroll
  for (int q = 0; q < 8; ++q) {
    unsigned u0 = __float_as_uint(braw[q].x);
    unsigned u1 = __float_as_uint(braw[q].y);
    unsigned u2 = __float_as_uint(braw[q].z);
    unsigned u3 = __float_as_uint(braw[q].w);
    float v[8] = {bflo(u0), bfhi(u0), bflo(u1), bfhi(u1),
                  bflo(u2), bfhi(u2), bflo(u3), bfhi(u3)};
    float4 e0 = eg[2 * q], e1 = eg[2 * q + 1];
    int j = q * 8;
    float4 o0, o1;
    o0.x = leaky(fmaf(v[0], scs[j + 0], scs[64 + j + 0])) + e0.x;
    o0.y = leaky(fmaf(v[1], scs[j + 1], scs[64 + j + 1])) + e0.y;
    o0.z = leaky(fmaf(v[2], scs[j + 2], scs[64 + j + 2])) + e0.z;
    o0.w = leaky(fmaf(v[3], scs[j + 3], scs[64 + j + 3])) + e0.w;
    o1.x = leaky(fmaf(v[4], scs[j + 4], scs[64 + j + 4])) + e1.x;
    o1.y = leaky(fmaf(v[5], scs[j + 5], scs[64 + j + 5])) + e1.y;
    o1.z = leaky(fmaf(v[6], scs[j + 6], scs[64 + j + 6])) + e1.z;
    o1.w = leaky(fmaf(v[7], scs[j + 7], scs[64 + j + 7])) + e1.w;
    slot[2 * q] = o0;
    slot[2 * q + 1] = o1;
  }
}

extern "C" void kernel_launch(void* const* d_in, const int* in_sizes, int n_in,
                              void* d_out, int out_size, void* d_ws, size_t ws_size,
                              hipStream_t stream) {
  const float* V      = (const float*)d_in[0];
  const float* Eg     = (const float*)d_in[1];
  const int*   src    = (const int*)d_in[2];
  const int*   dst    = (const int*)d_in[3];
  const float* W_ops  = (const float*)d_in[4];
  const float* b_ops  = (const float*)d_in[5];
  const float* W_cat  = (const float*)d_in[6];
  const float* b_cat  = (const float*)d_in[7];
  const float* W_S    = (const float*)d_in[8];
  const float* b_S    = (const float*)d_in[9];
  const float* gammaV = (const float*)d_in[10];
  const float* betaV  = (const float*)d_in[11];
  const float* gammaE = (const float*)d_in[12];
  const float* betaE  = (const float*)d_in[13];

  float* ws = (float*)d_ws;
  const size_t ND = (size_t)N_NODES * 64;
  const size_t NH = (size_t)N_NODES * 32;   // packed row units
  unsigned* Vb  = (unsigned*)ws;
  unsigned* Ab  = (unsigned*)ws + NH;
  unsigned* Cb  = (unsigned*)ws + 2 * NH;
  unsigned* PsP = (unsigned*)ws + 3 * NH;
  unsigned* PdP = (unsigned*)ws + 4 * NH;
  float* xb   = ws + 5 * NH;
  float* W12g  = xb;
  float* Wc12g = xb + 4096;
  float* WAg   = xb + 8192;
  float* WBg   = xb + 12288;
  float* W0Bg  = xb + 16384;
  float* cg    = xb + 20480;
  float* b0Bg  = xb + 20544;
  float* statsV = xb + 20608;
  float* statsE = statsV + 128;
  float* scshV  = statsV + 256;
  float* scshE  = statsV + 384;
  int* counts = (int*)(statsV + 512);
  int* offs   = counts + N_NODES;
  int* cursor = offs + N_NODES + 1;
  int* ssrc   = cursor + N_NODES;
  float* partials = (float*)(ssrc + M_EDGES);   // NEBLK*128 floats

  float* Vout  = (float*)d_out;
  float* EoutF = Vout + ND;                      // E region (slots)
  unsigned* EoutSlots = (unsigned*)EoutF;

  hipMemsetAsync(counts, 0, N_NODES * sizeof(int), stream);
  hipMemsetAsync(statsV, 0, 256 * sizeof(float), stream);

  const int eb = (M_EDGES + 255) / 256;
  const int rb = (N_NODES + 255) / 256;
  prep1_k<<<2, 256, 0, stream>>>(W_ops, W_cat, W12g, Wc12g);
  prep2_k<<<2, 256, 0, stream>>>(W_ops, b_ops, W_cat, b_cat, W12g, Wc12g, WAg, WBg, cg);
  prep3_k<<<1, 256, 0, stream>>>(W_ops, b_ops, WBg, W0Bg, b0Bg);
  hist_k<<<eb, 256, 0, stream>>>(dst, counts);
  scan_k<<<1, 256, 0, stream>>>(counts, offs, cursor);
  fill_k<<<eb, 256, 0, stream>>>(src, dst, cursor, ssrc);

  convbf_k<<<(N_NODES * 8 + 255) / 256, 256, 0, stream>>>(V, Vb, N_NODES * 8);
  gatherb_k<<<N_NODES / 4, 256, 0, stream>>>(Vb, offs, ssrc, Ab);
  gatherb_k<<<N_NODES / 4, 256, 0, stream>>>(Ab, offs, ssrc, Cb);
  vnew_k<<<rb, 256, 0, stream>>>(Ab, Cb, counts, WAg, W0Bg, cg, b0Bg, Vout);
  proj_k<<<rb, 256, 0, stream>>>(Vout, W_S, b_S, PsP, PdP);
  edge_k<<<NEBLK, 256, 0, stream>>>(Eg, src, dst, PsP, PdP, W_S, EoutSlots, partials);
  reduce_stats_k<<<64, 256, 0, stream>>>(partials, statsE);
  col_stats_k<<<512, 256, 0, stream>>>(Vout, ND, statsV);
  finalize_k<<<1, 64, 0, stream>>>(statsV, 1.f / N_NODES, gammaV, betaV, scshV);
  finalize_k<<<1, 64, 0, stream>>>(statsE, 1.f / M_EDGES, gammaE, betaE, scshE);
  bn_apply_k<<<(int)((ND / 4 + 255) / 256), 256, 0, stream>>>(Vout, V, scshV, (int)(ND / 4));
  bn_applyE_k<<<M_EDGES / 256, 256, 0, stream>>>(EoutF, Eg, scshE);
}

// Round 11
// 809.215 us; speedup vs baseline: 1.1231x; 1.1231x over previous
//
#include <hip/hip_runtime.h>
#include <hip/hip_bf16.h>

#define N_NODES 50000
#define M_EDGES 800000
#define LEAKY_F 0.2f
#define BN_EPS 1e-5f
#define NEBLK (M_EDGES / 64)

__device__ __forceinline__ float leaky(float x) { return x >= 0.f ? x : LEAKY_F * x; }

// round-to-nearest-even f32 -> bf16 (finite inputs)
__device__ __forceinline__ unsigned f2bf(float f) {
  unsigned u = __float_as_uint(f);
  return (u + 0x7fffu + ((u >> 16) & 1u)) >> 16;
}
__device__ __forceinline__ unsigned packbf(float a, float b) {
  return (f2bf(b) << 16) | f2bf(a);
}
__device__ __forceinline__ float bflo(unsigned u) { return __uint_as_float(u << 16); }
__device__ __forceinline__ float bfhi(unsigned u) { return __uint_as_float(u & 0xffff0000u); }

// ================= CSR build =================
__global__ __launch_bounds__(256) void hist_k(const int* __restrict__ dst,
                                              int* __restrict__ counts) {
  int e = blockIdx.x * 256 + threadIdx.x;
  if (e < M_EDGES) atomicAdd(&counts[dst[e]], 1);
}

__global__ __launch_bounds__(256) void scan_k(const int* __restrict__ counts,
                                              int* __restrict__ offs,
                                              int* __restrict__ cursor) {
  __shared__ int chunk[256];
  const int CH = (N_NODES + 255) / 256;
  int tid = threadIdx.x;
  int beg = tid * CH, end = min(beg + CH, N_NODES);
  int s = 0;
  for (int i = beg; i < end; ++i) s += counts[i];
  chunk[tid] = s;
  __syncthreads();
  if (tid == 0) {
    int run = 0;
    for (int i = 0; i < 256; ++i) { int c = chunk[i]; chunk[i] = run; run += c; }
  }
  __syncthreads();
  int base = chunk[tid];
  for (int i = beg; i < end; ++i) {
    offs[i] = base;
    cursor[i] = base;
    base += counts[i];
  }
  if (tid == 0) offs[N_NODES] = M_EDGES;
}

__global__ __launch_bounds__(256) void fill_k(const int* __restrict__ src,
                                              const int* __restrict__ dst,
                                              int* __restrict__ cursor,
                                              int* __restrict__ ssrc) {
  int e = blockIdx.x * 256 + threadIdx.x;
  if (e >= M_EDGES) return;
  int p = atomicAdd(&cursor[dst[e]], 1);
  ssrc[p] = src[e];
}

// ---- f32 rows -> packed bf16 rows (uint4 per thread = 8 floats) ----
__global__ __launch_bounds__(256) void convbf_k(const float* __restrict__ X,
                                                unsigned* __restrict__ Xb, int n4) {
  int i = blockIdx.x * 256 + threadIdx.x;
  if (i >= n4) return;
  const float4* s4 = reinterpret_cast<const float4*>(X) + (size_t)i * 2;
  float4 a = s4[0], b = s4[1];
  uint4 o;
  o.x = packbf(a.x, a.y);
  o.y = packbf(a.z, a.w);
  o.z = packbf(b.x, b.y);
  o.w = packbf(b.z, b.w);
  reinterpret_cast<uint4*>(Xb)[i] = o;
}

// ---- segment gather-sum over packed-bf16 rows; wave per node, half-wave per edge ----
__global__ __launch_bounds__(256) void gatherb_k(const unsigned* __restrict__ Xb,
                                                 const int* __restrict__ offs,
                                                 const int* __restrict__ ssrc,
                                                 unsigned* __restrict__ Ob) {
  int n = blockIdx.x * 4 + (threadIdx.x >> 6);
  int lane = threadIdx.x & 63;
  int half = lane >> 5, col = lane & 31;
  int beg = offs[n], end = offs[n + 1];
  float a0 = 0.f, a1 = 0.f;
  for (int i = beg + half; i < end; i += 2) {
    unsigned u = Xb[(size_t)ssrc[i] * 32 + col];
    a0 += bflo(u);
    a1 += bfhi(u);
  }
  a0 += __shfl_xor(a0, 32);
  a1 += __shfl_xor(a1, 32);
  if (half == 0) Ob[(size_t)n * 32 + col] = packbf(a0, a1);
}

// ================= weight-prep (algebraic collapse) =================
__global__ __launch_bounds__(256) void prep1_k(const float* __restrict__ W_ops,
                                               const float* __restrict__ W_cat,
                                               float* __restrict__ W12g,
                                               float* __restrict__ Wc12g) {
  __shared__ float Wa[4096], Wb[4096];
  int tid = threadIdx.x;
  const float *Am, *Bm, *Add;
  float* Out;
  if (blockIdx.x == 0) { Am = W_ops; Bm = W_ops + 8192; Add = W_ops + 4096; Out = W12g; }
  else { Am = W_ops + 16384; Bm = W_cat + 8192; Add = W_cat + 4096; Out = Wc12g; }
  for (int i = tid; i < 4096; i += 256) { Wa[i] = Am[i]; Wb[i] = Bm[i]; }
  __syncthreads();
  for (int t = 0; t < 16; ++t) {
    int o = tid + t * 256;
    int r = o >> 6, j = o & 63;
    float acc = Add[o];
#pragma unroll
    for (int k = 0; k < 64; ++k) acc = fmaf(Wa[r * 64 + k], Wb[k * 64 + j], acc);
    Out[o] = acc;
  }
}

__global__ __launch_bounds__(256) void prep2_k(const float* __restrict__ W_ops,
                                               const float* __restrict__ b_ops,
                                               const float* __restrict__ W_cat,
                                               const float* __restrict__ b_cat,
                                               const float* __restrict__ W12g,
                                               const float* __restrict__ Wc12g,
                                               float* __restrict__ WAg,
                                               float* __restrict__ WBg,
                                               float* __restrict__ cg) {
  __shared__ float M0[4096], M1[4096], M2[4096], M3[4096], M4[4096];
  __shared__ float bb[64];
  int tid = threadIdx.x;
  if (blockIdx.x == 0) {
    for (int i = tid; i < 4096; i += 256) {
      M0[i] = W_ops[i];
      M1[i] = W_cat[i];
      M2[i] = W12g[i];
      M3[i] = Wc12g[i];
    }
    __syncthreads();
    for (int t = 0; t < 16; ++t) {
      int o = tid + t * 256;
      int r = o >> 6, j = o & 63;
      float acc = 0.f;
#pragma unroll
      for (int k = 0; k < 64; ++k) {
        acc = fmaf(M0[r * 64 + k], M1[k * 64 + j], acc);
        acc = fmaf(M2[r * 64 + k], M3[k * 64 + j], acc);
      }
      WAg[o] = acc;
    }
  } else {
    for (int i = tid; i < 4096; i += 256) {
      M0[i] = W_ops[3 * 4096 + i];
      M1[i] = W_cat[8192 + i];
      M2[i] = W_ops[2 * 4096 + i];
      M3[i] = W_cat[i];
      M4[i] = Wc12g[i];
    }
    __syncthreads();
    for (int t = 0; t < 16; ++t) {
      int o = tid + t * 256;
      int r = o >> 6, j = o & 63;
      float acc = 0.f;
#pragma unroll
      for (int k = 0; k < 64; ++k) acc = fmaf(M0[r * 64 + k], M1[k * 64 + j], acc);
      WBg[o] = acc;
    }
    if (tid < 64) {
      int j = tid;
      float acc = b_ops[64 + j] + b_ops[128 + j];
#pragma unroll
      for (int k = 0; k < 64; ++k) acc = fmaf(b_ops[k], M2[k * 64 + j], acc);
      bb[j] = acc;
    }
    __syncthreads();
    if (tid < 64) {
      int j = tid;
      float acc = b_cat[j];
#pragma unroll
      for (int k = 0; k < 64; ++k) {
        acc = fmaf(b_ops[k], M3[k * 64 + j], acc);
        acc = fmaf(bb[k], M4[k * 64 + j], acc);
        acc = fmaf(b_ops[192 + k] + b_ops[256 + k], M1[k * 64 + j], acc);
      }
      cg[j] = acc;
    }
  }
}

// prep3: W0B = W0@WB ; b0B = b0@WB   (B = C@W0 + deg*b0 substitution)
__global__ __launch_bounds__(256) void prep3_k(const float* __restrict__ W_ops,
                                               const float* __restrict__ b_ops,
                                               const float* __restrict__ WBg,
                                               float* __restrict__ W0Bg,
                                               float* __restrict__ b0Bg) {
  __shared__ float Wa[4096], Wb[4096];
  int tid = threadIdx.x;
  for (int i = tid; i < 4096; i += 256) { Wa[i] = W_ops[i]; Wb[i] = WBg[i]; }
  __syncthreads();
  for (int t = 0; t < 16; ++t) {
    int o = tid + t * 256;
    int r = o >> 6, j = o & 63;
    float acc = 0.f;
#pragma unroll
    for (int k = 0; k < 64; ++k) acc = fmaf(Wa[r * 64 + k], Wb[k * 64 + j], acc);
    W0Bg[o] = acc;
  }
  if (tid < 64) {
    float acc = 0.f;
#pragma unroll
    for (int k = 0; k < 64; ++k) acc = fmaf(b_ops[k], Wb[k * 64 + tid], acc);
    b0Bg[tid] = acc;
  }
}

// Vnew = A@WA + C@W0B + deg*b0B + c   (A, C packed bf16)
__global__ __launch_bounds__(256) void vnew_k(const unsigned* __restrict__ Ab,
                                              const unsigned* __restrict__ Cb,
                                              const int* __restrict__ counts,
                                              const float* __restrict__ WAg,
                                              const float* __restrict__ W0Bg,
                                              const float* __restrict__ cg,
                                              const float* __restrict__ b0Bg,
                                              float* __restrict__ Vnew) {
  __shared__ float WA[4096], WB[4096];
  __shared__ float cb[64], b0v[64];
  int tid = threadIdx.x;
  for (int i = tid; i < 4096; i += 256) { WA[i] = WAg[i]; WB[i] = W0Bg[i]; }
  if (tid < 64) { cb[tid] = cg[tid]; b0v[tid] = b0Bg[tid]; }
  __syncthreads();
  int r = blockIdx.x * 256 + tid;
  if (r >= N_NODES) return;
  float xa[64], xc[64];
  const uint4* Ar = reinterpret_cast<const uint4*>(Ab + (size_t)r * 32);
  const uint4* Cr = reinterpret_cast<const uint4*>(Cb + (size_t)r * 32);
#pragma unroll
  for (int q = 0; q < 8; ++q) {
    uint4 ua = Ar[q];
    xa[q * 8 + 0] = bflo(ua.x); xa[q * 8 + 1] = bfhi(ua.x);
    xa[q * 8 + 2] = bflo(ua.y); xa[q * 8 + 3] = bfhi(ua.y);
    xa[q * 8 + 4] = bflo(ua.z); xa[q * 8 + 5] = bfhi(ua.z);
    xa[q * 8 + 6] = bflo(ua.w); xa[q * 8 + 7] = bfhi(ua.w);
    uint4 uc = Cr[q];
    xc[q * 8 + 0] = bflo(uc.x); xc[q * 8 + 1] = bfhi(uc.x);
    xc[q * 8 + 2] = bflo(uc.y); xc[q * 8 + 3] = bfhi(uc.y);
    xc[q * 8 + 4] = bflo(uc.z); xc[q * 8 + 5] = bfhi(uc.z);
    xc[q * 8 + 6] = bflo(uc.w); xc[q * 8 + 7] = bfhi(uc.w);
  }
  float deg = (float)counts[r];
  float4* Or = reinterpret_cast<float4*>(Vnew + (size_t)r * 64);
  for (int j0 = 0; j0 < 64; j0 += 4) {
    float a0 = fmaf(deg, b0v[j0], cb[j0]);
    float a1 = fmaf(deg, b0v[j0 + 1], cb[j0 + 1]);
    float a2 = fmaf(deg, b0v[j0 + 2], cb[j0 + 2]);
    float a3 = fmaf(deg, b0v[j0 + 3], cb[j0 + 3]);
#pragma unroll
    for (int k = 0; k < 64; ++k) {
      float4 wa = *reinterpret_cast<const float4*>(&WA[k * 64 + j0]);
      a0 = fmaf(xa[k], wa.x, a0);
      a1 = fmaf(xa[k], wa.y, a1);
      a2 = fmaf(xa[k], wa.z, a2);
      a3 = fmaf(xa[k], wa.w, a3);
      float4 wb = *reinterpret_cast<const float4*>(&WB[k * 64 + j0]);
      a0 = fmaf(xc[k], wb.x, a0);
      a1 = fmaf(xc[k], wb.y, a1);
      a2 = fmaf(xc[k], wb.z, a2);
      a3 = fmaf(xc[k], wb.w, a3);
    }
    Or[j0 >> 2] = make_float4(a0, a1, a2, a3);
  }
}

// Ps/Pd written as packed bf16 pairs (row = 32 uints = 128 B)
__global__ __launch_bounds__(256) void proj_k(const float* __restrict__ Vnew,
                                              const float* __restrict__ W_S,
                                              const float* __restrict__ b_S,
                                              unsigned* __restrict__ PsP,
                                              unsigned* __restrict__ PdP) {
  __shared__ float W0s[4096], W2s[4096];
  __shared__ float bias[64];
  int tid = threadIdx.x;
  for (int i = tid; i < 4096; i += 256) { W0s[i] = W_S[i]; W2s[i] = W_S[8192 + i]; }
  if (tid < 64) bias[tid] = b_S[tid];
  __syncthreads();
  int r = blockIdx.x * 256 + tid;
  if (r >= N_NODES) return;
  float x[64];
  const float4* Xr = reinterpret_cast<const float4*>(Vnew + (size_t)r * 64);
#pragma unroll
  for (int q = 0; q < 16; ++q) {
    float4 v = Xr[q];
    x[q * 4] = v.x; x[q * 4 + 1] = v.y; x[q * 4 + 2] = v.z; x[q * 4 + 3] = v.w;
  }
  for (int j0 = 0; j0 < 64; j0 += 4) {
    float a0 = bias[j0], a1 = bias[j0 + 1], a2 = bias[j0 + 2], a3 = bias[j0 + 3];
    float d0 = 0.f, d1 = 0.f, d2 = 0.f, d3 = 0.f;
#pragma unroll
    for (int k = 0; k < 64; ++k) {
      float xk = x[k];
      float4 w = *reinterpret_cast<const float4*>(&W0s[k * 64 + j0]);
      a0 = fmaf(xk, w.x, a0);
      a1 = fmaf(xk, w.y, a1);
      a2 = fmaf(xk, w.z, a2);
      a3 = fmaf(xk, w.w, a3);
      float4 u = *reinterpret_cast<const float4*>(&W2s[k * 64 + j0]);
      d0 = fmaf(xk, u.x, d0);
      d1 = fmaf(xk, u.y, d1);
      d2 = fmaf(xk, u.z, d2);
      d3 = fmaf(xk, u.w, d3);
    }
    uint2 ps = make_uint2(packbf(a0, a1), packbf(a2, a3));
    uint2 pd = make_uint2(packbf(d0, d1), packbf(d2, d3));
    *reinterpret_cast<uint2*>(&PsP[(size_t)r * 32 + (j0 >> 1)]) = ps;
    *reinterpret_cast<uint2*>(&PdP[(size_t)r * 32 + (j0 >> 1)]) = pd;
  }
}

// ---- edge, original order; f32 W in LDS, bf16 Ea/Spd;
// E_new written packed-bf16 into low 128B of each 256B d_out slot ----
__global__ __launch_bounds__(256) void edge_k(
    const float* __restrict__ Eg, const int* __restrict__ src, const int* __restrict__ dst,
    const unsigned* __restrict__ PsP, const unsigned* __restrict__ PdP,
    const float* __restrict__ W_S, unsigned* __restrict__ EoutSlots,
    float* __restrict__ partials) {
  __shared__ float Wm[4096];
  __shared__ unsigned Ea[64][33];
  __shared__ unsigned Spd[64][34];
  __shared__ float ls[128];
  int tid = threadIdx.x;
  int e0 = blockIdx.x * 64;
  int l16 = tid & 15, g16 = tid >> 4;

  // phase A: issue gather row-loads into regs (latency overlaps staging)
  uint2 pa[4], pb[4];
#pragma unroll
  for (int rr = 0; rr < 4; ++rr) {
    int p = e0 + rr * 16 + g16;
    int s = src[p], d = dst[p];
    pa[rr] = *reinterpret_cast<const uint2*>(&PsP[(size_t)s * 32 + 2 * l16]);
    pb[rr] = *reinterpret_cast<const uint2*>(&PdP[(size_t)d * 32 + 2 * l16]);
  }
  for (int i = tid; i < 4096; i += 256) Wm[i] = W_S[4096 + i];
  if (tid < 128) ls[tid] = 0.f;
  for (int q = tid; q < 1024; q += 256) {
    int e = q >> 4, kq = q & 15;
    float4 vv = reinterpret_cast<const float4*>(Eg)[(size_t)(e0 + e) * 16 + kq];
    Ea[e][kq * 2]     = packbf(leaky(vv.x), leaky(vv.y));
    Ea[e][kq * 2 + 1] = packbf(leaky(vv.z), leaky(vv.w));
  }
#pragma unroll
  for (int rr = 0; rr < 4; ++rr) {
    int r = rr * 16 + g16;
    float fx = bflo(pa[rr].x) + bflo(pb[rr].x);
    float fy = bfhi(pa[rr].x) + bfhi(pb[rr].x);
    float fz = bflo(pa[rr].y) + bflo(pb[rr].y);
    float fw = bfhi(pa[rr].y) + bfhi(pb[rr].y);
    *reinterpret_cast<uint2*>(&Spd[r][l16 * 2]) = make_uint2(packbf(fx, fy), packbf(fz, fw));
  }
  __syncthreads();

  int eq = tid & 15, cq = tid >> 4;
  int eb = eq * 4;
  float acc[4][4];
#pragma unroll
  for (int i = 0; i < 4; ++i) {
    uint2 sp = *reinterpret_cast<const uint2*>(&Spd[eb + i][cq * 2]);
    acc[i][0] = bflo(sp.x);
    acc[i][1] = bfhi(sp.x);
    acc[i][2] = bflo(sp.y);
    acc[i][3] = bfhi(sp.y);
  }

#pragma unroll 4
  for (int k2 = 0; k2 < 32; ++k2) {
    float4 w0 = *reinterpret_cast<const float4*>(&Wm[(2 * k2) * 64 + cq * 4]);
    float4 w1 = *reinterpret_cast<const float4*>(&Wm[(2 * k2 + 1) * 64 + cq * 4]);
#pragma unroll
    for (int i = 0; i < 4; ++i) {
      unsigned ue = Ea[eb + i][k2];
      float ev0 = bflo(ue), ev1 = bfhi(ue);
      acc[i][0] = fmaf(ev0, w0.x, acc[i][0]);
      acc[i][1] = fmaf(ev0, w0.y, acc[i][1]);
      acc[i][2] = fmaf(ev0, w0.z, acc[i][2]);
      acc[i][3] = fmaf(ev0, w0.w, acc[i][3]);
      acc[i][0] = fmaf(ev1, w1.x, acc[i][0]);
      acc[i][1] = fmaf(ev1, w1.y, acc[i][1]);
      acc[i][2] = fmaf(ev1, w1.z, acc[i][2]);
      acc[i][3] = fmaf(ev1, w1.w, acc[i][3]);
    }
  }

  float s4[4] = {0.f, 0.f, 0.f, 0.f}, q4[4] = {0.f, 0.f, 0.f, 0.f};
#pragma unroll
  for (int i = 0; i < 4; ++i) {
    uint2 st = make_uint2(packbf(acc[i][0], acc[i][1]), packbf(acc[i][2], acc[i][3]));
    *reinterpret_cast<uint2*>(&EoutSlots[(size_t)(e0 + eb + i) * 64 + cq * 2]) = st;
#pragma unroll
    for (int c = 0; c < 4; ++c) {
      s4[c] += acc[i][c];
      q4[c] = fmaf(acc[i][c], acc[i][c], q4[c]);
    }
  }
#pragma unroll
  for (int off = 8; off; off >>= 1) {
#pragma unroll
    for (int c = 0; c < 4; ++c) {
      s4[c] += __shfl_xor(s4[c], off, 16);
      q4[c] += __shfl_xor(q4[c], off, 16);
    }
  }
  if (eq == 0) {
#pragma unroll
    for (int c = 0; c < 4; ++c) {
      atomicAdd(&ls[cq * 4 + c], s4[c]);
      atomicAdd(&ls[64 + cq * 4 + c], q4[c]);
    }
  }
  __syncthreads();
  if (tid < 128) partials[(size_t)blockIdx.x * 128 + tid] = ls[tid];
}

// ---- reduce per-block partials [NEBLK][128] -> stats[128] ----
__global__ __launch_bounds__(256) void reduce_stats_k(const float* __restrict__ partials,
                                                      float* __restrict__ stats) {
  __shared__ float ls[128];
  int tid = threadIdx.x;
  if (tid < 128) ls[tid] = 0.f;
  __syncthreads();
  int c = tid & 127;
  int half = tid >> 7;
  float s = 0.f;
  for (int r = blockIdx.x * 2 + half; r < NEBLK; r += 2 * gridDim.x) {
    s += partials[(size_t)r * 128 + c];
  }
  atomicAdd(&ls[c], s);
  __syncthreads();
  if (tid < 128) atomicAdd(&stats[tid], ls[tid]);
}

// ---- per-column sum / sumsq (for V side) ----
__global__ __launch_bounds__(256) void col_stats_k(
    const float* __restrict__ X, size_t nelem, float* __restrict__ sums) {
  __shared__ float ls[128];
  int tid = threadIdx.x;
  if (tid < 128) ls[tid] = 0.f;
  __syncthreads();
  int j = tid & 63;
  float s = 0.f, ss = 0.f;
  size_t stride = (size_t)gridDim.x * blockDim.x;
  for (size_t i = (size_t)blockIdx.x * blockDim.x + tid; i < nelem; i += stride) {
    float x = X[i];
    s += x;
    ss = fmaf(x, x, ss);
  }
  atomicAdd(&ls[j], s);
  atomicAdd(&ls[64 + j], ss);
  __syncthreads();
  if (tid < 128) atomicAdd(&sums[tid], ls[tid]);
}

__global__ void finalize_k(const float* __restrict__ sums, float inv_n,
                           const float* __restrict__ gamma, const float* __restrict__ beta,
                           float* __restrict__ sc_shift) {
  int j = threadIdx.x;
  float mu = sums[j] * inv_n;
  float var = sums[64 + j] * inv_n - mu * mu;
  float sc = gamma[j] * rsqrtf(var + BN_EPS);
  sc_shift[j] = sc;
  sc_shift[64 + j] = beta[j] - mu * sc;
}

// ---- V side: in-place f32 bn+leaky+residual ----
__global__ __launch_bounds__(256) void bn_apply_k(
    float* __restrict__ X, const float* __restrict__ resid,
    const float* __restrict__ sc_shift, int n4) {
  int i = blockIdx.x * blockDim.x + threadIdx.x;
  if (i >= n4) return;
  int jq = i & 15;
  float4 x = reinterpret_cast<float4*>(X)[i];
  float4 r = reinterpret_cast<const float4*>(resid)[i];
  float4 sc = reinterpret_cast<const float4*>(sc_shift)[jq];
  float4 sh = reinterpret_cast<const float4*>(sc_shift + 64)[jq];
  float4 y;
  y.x = leaky(fmaf(x.x, sc.x, sh.x)) + r.x;
  y.y = leaky(fmaf(x.y, sc.y, sh.y)) + r.y;
  y.z = leaky(fmaf(x.z, sc.z, sh.z)) + r.z;
  y.w = leaky(fmaf(x.w, sc.w, sh.w)) + r.w;
  reinterpret_cast<float4*>(X)[i] = y;
}

// ---- E side, COALESCED float4-per-thread: thread i owns output float4 i.
// Reads its 4 bf16 vals as float2 from the slot's low 128B (16 lanes = 128B
// contiguous), Eg[i] (1KB/wave), writes f32 float4 (1KB/wave). In-place safe:
// a row's 16 threads sit in one wave; slot loads precede stores in the
// instruction stream; all accesses float-typed (no TBAA reorder). ----
__global__ __launch_bounds__(256) void bn_applyE_k(
    float* __restrict__ EoutF, const float* __restrict__ Eg,
    const float* __restrict__ sc_shift) {
  __shared__ float scs[128];
  int tid = threadIdx.x;
  if (tid < 128) scs[tid] = sc_shift[tid];
  __syncthreads();
  int i = blockIdx.x * 256 + tid;           // float4 index over M*16
  int jq = i & 15;
  float2 pr = reinterpret_cast<const float2*>(EoutF)[((size_t)(i >> 4)) * 32 + jq];
  unsigned u0 = __float_as_uint(pr.x);
  unsigned u1 = __float_as_uint(pr.y);
  float v0 = bflo(u0), v1 = bfhi(u0), v2 = bflo(u1), v3 = bfhi(u1);
  float4 eg = reinterpret_cast<const float4*>(Eg)[i];
  int j = jq * 4;
  float4 o;
  o.x = leaky(fmaf(v0, scs[j + 0], scs[64 + j + 0])) + eg.x;
  o.y = leaky(fmaf(v1, scs[j + 1], scs[64 + j + 1])) + eg.y;
  o.z = leaky(fmaf(v2, scs[j + 2], scs[64 + j + 2])) + eg.z;
  o.w = leaky(fmaf(v3, scs[j + 3], scs[64 + j + 3])) + eg.w;
  reinterpret_cast<float4*>(EoutF)[i] = o;
}

extern "C" void kernel_launch(void* const* d_in, const int* in_sizes, int n_in,
                              void* d_out, int out_size, void* d_ws, size_t ws_size,
                              hipStream_t stream) {
  const float* V      = (const float*)d_in[0];
  const float* Eg     = (const float*)d_in[1];
  const int*   src    = (const int*)d_in[2];
  const int*   dst    = (const int*)d_in[3];
  const float* W_ops  = (const float*)d_in[4];
  const float* b_ops  = (const float*)d_in[5];
  const float* W_cat  = (const float*)d_in[6];
  const float* b_cat  = (const float*)d_in[7];
  const float* W_S    = (const float*)d_in[8];
  const float* b_S    = (const float*)d_in[9];
  const float* gammaV = (const float*)d_in[10];
  const float* betaV  = (const float*)d_in[11];
  const float* gammaE = (const float*)d_in[12];
  const float* betaE  = (const float*)d_in[13];

  float* ws = (float*)d_ws;
  const size_t ND = (size_t)N_NODES * 64;
  const size_t NH = (size_t)N_NODES * 32;   // packed row units
  unsigned* Vb  = (unsigned*)ws;
  unsigned* Ab  = (unsigned*)ws + NH;
  unsigned* Cb  = (unsigned*)ws + 2 * NH;
  unsigned* PsP = (unsigned*)ws + 3 * NH;
  unsigned* PdP = (unsigned*)ws + 4 * NH;
  float* xb   = ws + 5 * NH;
  float* W12g  = xb;
  float* Wc12g = xb + 4096;
  float* WAg   = xb + 8192;
  float* WBg   = xb + 12288;
  float* W0Bg  = xb + 16384;
  float* cg    = xb + 20480;
  float* b0Bg  = xb + 20544;
  float* statsV = xb + 20608;
  float* statsE = statsV + 128;
  float* scshV  = statsV + 256;
  float* scshE  = statsV + 384;
  int* counts = (int*)(statsV + 512);
  int* offs   = counts + N_NODES;
  int* cursor = offs + N_NODES + 1;
  int* ssrc   = cursor + N_NODES;
  float* partials = (float*)(ssrc + M_EDGES);   // NEBLK*128 floats

  float* Vout  = (float*)d_out;
  float* EoutF = Vout + ND;                      // E region (slots)
  unsigned* EoutSlots = (unsigned*)EoutF;

  hipMemsetAsync(counts, 0, N_NODES * sizeof(int), stream);
  hipMemsetAsync(statsV, 0, 256 * sizeof(float), stream);

  const int eb = (M_EDGES + 255) / 256;
  const int rb = (N_NODES + 255) / 256;
  prep1_k<<<2, 256, 0, stream>>>(W_ops, W_cat, W12g, Wc12g);
  prep2_k<<<2, 256, 0, stream>>>(W_ops, b_ops, W_cat, b_cat, W12g, Wc12g, WAg, WBg, cg);
  prep3_k<<<1, 256, 0, stream>>>(W_ops, b_ops, WBg, W0Bg, b0Bg);
  hist_k<<<eb, 256, 0, stream>>>(dst, counts);
  scan_k<<<1, 256, 0, stream>>>(counts, offs, cursor);
  fill_k<<<eb, 256, 0, stream>>>(src, dst, cursor, ssrc);

  convbf_k<<<(N_NODES * 8 + 255) / 256, 256, 0, stream>>>(V, Vb, N_NODES * 8);
  gatherb_k<<<N_NODES / 4, 256, 0, stream>>>(Vb, offs, ssrc, Ab);
  gatherb_k<<<N_NODES / 4, 256, 0, stream>>>(Ab, offs, ssrc, Cb);
  vnew_k<<<rb, 256, 0, stream>>>(Ab, Cb, counts, WAg, W0Bg, cg, b0Bg, Vout);
  proj_k<<<rb, 256, 0, stream>>>(Vout, W_S, b_S, PsP, PdP);
  edge_k<<<NEBLK, 256, 0, stream>>>(Eg, src, dst, PsP, PdP, W_S, EoutSlots, partials);
  reduce_stats_k<<<64, 256, 0, stream>>>(partials, statsE);
  col_stats_k<<<512, 256, 0, stream>>>(Vout, ND, statsV);
  finalize_k<<<1, 64, 0, stream>>>(statsV, 1.f / N_NODES, gammaV, betaV, scshV);
  finalize_k<<<1, 64, 0, stream>>>(statsE, 1.f / M_EDGES, gammaE, betaE, scshE);
  bn_apply_k<<<(int)((ND / 4 + 255) / 256), 256, 0, stream>>>(Vout, V, scshV, (int)(ND / 4));
  bn_applyE_k<<<M_EDGES * 16 / 256, 256, 0, stream>>>(EoutF, Eg, scshE);
}

// Round 12
// 730.889 us; speedup vs baseline: 1.2435x; 1.1072x over previous
//
#include <hip/hip_runtime.h>
#include <hip/hip_bf16.h>

#define N_NODES 50000
#define M_EDGES 800000
#define LEAKY_F 0.2f
#define BN_EPS 1e-5f
#define NEBLK (M_EDGES / 64)

typedef short bf16x8 __attribute__((ext_vector_type(8)));
typedef float f32x4 __attribute__((ext_vector_type(4)));

__device__ __forceinline__ float leaky(float x) { return x >= 0.f ? x : LEAKY_F * x; }

// round-to-nearest-even f32 -> bf16 (finite inputs)
__device__ __forceinline__ unsigned f2bf(float f) {
  unsigned u = __float_as_uint(f);
  return (u + 0x7fffu + ((u >> 16) & 1u)) >> 16;
}
__device__ __forceinline__ unsigned packbf(float a, float b) {
  return (f2bf(b) << 16) | f2bf(a);
}
__device__ __forceinline__ float bflo(unsigned u) { return __uint_as_float(u << 16); }
__device__ __forceinline__ float bfhi(unsigned u) { return __uint_as_float(u & 0xffff0000u); }

// ================= CSR build =================
__global__ __launch_bounds__(256) void hist_k(const int* __restrict__ dst,
                                              int* __restrict__ counts) {
  int e = blockIdx.x * 256 + threadIdx.x;
  if (e < M_EDGES) atomicAdd(&counts[dst[e]], 1);
}

__global__ __launch_bounds__(256) void scan_k(const int* __restrict__ counts,
                                              int* __restrict__ offs,
                                              int* __restrict__ cursor) {
  __shared__ int chunk[256];
  const int CH = (N_NODES + 255) / 256;
  int tid = threadIdx.x;
  int beg = tid * CH, end = min(beg + CH, N_NODES);
  int s = 0;
  for (int i = beg; i < end; ++i) s += counts[i];
  chunk[tid] = s;
  __syncthreads();
  if (tid == 0) {
    int run = 0;
    for (int i = 0; i < 256; ++i) { int c = chunk[i]; chunk[i] = run; run += c; }
  }
  __syncthreads();
  int base = chunk[tid];
  for (int i = beg; i < end; ++i) {
    offs[i] = base;
    cursor[i] = base;
    base += counts[i];
  }
  if (tid == 0) offs[N_NODES] = M_EDGES;
}

__global__ __launch_bounds__(256) void fill_k(const int* __restrict__ src,
                                              const int* __restrict__ dst,
                                              int* __restrict__ cursor,
                                              int* __restrict__ ssrc) {
  int e = blockIdx.x * 256 + threadIdx.x;
  if (e >= M_EDGES) return;
  int p = atomicAdd(&cursor[dst[e]], 1);
  ssrc[p] = src[e];
}

// ---- f32 rows -> packed bf16 rows ----
__global__ __launch_bounds__(256) void convbf_k(const float* __restrict__ X,
                                                unsigned* __restrict__ Xb, int n4) {
  int i = blockIdx.x * 256 + threadIdx.x;
  if (i >= n4) return;
  const float4* s4 = reinterpret_cast<const float4*>(X) + (size_t)i * 2;
  float4 a = s4[0], b = s4[1];
  uint4 o;
  o.x = packbf(a.x, a.y);
  o.y = packbf(a.z, a.w);
  o.z = packbf(b.x, b.y);
  o.w = packbf(b.z, b.w);
  reinterpret_cast<uint4*>(Xb)[i] = o;
}

// ---- segment gather-sum over packed-bf16 rows; wave per node, half-wave per edge ----
__global__ __launch_bounds__(256) void gatherb_k(const unsigned* __restrict__ Xb,
                                                 const int* __restrict__ offs,
                                                 const int* __restrict__ ssrc,
                                                 unsigned* __restrict__ Ob) {
  int n = blockIdx.x * 4 + (threadIdx.x >> 6);
  int lane = threadIdx.x & 63;
  int half = lane >> 5, col = lane & 31;
  int beg = offs[n], end = offs[n + 1];
  float a0 = 0.f, a1 = 0.f;
  for (int i = beg + half; i < end; i += 2) {
    unsigned u = Xb[(size_t)ssrc[i] * 32 + col];
    a0 += bflo(u);
    a1 += bfhi(u);
  }
  a0 += __shfl_xor(a0, 32);
  a1 += __shfl_xor(a1, 32);
  if (half == 0) Ob[(size_t)n * 32 + col] = packbf(a0, a1);
}

// ================= weight-prep (algebraic collapse) =================
__global__ __launch_bounds__(256) void prep1_k(const float* __restrict__ W_ops,
                                               const float* __restrict__ W_cat,
                                               float* __restrict__ W12g,
                                               float* __restrict__ Wc12g) {
  __shared__ float Wa[4096], Wb[4096];
  int tid = threadIdx.x;
  const float *Am, *Bm, *Add;
  float* Out;
  if (blockIdx.x == 0) { Am = W_ops; Bm = W_ops + 8192; Add = W_ops + 4096; Out = W12g; }
  else { Am = W_ops + 16384; Bm = W_cat + 8192; Add = W_cat + 4096; Out = Wc12g; }
  for (int i = tid; i < 4096; i += 256) { Wa[i] = Am[i]; Wb[i] = Bm[i]; }
  __syncthreads();
  for (int t = 0; t < 16; ++t) {
    int o = tid + t * 256;
    int r = o >> 6, j = o & 63;
    float acc = Add[o];
#pragma unroll
    for (int k = 0; k < 64; ++k) acc = fmaf(Wa[r * 64 + k], Wb[k * 64 + j], acc);
    Out[o] = acc;
  }
}

__global__ __launch_bounds__(256) void prep2_k(const float* __restrict__ W_ops,
                                               const float* __restrict__ b_ops,
                                               const float* __restrict__ W_cat,
                                               const float* __restrict__ b_cat,
                                               const float* __restrict__ W12g,
                                               const float* __restrict__ Wc12g,
                                               float* __restrict__ WAg,
                                               float* __restrict__ WBg,
                                               float* __restrict__ cg) {
  __shared__ float M0[4096], M1[4096], M2[4096], M3[4096], M4[4096];
  __shared__ float bb[64];
  int tid = threadIdx.x;
  if (blockIdx.x == 0) {
    for (int i = tid; i < 4096; i += 256) {
      M0[i] = W_ops[i];
      M1[i] = W_cat[i];
      M2[i] = W12g[i];
      M3[i] = Wc12g[i];
    }
    __syncthreads();
    for (int t = 0; t < 16; ++t) {
      int o = tid + t * 256;
      int r = o >> 6, j = o & 63;
      float acc = 0.f;
#pragma unroll
      for (int k = 0; k < 64; ++k) {
        acc = fmaf(M0[r * 64 + k], M1[k * 64 + j], acc);
        acc = fmaf(M2[r * 64 + k], M3[k * 64 + j], acc);
      }
      WAg[o] = acc;
    }
  } else {
    for (int i = tid; i < 4096; i += 256) {
      M0[i] = W_ops[3 * 4096 + i];
      M1[i] = W_cat[8192 + i];
      M2[i] = W_ops[2 * 4096 + i];
      M3[i] = W_cat[i];
      M4[i] = Wc12g[i];
    }
    __syncthreads();
    for (int t = 0; t < 16; ++t) {
      int o = tid + t * 256;
      int r = o >> 6, j = o & 63;
      float acc = 0.f;
#pragma unroll
      for (int k = 0; k < 64; ++k) acc = fmaf(M0[r * 64 + k], M1[k * 64 + j], acc);
      WBg[o] = acc;
    }
    if (tid < 64) {
      int j = tid;
      float acc = b_ops[64 + j] + b_ops[128 + j];
#pragma unroll
      for (int k = 0; k < 64; ++k) acc = fmaf(b_ops[k], M2[k * 64 + j], acc);
      bb[j] = acc;
    }
    __syncthreads();
    if (tid < 64) {
      int j = tid;
      float acc = b_cat[j];
#pragma unroll
      for (int k = 0; k < 64; ++k) {
        acc = fmaf(b_ops[k], M3[k * 64 + j], acc);
        acc = fmaf(bb[k], M4[k * 64 + j], acc);
        acc = fmaf(b_ops[192 + k] + b_ops[256 + k], M1[k * 64 + j], acc);
      }
      cg[j] = acc;
    }
  }
}

// prep3: W0B = W0@WB ; b0B = b0@WB
__global__ __launch_bounds__(256) void prep3_k(const float* __restrict__ W_ops,
                                               const float* __restrict__ b_ops,
                                               const float* __restrict__ WBg,
                                               float* __restrict__ W0Bg,
                                               float* __restrict__ b0Bg) {
  __shared__ float Wa[4096], Wb[4096];
  int tid = threadIdx.x;
  for (int i = tid; i < 4096; i += 256) { Wa[i] = W_ops[i]; Wb[i] = WBg[i]; }
  __syncthreads();
  for (int t = 0; t < 16; ++t) {
    int o = tid + t * 256;
    int r = o >> 6, j = o & 63;
    float acc = 0.f;
#pragma unroll
    for (int k = 0; k < 64; ++k) acc = fmaf(Wa[r * 64 + k], Wb[k * 64 + j], acc);
    W0Bg[o] = acc;
  }
  if (tid < 64) {
    float acc = 0.f;
#pragma unroll
    for (int k = 0; k < 64; ++k) acc = fmaf(b_ops[k], Wb[k * 64 + tid], acc);
    b0Bg[tid] = acc;
  }
}

// Vnew = A@WA + C@W0B + deg*b0B + c, then Ps/Pd = Vnew@{Ws0,Ws2} fused
// (grid is only ~196 blocks on 256 CUs -> big LDS is free)
__global__ __launch_bounds__(256) void vnewproj_k(
    const unsigned* __restrict__ Ab, const unsigned* __restrict__ Cb,
    const int* __restrict__ counts,
    const float* __restrict__ WAg, const float* __restrict__ W0Bg,
    const float* __restrict__ cg, const float* __restrict__ b0Bg,
    const float* __restrict__ W_S, const float* __restrict__ b_S,
    float* __restrict__ Vnew, unsigned* __restrict__ PsP, unsigned* __restrict__ PdP) {
  __shared__ float WA[4096], WB[4096], W0s[4096], W2s[4096];
  __shared__ float cb[64], b0v[64], bias[64];
  int tid = threadIdx.x;
  for (int i = tid; i < 4096; i += 256) {
    WA[i] = WAg[i];
    WB[i] = W0Bg[i];
    W0s[i] = W_S[i];
    W2s[i] = W_S[8192 + i];
  }
  if (tid < 64) { cb[tid] = cg[tid]; b0v[tid] = b0Bg[tid]; bias[tid] = b_S[tid]; }
  __syncthreads();
  int r = blockIdx.x * 256 + tid;
  if (r >= N_NODES) return;
  {
    float xa[64], xc[64];
    const uint4* Ar = reinterpret_cast<const uint4*>(Ab + (size_t)r * 32);
    const uint4* Cr = reinterpret_cast<const uint4*>(Cb + (size_t)r * 32);
#pragma unroll
    for (int q = 0; q < 8; ++q) {
      uint4 ua = Ar[q];
      xa[q * 8 + 0] = bflo(ua.x); xa[q * 8 + 1] = bfhi(ua.x);
      xa[q * 8 + 2] = bflo(ua.y); xa[q * 8 + 3] = bfhi(ua.y);
      xa[q * 8 + 4] = bflo(ua.z); xa[q * 8 + 5] = bfhi(ua.z);
      xa[q * 8 + 6] = bflo(ua.w); xa[q * 8 + 7] = bfhi(ua.w);
      uint4 uc = Cr[q];
      xc[q * 8 + 0] = bflo(uc.x); xc[q * 8 + 1] = bfhi(uc.x);
      xc[q * 8 + 2] = bflo(uc.y); xc[q * 8 + 3] = bfhi(uc.y);
      xc[q * 8 + 4] = bflo(uc.z); xc[q * 8 + 5] = bfhi(uc.z);
      xc[q * 8 + 6] = bflo(uc.w); xc[q * 8 + 7] = bfhi(uc.w);
    }
    float deg = (float)counts[r];
    float4* Or = reinterpret_cast<float4*>(Vnew + (size_t)r * 64);
    for (int j0 = 0; j0 < 64; j0 += 4) {
      float a0 = fmaf(deg, b0v[j0], cb[j0]);
      float a1 = fmaf(deg, b0v[j0 + 1], cb[j0 + 1]);
      float a2 = fmaf(deg, b0v[j0 + 2], cb[j0 + 2]);
      float a3 = fmaf(deg, b0v[j0 + 3], cb[j0 + 3]);
#pragma unroll
      for (int k = 0; k < 64; ++k) {
        float4 wa = *reinterpret_cast<const float4*>(&WA[k * 64 + j0]);
        a0 = fmaf(xa[k], wa.x, a0);
        a1 = fmaf(xa[k], wa.y, a1);
        a2 = fmaf(xa[k], wa.z, a2);
        a3 = fmaf(xa[k], wa.w, a3);
        float4 wb = *reinterpret_cast<const float4*>(&WB[k * 64 + j0]);
        a0 = fmaf(xc[k], wb.x, a0);
        a1 = fmaf(xc[k], wb.y, a1);
        a2 = fmaf(xc[k], wb.z, a2);
        a3 = fmaf(xc[k], wb.w, a3);
      }
      Or[j0 >> 2] = make_float4(a0, a1, a2, a3);
    }
  }
  // phase 2: reload own row (L2-hot) and project
  {
    float x[64];
    const float4* Xr = reinterpret_cast<const float4*>(Vnew + (size_t)r * 64);
#pragma unroll
    for (int q = 0; q < 16; ++q) {
      float4 v = Xr[q];
      x[q * 4] = v.x; x[q * 4 + 1] = v.y; x[q * 4 + 2] = v.z; x[q * 4 + 3] = v.w;
    }
    for (int j0 = 0; j0 < 64; j0 += 4) {
      float a0 = bias[j0], a1 = bias[j0 + 1], a2 = bias[j0 + 2], a3 = bias[j0 + 3];
      float d0 = 0.f, d1 = 0.f, d2 = 0.f, d3 = 0.f;
#pragma unroll
      for (int k = 0; k < 64; ++k) {
        float xk = x[k];
        float4 w = *reinterpret_cast<const float4*>(&W0s[k * 64 + j0]);
        a0 = fmaf(xk, w.x, a0);
        a1 = fmaf(xk, w.y, a1);
        a2 = fmaf(xk, w.z, a2);
        a3 = fmaf(xk, w.w, a3);
        float4 u = *reinterpret_cast<const float4*>(&W2s[k * 64 + j0]);
        d0 = fmaf(xk, u.x, d0);
        d1 = fmaf(xk, u.y, d1);
        d2 = fmaf(xk, u.z, d2);
        d3 = fmaf(xk, u.w, d3);
      }
      uint2 ps = make_uint2(packbf(a0, a1), packbf(a2, a3));
      uint2 pd = make_uint2(packbf(d0, d1), packbf(d2, d3));
      *reinterpret_cast<uint2*>(&PsP[(size_t)r * 32 + (j0 >> 1)]) = ps;
      *reinterpret_cast<uint2*>(&PdP[(size_t)r * 32 + (j0 >> 1)]) = pd;
    }
  }
}

// ---- edge, MFMA version: E@Wmid on matrix cores (16x16x32 bf16),
// fragment-order LDS staging, Spd add + stats + bf16 slot store ----
__global__ __launch_bounds__(256) void edge_k(
    const float* __restrict__ Eg, const int* __restrict__ src, const int* __restrict__ dst,
    const unsigned* __restrict__ PsP, const unsigned* __restrict__ PdP,
    const float* __restrict__ W_S, unsigned* __restrict__ EoutSlots,
    float* __restrict__ partials) {
  __shared__ unsigned WtF[2048];     // B-frags: ((jt*2+kh)*64 + lane)*4 + ui
  __shared__ unsigned EaF[2048];     // A-frags: ((et*2+kh)*64 + lane)*4 + ui
  __shared__ unsigned Spd[64][34];   // bf16 pairs of Ps[src]+Pd[dst]
  __shared__ float ls[128];
  int tid = threadIdx.x;
  int e0 = blockIdx.x * 64;
  int l16 = tid & 15, g16 = tid >> 4;

  // phase A: issue gather row-loads into regs (latency overlaps staging)
  uint2 pa[4], pb[4];
#pragma unroll
  for (int rr = 0; rr < 4; ++rr) {
    int p = e0 + rr * 16 + g16;
    int s = src[p], d = dst[p];
    pa[rr] = *reinterpret_cast<const uint2*>(&PsP[(size_t)s * 32 + 2 * l16]);
    pb[rr] = *reinterpret_cast<const uint2*>(&PdP[(size_t)d * 32 + 2 * l16]);
  }
  // stage W as B-operand fragments (lane = col16 + 16*kgroup, 8 k-contig bf16)
  for (int q = tid; q < 2048; q += 256) {
    int j = q & 63, k2 = q >> 6;                 // k2 = k/2 in [0,32)
    float w0 = W_S[4096 + (2 * k2) * 64 + j];
    float w1 = W_S[4096 + (2 * k2 + 1) * 64 + j];
    int kh = k2 >> 4, k2h = k2 & 15;
    int lane = (j & 15) + 16 * (k2h >> 2);
    WtF[((((j >> 4) << 1) + kh) * 64 + lane) * 4 + (k2h & 3)] = packbf(w0, w1);
  }
  if (tid < 128) ls[tid] = 0.f;
  // stage leaky(E) as A-operand fragments
  for (int q = tid; q < 1024; q += 256) {
    int e = q >> 4, kq = q & 15;
    float4 vv = reinterpret_cast<const float4*>(Eg)[(size_t)(e0 + e) * 16 + kq];
    unsigned u0 = packbf(leaky(vv.x), leaky(vv.y));
    unsigned u1 = packbf(leaky(vv.z), leaky(vv.w));
    int k2a = 2 * kq;
    int kh = k2a >> 4, k2h = k2a & 15;           // k2h even -> ui in {0,2}
    int lane = (e & 15) + 16 * (k2h >> 2);
    int base = ((((e >> 4) << 1) + kh) * 64 + lane) * 4 + (k2h & 3);
    EaF[base] = u0;
    EaF[base + 1] = u1;
  }
  // Spd = Ps[src]+Pd[dst] (f32 add, bf16 store)
#pragma unroll
  for (int rr = 0; rr < 4; ++rr) {
    int r = rr * 16 + g16;
    float fx = bflo(pa[rr].x) + bflo(pb[rr].x);
    float fy = bfhi(pa[rr].x) + bfhi(pb[rr].x);
    float fz = bflo(pa[rr].y) + bflo(pb[rr].y);
    float fw = bfhi(pa[rr].y) + bfhi(pb[rr].y);
    *reinterpret_cast<uint2*>(&Spd[r][l16 * 2]) = make_uint2(packbf(fx, fy), packbf(fz, fw));
  }
  __syncthreads();

  int lane = tid & 63;
  int et = tid >> 6;                              // wave id = e-tile
  f32x4 acc0 = {0.f, 0.f, 0.f, 0.f};
  f32x4 acc1 = {0.f, 0.f, 0.f, 0.f};
  f32x4 acc2 = {0.f, 0.f, 0.f, 0.f};
  f32x4 acc3 = {0.f, 0.f, 0.f, 0.f};
#pragma unroll
  for (int kh = 0; kh < 2; ++kh) {
    uint4 au = *reinterpret_cast<const uint4*>(&EaF[(((et << 1) + kh) * 64 + lane) * 4]);
    bf16x8 afr = *reinterpret_cast<bf16x8*>(&au);
    uint4 b0 = *reinterpret_cast<const uint4*>(&WtF[((0 * 2 + kh) * 64 + lane) * 4]);
    uint4 b1 = *reinterpret_cast<const uint4*>(&WtF[((1 * 2 + kh) * 64 + lane) * 4]);
    uint4 b2 = *reinterpret_cast<const uint4*>(&WtF[((2 * 2 + kh) * 64 + lane) * 4]);
    uint4 b3 = *reinterpret_cast<const uint4*>(&WtF[((3 * 2 + kh) * 64 + lane) * 4]);
    acc0 = __builtin_amdgcn_mfma_f32_16x16x32_bf16(afr, *reinterpret_cast<bf16x8*>(&b0), acc0, 0, 0, 0);
    acc1 = __builtin_amdgcn_mfma_f32_16x16x32_bf16(afr, *reinterpret_cast<bf16x8*>(&b1), acc1, 0, 0, 0);
    acc2 = __builtin_amdgcn_mfma_f32_16x16x32_bf16(afr, *reinterpret_cast<bf16x8*>(&b2), acc2, 0, 0, 0);
    acc3 = __builtin_amdgcn_mfma_f32_16x16x32_bf16(afr, *reinterpret_cast<bf16x8*>(&b3), acc3, 0, 0, 0);
  }

  // C layout: col = lane&15, row(e within tile) = (lane>>4)*4 + reg  [m89]
  int col15 = lane & 15, g4 = lane >> 4;
  float s4[4] = {0.f, 0.f, 0.f, 0.f}, q4[4] = {0.f, 0.f, 0.f, 0.f};
  f32x4 accs[4];
#pragma unroll
  for (int jt = 0; jt < 4; ++jt) {
    f32x4 a = (jt == 0) ? acc0 : (jt == 1) ? acc1 : (jt == 2) ? acc2 : acc3;
#pragma unroll
    for (int reg = 0; reg < 4; ++reg) {
      int e = et * 16 + g4 * 4 + reg;
      int j = jt * 16 + col15;
      unsigned sp = Spd[e][j >> 1];
      float add = (j & 1) ? bfhi(sp) : bflo(sp);
      float v = a[reg] + add;
      a[reg] = v;
      s4[jt] += v;
      q4[jt] = fmaf(v, v, q4[jt]);
    }
    accs[jt] = a;
  }
  // pack bf16 pairs via shfl_xor(1) (partner holds adjacent column), store
#pragma unroll
  for (int jt = 0; jt < 4; ++jt) {
#pragma unroll
    for (int reg = 0; reg < 4; ++reg) {
      float v = accs[jt][reg];
      float pv = __shfl_xor(v, 1);
      if (!(col15 & 1)) {
        int e = e0 + et * 16 + g4 * 4 + reg;
        EoutSlots[(size_t)e * 64 + jt * 8 + (col15 >> 1)] = packbf(v, pv);
      }
    }
  }
  // stats: reduce over the 4 lanes sharing a column (xor 16, 32)
#pragma unroll
  for (int jt = 0; jt < 4; ++jt) {
    s4[jt] += __shfl_xor(s4[jt], 16);
    q4[jt] += __shfl_xor(q4[jt], 16);
    s4[jt] += __shfl_xor(s4[jt], 32);
    q4[jt] += __shfl_xor(q4[jt], 32);
  }
  if (g4 == 0) {
#pragma unroll
    for (int jt = 0; jt < 4; ++jt) {
      atomicAdd(&ls[jt * 16 + col15], s4[jt]);
      atomicAdd(&ls[64 + jt * 16 + col15], q4[jt]);
    }
  }
  __syncthreads();
  if (tid < 128) partials[(size_t)blockIdx.x * 128 + tid] = ls[tid];
}

// ---- reduce per-block partials [NEBLK][128] -> stats[128] ----
__global__ __launch_bounds__(256) void reduce_stats_k(const float* __restrict__ partials,
                                                      float* __restrict__ stats) {
  __shared__ float ls[128];
  int tid = threadIdx.x;
  if (tid < 128) ls[tid] = 0.f;
  __syncthreads();
  int c = tid & 127;
  int half = tid >> 7;
  float s = 0.f;
  for (int r = blockIdx.x * 2 + half; r < NEBLK; r += 2 * gridDim.x) {
    s += partials[(size_t)r * 128 + c];
  }
  atomicAdd(&ls[c], s);
  __syncthreads();
  if (tid < 128) atomicAdd(&stats[tid], ls[tid]);
}

// ---- per-column sum / sumsq (for V side) ----
__global__ __launch_bounds__(256) void col_stats_k(
    const float* __restrict__ X, size_t nelem, float* __restrict__ sums) {
  __shared__ float ls[128];
  int tid = threadIdx.x;
  if (tid < 128) ls[tid] = 0.f;
  __syncthreads();
  int j = tid & 63;
  float s = 0.f, ss = 0.f;
  size_t stride = (size_t)gridDim.x * blockDim.x;
  for (size_t i = (size_t)blockIdx.x * blockDim.x + tid; i < nelem; i += stride) {
    float x = X[i];
    s += x;
    ss = fmaf(x, x, ss);
  }
  atomicAdd(&ls[j], s);
  atomicAdd(&ls[64 + j], ss);
  __syncthreads();
  if (tid < 128) atomicAdd(&sums[tid], ls[tid]);
}

__global__ void finalize_k(const float* __restrict__ sums, float inv_n,
                           const float* __restrict__ gamma, const float* __restrict__ beta,
                           float* __restrict__ sc_shift) {
  int j = threadIdx.x;
  float mu = sums[j] * inv_n;
  float var = sums[64 + j] * inv_n - mu * mu;
  float sc = gamma[j] * rsqrtf(var + BN_EPS);
  sc_shift[j] = sc;
  sc_shift[64 + j] = beta[j] - mu * sc;
}

// ---- V side: in-place f32 bn+leaky+residual ----
__global__ __launch_bounds__(256) void bn_apply_k(
    float* __restrict__ X, const float* __restrict__ resid,
    const float* __restrict__ sc_shift, int n4) {
  int i = blockIdx.x * blockDim.x + threadIdx.x;
  if (i >= n4) return;
  int jq = i & 15;
  float4 x = reinterpret_cast<float4*>(X)[i];
  float4 r = reinterpret_cast<const float4*>(resid)[i];
  float4 sc = reinterpret_cast<const float4*>(sc_shift)[jq];
  float4 sh = reinterpret_cast<const float4*>(sc_shift + 64)[jq];
  float4 y;
  y.x = leaky(fmaf(x.x, sc.x, sh.x)) + r.x;
  y.y = leaky(fmaf(x.y, sc.y, sh.y)) + r.y;
  y.z = leaky(fmaf(x.z, sc.z, sh.z)) + r.z;
  y.w = leaky(fmaf(x.w, sc.w, sh.w)) + r.w;
  reinterpret_cast<float4*>(X)[i] = y;
}

// ---- E side, coalesced float4-per-thread slot expansion ----
__global__ __launch_bounds__(256) void bn_applyE_k(
    float* __restrict__ EoutF, const float* __restrict__ Eg,
    const float* __restrict__ sc_shift) {
  __shared__ float scs[128];
  int tid = threadIdx.x;
  if (tid < 128) scs[tid] = sc_shift[tid];
  __syncthreads();
  int i = blockIdx.x * 256 + tid;
  int jq = i & 15;
  float2 pr = reinterpret_cast<const float2*>(EoutF)[((size_t)(i >> 4)) * 32 + jq];
  unsigned u0 = __float_as_uint(pr.x);
  unsigned u1 = __float_as_uint(pr.y);
  float v0 = bflo(u0), v1 = bfhi(u0), v2 = bflo(u1), v3 = bfhi(u1);
  float4 eg = reinterpret_cast<const float4*>(Eg)[i];
  int j = jq * 4;
  float4 o;
  o.x = leaky(fmaf(v0, scs[j + 0], scs[64 + j + 0])) + eg.x;
  o.y = leaky(fmaf(v1, scs[j + 1], scs[64 + j + 1])) + eg.y;
  o.z = leaky(fmaf(v2, scs[j + 2], scs[64 + j + 2])) + eg.z;
  o.w = leaky(fmaf(v3, scs[j + 3], scs[64 + j + 3])) + eg.w;
  reinterpret_cast<float4*>(EoutF)[i] = o;
}

extern "C" void kernel_launch(void* const* d_in, const int* in_sizes, int n_in,
                              void* d_out, int out_size, void* d_ws, size_t ws_size,
                              hipStream_t stream) {
  const float* V      = (const float*)d_in[0];
  const float* Eg     = (const float*)d_in[1];
  const int*   src    = (const int*)d_in[2];
  const int*   dst    = (const int*)d_in[3];
  const float* W_ops  = (const float*)d_in[4];
  const float* b_ops  = (const float*)d_in[5];
  const float* W_cat  = (const float*)d_in[6];
  const float* b_cat  = (const float*)d_in[7];
  const float* W_S    = (const float*)d_in[8];
  const float* b_S    = (const float*)d_in[9];
  const float* gammaV = (const float*)d_in[10];
  const float* betaV  = (const float*)d_in[11];
  const float* gammaE = (const float*)d_in[12];
  const float* betaE  = (const float*)d_in[13];

  float* ws = (float*)d_ws;
  const size_t ND = (size_t)N_NODES * 64;
  const size_t NH = (size_t)N_NODES * 32;
  unsigned* Vb  = (unsigned*)ws;
  unsigned* Ab  = (unsigned*)ws + NH;
  unsigned* Cb  = (unsigned*)ws + 2 * NH;
  unsigned* PsP = (unsigned*)ws + 3 * NH;
  unsigned* PdP = (unsigned*)ws + 4 * NH;
  float* xb   = ws + 5 * NH;
  float* W12g  = xb;
  float* Wc12g = xb + 4096;
  float* WAg   = xb + 8192;
  float* WBg   = xb + 12288;
  float* W0Bg  = xb + 16384;
  float* cg    = xb + 20480;
  float* b0Bg  = xb + 20544;
  float* statsV = xb + 20608;
  float* statsE = statsV + 128;
  float* scshV  = statsV + 256;
  float* scshE  = statsV + 384;
  int* counts = (int*)(statsV + 512);
  int* offs   = counts + N_NODES;
  int* cursor = offs + N_NODES + 1;
  int* ssrc   = cursor + N_NODES;
  float* partials = (float*)(ssrc + M_EDGES);

  float* Vout  = (float*)d_out;
  float* EoutF = Vout + ND;
  unsigned* EoutSlots = (unsigned*)EoutF;

  hipMemsetAsync(counts, 0, N_NODES * sizeof(int), stream);
  hipMemsetAsync(statsV, 0, 256 * sizeof(float), stream);

  const int eb = (M_EDGES + 255) / 256;
  const int rb = (N_NODES + 255) / 256;
  prep1_k<<<2, 256, 0, stream>>>(W_ops, W_cat, W12g, Wc12g);
  prep2_k<<<2, 256, 0, stream>>>(W_ops, b_ops, W_cat, b_cat, W12g, Wc12g, WAg, WBg, cg);
  prep3_k<<<1, 256, 0, stream>>>(W_ops, b_ops, WBg, W0Bg, b0Bg);
  hist_k<<<eb, 256, 0, stream>>>(dst, counts);
  scan_k<<<1, 256, 0, stream>>>(counts, offs, cursor);
  fill_k<<<eb, 256, 0, stream>>>(src, dst, cursor, ssrc);

  convbf_k<<<(N_NODES * 8 + 255) / 256, 256, 0, stream>>>(V, Vb, N_NODES * 8);
  gatherb_k<<<N_NODES / 4, 256, 0, stream>>>(Vb, offs, ssrc, Ab);
  gatherb_k<<<N_NODES / 4, 256, 0, stream>>>(Ab, offs, ssrc, Cb);
  vnewproj_k<<<rb, 256, 0, stream>>>(Ab, Cb, counts, WAg, W0Bg, cg, b0Bg,
                                     W_S, b_S, Vout, PsP, PdP);
  edge_k<<<NEBLK, 256, 0, stream>>>(Eg, src, dst, PsP, PdP, W_S, EoutSlots, partials);
  reduce_stats_k<<<64, 256, 0, stream>>>(partials, statsE);
  col_stats_k<<<512, 256, 0, stream>>>(Vout, ND, statsV);
  finalize_k<<<1, 64, 0, stream>>>(statsV, 1.f / N_NODES, gammaV, betaV, scshV);
  finalize_k<<<1, 64, 0, stream>>>(statsE, 1.f / M_EDGES, gammaE, betaE, scshE);
  bn_apply_k<<<(int)((ND / 4 + 255) / 256), 256, 0, stream>>>(Vout, V, scshV, (int)(ND / 4));
  bn_applyE_k<<<M_EDGES * 16 / 256, 256, 0, stream>>>(EoutF, Eg, scshE);
}

// Round 13
// 590.574 us; speedup vs baseline: 1.5389x; 1.2376x over previous
//
#include <hip/hip_runtime.h>
#include <hip/hip_bf16.h>

#define N_NODES 50000
#define M_EDGES 800000
#define LEAKY_F 0.2f
#define BN_EPS 1e-5f
#define NEBLK (M_EDGES / 64)
#define NVBLK ((N_NODES + 63) / 64)

typedef short bf16x8 __attribute__((ext_vector_type(8)));
typedef float f32x4 __attribute__((ext_vector_type(4)));

__device__ __forceinline__ float leaky(float x) { return x >= 0.f ? x : LEAKY_F * x; }

__device__ __forceinline__ unsigned f2bf(float f) {
  unsigned u = __float_as_uint(f);
  return (u + 0x7fffu + ((u >> 16) & 1u)) >> 16;
}
__device__ __forceinline__ unsigned packbf(float a, float b) {
  return (f2bf(b) << 16) | f2bf(a);
}
__device__ __forceinline__ float bflo(unsigned u) { return __uint_as_float(u << 16); }
__device__ __forceinline__ float bfhi(unsigned u) { return __uint_as_float(u & 0xffff0000u); }

// ================= CSR build =================
__global__ __launch_bounds__(256) void hist_k(const int* __restrict__ dst,
                                              int* __restrict__ counts) {
  int e = blockIdx.x * 256 + threadIdx.x;
  if (e < M_EDGES) atomicAdd(&counts[dst[e]], 1);
}

__global__ __launch_bounds__(256) void scan_k(const int* __restrict__ counts,
                                              int* __restrict__ offs,
                                              int* __restrict__ cursor) {
  __shared__ int chunk[256];
  const int CH = (N_NODES + 255) / 256;
  int tid = threadIdx.x;
  int beg = tid * CH, end = min(beg + CH, N_NODES);
  int s = 0;
  for (int i = beg; i < end; ++i) s += counts[i];
  chunk[tid] = s;
  __syncthreads();
  if (tid == 0) {
    int run = 0;
    for (int i = 0; i < 256; ++i) { int c = chunk[i]; chunk[i] = run; run += c; }
  }
  __syncthreads();
  int base = chunk[tid];
  for (int i = beg; i < end; ++i) {
    offs[i] = base;
    cursor[i] = base;
    base += counts[i];
  }
  if (tid == 0) offs[N_NODES] = M_EDGES;
}

__global__ __launch_bounds__(256) void fill_k(const int* __restrict__ src,
                                              const int* __restrict__ dst,
                                              int* __restrict__ cursor,
                                              int* __restrict__ ssrc) {
  int e = blockIdx.x * 256 + threadIdx.x;
  if (e >= M_EDGES) return;
  int p = atomicAdd(&cursor[dst[e]], 1);
  ssrc[p] = src[e];
}

// ---- f32 rows -> packed bf16 rows ----
__global__ __launch_bounds__(256) void convbf_k(const float* __restrict__ X,
                                                unsigned* __restrict__ Xb, int n4) {
  int i = blockIdx.x * 256 + threadIdx.x;
  if (i >= n4) return;
  const float4* s4 = reinterpret_cast<const float4*>(X) + (size_t)i * 2;
  float4 a = s4[0], b = s4[1];
  uint4 o;
  o.x = packbf(a.x, a.y);
  o.y = packbf(a.z, a.w);
  o.z = packbf(b.x, b.y);
  o.w = packbf(b.z, b.w);
  reinterpret_cast<uint4*>(Xb)[i] = o;
}

// ---- segment gather-sum over packed-bf16 rows; wave/node, half-wave/edge, 4x MLP ----
__global__ __launch_bounds__(256) void gatherb_k(const unsigned* __restrict__ Xb,
                                                 const int* __restrict__ offs,
                                                 const int* __restrict__ ssrc,
                                                 unsigned* __restrict__ Ob) {
  int n = blockIdx.x * 4 + (threadIdx.x >> 6);
  int lane = threadIdx.x & 63;
  int half = lane >> 5, col = lane & 31;
  int beg = offs[n], end = offs[n + 1];
  float a0 = 0.f, a1 = 0.f;
  int i = beg + half;
  for (; i + 6 < end; i += 8) {
    int s0 = ssrc[i], s1 = ssrc[i + 2], s2 = ssrc[i + 4], s3 = ssrc[i + 6];
    unsigned u0 = Xb[(size_t)s0 * 32 + col];
    unsigned u1 = Xb[(size_t)s1 * 32 + col];
    unsigned u2 = Xb[(size_t)s2 * 32 + col];
    unsigned u3 = Xb[(size_t)s3 * 32 + col];
    a0 += (bflo(u0) + bflo(u1)) + (bflo(u2) + bflo(u3));
    a1 += (bfhi(u0) + bfhi(u1)) + (bfhi(u2) + bfhi(u3));
  }
  for (; i < end; i += 2) {
    unsigned u = Xb[(size_t)ssrc[i] * 32 + col];
    a0 += bflo(u);
    a1 += bfhi(u);
  }
  a0 += __shfl_xor(a0, 32);
  a1 += __shfl_xor(a1, 32);
  if (half == 0) Ob[(size_t)n * 32 + col] = packbf(a0, a1);
}

// ================= weight-prep (algebraic collapse) =================
__global__ __launch_bounds__(256) void prep1_k(const float* __restrict__ W_ops,
                                               const float* __restrict__ W_cat,
                                               float* __restrict__ W12g,
                                               float* __restrict__ Wc12g) {
  __shared__ float Wa[4096], Wb[4096];
  int tid = threadIdx.x;
  const float *Am, *Bm, *Add;
  float* Out;
  if (blockIdx.x == 0) { Am = W_ops; Bm = W_ops + 8192; Add = W_ops + 4096; Out = W12g; }
  else { Am = W_ops + 16384; Bm = W_cat + 8192; Add = W_cat + 4096; Out = Wc12g; }
  for (int i = tid; i < 4096; i += 256) { Wa[i] = Am[i]; Wb[i] = Bm[i]; }
  __syncthreads();
  for (int t = 0; t < 16; ++t) {
    int o = tid + t * 256;
    int r = o >> 6, j = o & 63;
    float acc = Add[o];
#pragma unroll
    for (int k = 0; k < 64; ++k) acc = fmaf(Wa[r * 64 + k], Wb[k * 64 + j], acc);
    Out[o] = acc;
  }
}

__global__ __launch_bounds__(256) void prep2_k(const float* __restrict__ W_ops,
                                               const float* __restrict__ b_ops,
                                               const float* __restrict__ W_cat,
                                               const float* __restrict__ b_cat,
                                               const float* __restrict__ W12g,
                                               const float* __restrict__ Wc12g,
                                               float* __restrict__ WAg,
                                               float* __restrict__ WBg,
                                               float* __restrict__ cg) {
  __shared__ float M0[4096], M1[4096], M2[4096], M3[4096], M4[4096];
  __shared__ float bb[64];
  int tid = threadIdx.x;
  if (blockIdx.x == 0) {
    for (int i = tid; i < 4096; i += 256) {
      M0[i] = W_ops[i];
      M1[i] = W_cat[i];
      M2[i] = W12g[i];
      M3[i] = Wc12g[i];
    }
    __syncthreads();
    for (int t = 0; t < 16; ++t) {
      int o = tid + t * 256;
      int r = o >> 6, j = o & 63;
      float acc = 0.f;
#pragma unroll
      for (int k = 0; k < 64; ++k) {
        acc = fmaf(M0[r * 64 + k], M1[k * 64 + j], acc);
        acc = fmaf(M2[r * 64 + k], M3[k * 64 + j], acc);
      }
      WAg[o] = acc;
    }
  } else {
    for (int i = tid; i < 4096; i += 256) {
      M0[i] = W_ops[3 * 4096 + i];
      M1[i] = W_cat[8192 + i];
      M2[i] = W_ops[2 * 4096 + i];
      M3[i] = W_cat[i];
      M4[i] = Wc12g[i];
    }
    __syncthreads();
    for (int t = 0; t < 16; ++t) {
      int o = tid + t * 256;
      int r = o >> 6, j = o & 63;
      float acc = 0.f;
#pragma unroll
      for (int k = 0; k < 64; ++k) acc = fmaf(M0[r * 64 + k], M1[k * 64 + j], acc);
      WBg[o] = acc;
    }
    if (tid < 64) {
      int j = tid;
      float acc = b_ops[64 + j] + b_ops[128 + j];
#pragma unroll
      for (int k = 0; k < 64; ++k) acc = fmaf(b_ops[k], M2[k * 64 + j], acc);
      bb[j] = acc;
    }
    __syncthreads();
    if (tid < 64) {
      int j = tid;
      float acc = b_cat[j];
#pragma unroll
      for (int k = 0; k < 64; ++k) {
        acc = fmaf(b_ops[k], M3[k * 64 + j], acc);
        acc = fmaf(bb[k], M4[k * 64 + j], acc);
        acc = fmaf(b_ops[192 + k] + b_ops[256 + k], M1[k * 64 + j], acc);
      }
      cg[j] = acc;
    }
  }
}

// prep3: W0B = W0@WB ; b0B = b0@WB
__global__ __launch_bounds__(256) void prep3_k(const float* __restrict__ W_ops,
                                               const float* __restrict__ b_ops,
                                               const float* __restrict__ WBg,
                                               float* __restrict__ W0Bg,
                                               float* __restrict__ b0Bg) {
  __shared__ float Wa[4096], Wb[4096];
  int tid = threadIdx.x;
  for (int i = tid; i < 4096; i += 256) { Wa[i] = W_ops[i]; Wb[i] = WBg[i]; }
  __syncthreads();
  for (int t = 0; t < 16; ++t) {
    int o = tid + t * 256;
    int r = o >> 6, j = o & 63;
    float acc = 0.f;
#pragma unroll
    for (int k = 0; k < 64; ++k) acc = fmaf(Wa[r * 64 + k], Wb[k * 64 + j], acc);
    W0Bg[o] = acc;
  }
  if (tid < 64) {
    float acc = 0.f;
#pragma unroll
    for (int k = 0; k < 64; ++k) acc = fmaf(b_ops[k], Wb[k * 64 + tid], acc);
    b0Bg[tid] = acc;
  }
}

// prepW: convert 5 weight matrices (contraction along rows) to fragment-ordered
// packed-bf16 tables: MF[((jt*2+kh)*64 + lane)*4 + ui], lane = col16 + 16*kgroup
__global__ __launch_bounds__(256) void prepW_k(
    const float* __restrict__ WAg, const float* __restrict__ W0Bg,
    const float* __restrict__ W_S,
    unsigned* __restrict__ WAF, unsigned* __restrict__ W0BF,
    unsigned* __restrict__ Ws0F, unsigned* __restrict__ Ws2F,
    unsigned* __restrict__ WmF) {
  const float* src;
  unsigned* dst;
  switch (blockIdx.x) {
    case 0: src = WAg; dst = WAF; break;
    case 1: src = W0Bg; dst = W0BF; break;
    case 2: src = W_S; dst = Ws0F; break;
    case 3: src = W_S + 8192; dst = Ws2F; break;
    default: src = W_S + 4096; dst = WmF; break;
  }
  for (int q = threadIdx.x; q < 2048; q += 256) {
    int ui = q & 3, ln = (q >> 2) & 63, t = q >> 8;
    int jt = t >> 1, kh = t & 1;
    int j = jt * 16 + (ln & 15);
    int k2 = kh * 16 + (ln >> 4) * 4 + ui;
    dst[q] = packbf(src[(2 * k2) * 64 + j], src[(2 * k2 + 1) * 64 + j]);
  }
}

// ---- node MFMA kernel: Vnew = A@WA + C@W0B + deg*b0B + c ; Ps/Pd = Vnew@{Ws0,Ws2}+bS
__global__ __launch_bounds__(256) void vnewproj_k(
    const unsigned* __restrict__ Ab, const unsigned* __restrict__ Cb,
    const int* __restrict__ counts,
    const unsigned* __restrict__ WAF, const unsigned* __restrict__ W0BF,
    const unsigned* __restrict__ Ws0F, const unsigned* __restrict__ Ws2F,
    const float* __restrict__ cg, const float* __restrict__ b0Bg,
    const float* __restrict__ b_S,
    float* __restrict__ Vnew, unsigned* __restrict__ PsP, unsigned* __restrict__ PdP) {
  __shared__ __align__(16) unsigned AF[2048], CF[2048], VF[2048];
  __shared__ float cb[64], b0v[64], bsv[64];
  int tid = threadIdx.x;
  int n0 = blockIdx.x * 64;
  // stage A,C fragments (clamped rows for the partial last block)
  for (int q = tid; q < 2048; q += 256) {
    int r = q >> 5, k2 = q & 31;
    int row = n0 + r;
    if (row >= N_NODES) row = N_NODES - 1;
    unsigned ua = Ab[(size_t)row * 32 + k2];
    unsigned uc = Cb[(size_t)row * 32 + k2];
    int kh = k2 >> 4, k2h = k2 & 15;
    int ln = (r & 15) + 16 * (k2h >> 2);
    int idx = ((((r >> 4) << 1) + kh) * 64 + ln) * 4 + (k2h & 3);
    AF[idx] = ua;
    CF[idx] = uc;
  }
  if (tid < 64) { cb[tid] = cg[tid]; b0v[tid] = b0Bg[tid]; bsv[tid] = b_S[tid]; }
  __syncthreads();

  int lane = tid & 63, et = tid >> 6;
  int col15 = lane & 15, g4 = lane >> 4;
  float deg[4];
#pragma unroll
  for (int reg = 0; reg < 4; ++reg) {
    int rg = n0 + et * 16 + g4 * 4 + reg;
    deg[reg] = (float)counts[rg < N_NODES ? rg : N_NODES - 1];
  }
  f32x4 a0 = {0.f, 0.f, 0.f, 0.f}, a1 = a0, a2 = a0, a3 = a0;
#pragma unroll
  for (int kh = 0; kh < 2; ++kh) {
    uint4 au = *reinterpret_cast<const uint4*>(&AF[(((et << 1) + kh) * 64 + lane) * 4]);
    uint4 cu = *reinterpret_cast<const uint4*>(&CF[(((et << 1) + kh) * 64 + lane) * 4]);
    bf16x8 afr = *reinterpret_cast<bf16x8*>(&au);
    bf16x8 cfr = *reinterpret_cast<bf16x8*>(&cu);
    uint4 wa0 = *reinterpret_cast<const uint4*>(&WAF[((0 * 2 + kh) * 64 + lane) * 4]);
    uint4 wa1 = *reinterpret_cast<const uint4*>(&WAF[((1 * 2 + kh) * 64 + lane) * 4]);
    uint4 wa2 = *reinterpret_cast<const uint4*>(&WAF[((2 * 2 + kh) * 64 + lane) * 4]);
    uint4 wa3 = *reinterpret_cast<const uint4*>(&WAF[((3 * 2 + kh) * 64 + lane) * 4]);
    uint4 wc0 = *reinterpret_cast<const uint4*>(&W0BF[((0 * 2 + kh) * 64 + lane) * 4]);
    uint4 wc1 = *reinterpret_cast<const uint4*>(&W0BF[((1 * 2 + kh) * 64 + lane) * 4]);
    uint4 wc2 = *reinterpret_cast<const uint4*>(&W0BF[((2 * 2 + kh) * 64 + lane) * 4]);
    uint4 wc3 = *reinterpret_cast<const uint4*>(&W0BF[((3 * 2 + kh) * 64 + lane) * 4]);
    a0 = __builtin_amdgcn_mfma_f32_16x16x32_bf16(afr, *reinterpret_cast<bf16x8*>(&wa0), a0, 0, 0, 0);
    a1 = __builtin_amdgcn_mfma_f32_16x16x32_bf16(afr, *reinterpret_cast<bf16x8*>(&wa1), a1, 0, 0, 0);
    a2 = __builtin_amdgcn_mfma_f32_16x16x32_bf16(afr, *reinterpret_cast<bf16x8*>(&wa2), a2, 0, 0, 0);
    a3 = __builtin_amdgcn_mfma_f32_16x16x32_bf16(afr, *reinterpret_cast<bf16x8*>(&wa3), a3, 0, 0, 0);
    a0 = __builtin_amdgcn_mfma_f32_16x16x32_bf16(cfr, *reinterpret_cast<bf16x8*>(&wc0), a0, 0, 0, 0);
    a1 = __builtin_amdgcn_mfma_f32_16x16x32_bf16(cfr, *reinterpret_cast<bf16x8*>(&wc1), a1, 0, 0, 0);
    a2 = __builtin_amdgcn_mfma_f32_16x16x32_bf16(cfr, *reinterpret_cast<bf16x8*>(&wc2), a2, 0, 0, 0);
    a3 = __builtin_amdgcn_mfma_f32_16x16x32_bf16(cfr, *reinterpret_cast<bf16x8*>(&wc3), a3, 0, 0, 0);
  }
  // bias add + f32 Vnew store + pack to VF fragments
#pragma unroll
  for (int jt = 0; jt < 4; ++jt) {
    f32x4 a = (jt == 0) ? a0 : (jt == 1) ? a1 : (jt == 2) ? a2 : a3;
    int j = jt * 16 + col15;
#pragma unroll
    for (int reg = 0; reg < 4; ++reg) {
      float v = a[reg] + fmaf(deg[reg], b0v[j], cb[j]);
      a[reg] = v;
      int rg = n0 + et * 16 + g4 * 4 + reg;
      if (rg < N_NODES) Vnew[(size_t)rg * 64 + j] = v;
    }
#pragma unroll
    for (int reg = 0; reg < 4; ++reg) {
      float v = a[reg];
      float pv = __shfl_xor(v, 1);
      if (!(col15 & 1)) {
        int k2p = jt * 8 + (col15 >> 1);
        int kh2 = k2p >> 4, k2h = k2p & 15;
        int ln = (g4 * 4 + reg) + 16 * (k2h >> 2);
        VF[(((et << 1) + kh2) * 64 + ln) * 4 + (k2h & 3)] = packbf(v, pv);
      }
    }
  }
  __syncthreads();
  // stage 2: Ps = VF@Ws0 + bS ; Pd = VF@Ws2
  f32x4 p0 = {0.f, 0.f, 0.f, 0.f}, p1 = p0, p2 = p0, p3 = p0;
  f32x4 d0 = p0, d1 = p0, d2 = p0, d3 = p0;
#pragma unroll
  for (int kh = 0; kh < 2; ++kh) {
    uint4 vu = *reinterpret_cast<const uint4*>(&VF[(((et << 1) + kh) * 64 + lane) * 4]);
    bf16x8 vfr = *reinterpret_cast<bf16x8*>(&vu);
    uint4 w00 = *reinterpret_cast<const uint4*>(&Ws0F[((0 * 2 + kh) * 64 + lane) * 4]);
    uint4 w01 = *reinterpret_cast<const uint4*>(&Ws0F[((1 * 2 + kh) * 64 + lane) * 4]);
    uint4 w02 = *reinterpret_cast<const uint4*>(&Ws0F[((2 * 2 + kh) * 64 + lane) * 4]);
    uint4 w03 = *reinterpret_cast<const uint4*>(&Ws0F[((3 * 2 + kh) * 64 + lane) * 4]);
    uint4 w20 = *reinterpret_cast<const uint4*>(&Ws2F[((0 * 2 + kh) * 64 + lane) * 4]);
    uint4 w21 = *reinterpret_cast<const uint4*>(&Ws2F[((1 * 2 + kh) * 64 + lane) * 4]);
    uint4 w22 = *reinterpret_cast<const uint4*>(&Ws2F[((2 * 2 + kh) * 64 + lane) * 4]);
    uint4 w23 = *reinterpret_cast<const uint4*>(&Ws2F[((3 * 2 + kh) * 64 + lane) * 4]);
    p0 = __builtin_amdgcn_mfma_f32_16x16x32_bf16(vfr, *reinterpret_cast<bf16x8*>(&w00), p0, 0, 0, 0);
    p1 = __builtin_amdgcn_mfma_f32_16x16x32_bf16(vfr, *reinterpret_cast<bf16x8*>(&w01), p1, 0, 0, 0);
    p2 = __builtin_amdgcn_mfma_f32_16x16x32_bf16(vfr, *reinterpret_cast<bf16x8*>(&w02), p2, 0, 0, 0);
    p3 = __builtin_amdgcn_mfma_f32_16x16x32_bf16(vfr, *reinterpret_cast<bf16x8*>(&w03), p3, 0, 0, 0);
    d0 = __builtin_amdgcn_mfma_f32_16x16x32_bf16(vfr, *reinterpret_cast<bf16x8*>(&w20), d0, 0, 0, 0);
    d1 = __builtin_amdgcn_mfma_f32_16x16x32_bf16(vfr, *reinterpret_cast<bf16x8*>(&w21), d1, 0, 0, 0);
    d2 = __builtin_amdgcn_mfma_f32_16x16x32_bf16(vfr, *reinterpret_cast<bf16x8*>(&w22), d2, 0, 0, 0);
    d3 = __builtin_amdgcn_mfma_f32_16x16x32_bf16(vfr, *reinterpret_cast<bf16x8*>(&w23), d3, 0, 0, 0);
  }
#pragma unroll
  for (int pt = 0; pt < 4; ++pt) {
    f32x4 p = (pt == 0) ? p0 : (pt == 1) ? p1 : (pt == 2) ? p2 : p3;
    f32x4 d = (pt == 0) ? d0 : (pt == 1) ? d1 : (pt == 2) ? d2 : d3;
    int pj = pt * 16 + col15;
#pragma unroll
    for (int reg = 0; reg < 4; ++reg) {
      float vp = p[reg] + bsv[pj];
      float vd = d[reg];
      float pvp = __shfl_xor(vp, 1);
      float pvd = __shfl_xor(vd, 1);
      if (!(col15 & 1)) {
        int rg = n0 + et * 16 + g4 * 4 + reg;
        if (rg < N_NODES) {
          PsP[(size_t)rg * 32 + pt * 8 + (col15 >> 1)] = packbf(vp, pvp);
          PdP[(size_t)rg * 32 + pt * 8 + (col15 >> 1)] = packbf(vd, pvd);
        }
      }
    }
  }
}

// ---- edge MFMA kernel: E@Wmid via matrix cores; W fragments from global table ----
__global__ __launch_bounds__(256) void edge_k(
    const float* __restrict__ Eg, const int* __restrict__ src, const int* __restrict__ dst,
    const unsigned* __restrict__ PsP, const unsigned* __restrict__ PdP,
    const unsigned* __restrict__ WmF, unsigned* __restrict__ EoutSlots,
    float* __restrict__ partials) {
  __shared__ __align__(16) unsigned EaF[2048];
  __shared__ unsigned Spd[64][34];
  __shared__ float ls[128];
  int tid = threadIdx.x;
  int e0 = blockIdx.x * 64;
  int l16 = tid & 15, g16 = tid >> 4;

  uint2 pa[4], pb[4];
#pragma unroll
  for (int rr = 0; rr < 4; ++rr) {
    int p = e0 + rr * 16 + g16;
    int s = src[p], d = dst[p];
    pa[rr] = *reinterpret_cast<const uint2*>(&PsP[(size_t)s * 32 + 2 * l16]);
    pb[rr] = *reinterpret_cast<const uint2*>(&PdP[(size_t)d * 32 + 2 * l16]);
  }
  if (tid < 128) ls[tid] = 0.f;
  for (int q = tid; q < 1024; q += 256) {
    int e = q >> 4, kq = q & 15;
    float4 vv = reinterpret_cast<const float4*>(Eg)[(size_t)(e0 + e) * 16 + kq];
    unsigned u0 = packbf(leaky(vv.x), leaky(vv.y));
    unsigned u1 = packbf(leaky(vv.z), leaky(vv.w));
    int k2a = 2 * kq;
    int kh = k2a >> 4, k2h = k2a & 15;
    int lane = (e & 15) + 16 * (k2h >> 2);
    int base = ((((e >> 4) << 1) + kh) * 64 + lane) * 4 + (k2h & 3);
    EaF[base] = u0;
    EaF[base + 1] = u1;
  }
#pragma unroll
  for (int rr = 0; rr < 4; ++rr) {
    int r = rr * 16 + g16;
    float fx = bflo(pa[rr].x) + bflo(pb[rr].x);
    float fy = bfhi(pa[rr].x) + bfhi(pb[rr].x);
    float fz = bflo(pa[rr].y) + bflo(pb[rr].y);
    float fw = bfhi(pa[rr].y) + bfhi(pb[rr].y);
    *reinterpret_cast<uint2*>(&Spd[r][l16 * 2]) = make_uint2(packbf(fx, fy), packbf(fz, fw));
  }
  __syncthreads();

  int lane = tid & 63;
  int et = tid >> 6;
  f32x4 acc0 = {0.f, 0.f, 0.f, 0.f};
  f32x4 acc1 = acc0, acc2 = acc0, acc3 = acc0;
#pragma unroll
  for (int kh = 0; kh < 2; ++kh) {
    uint4 au = *reinterpret_cast<const uint4*>(&EaF[(((et << 1) + kh) * 64 + lane) * 4]);
    bf16x8 afr = *reinterpret_cast<bf16x8*>(&au);
    uint4 b0 = *reinterpret_cast<const uint4*>(&WmF[((0 * 2 + kh) * 64 + lane) * 4]);
    uint4 b1 = *reinterpret_cast<const uint4*>(&WmF[((1 * 2 + kh) * 64 + lane) * 4]);
    uint4 b2 = *reinterpret_cast<const uint4*>(&WmF[((2 * 2 + kh) * 64 + lane) * 4]);
    uint4 b3 = *reinterpret_cast<const uint4*>(&WmF[((3 * 2 + kh) * 64 + lane) * 4]);
    acc0 = __builtin_amdgcn_mfma_f32_16x16x32_bf16(afr, *reinterpret_cast<bf16x8*>(&b0), acc0, 0, 0, 0);
    acc1 = __builtin_amdgcn_mfma_f32_16x16x32_bf16(afr, *reinterpret_cast<bf16x8*>(&b1), acc1, 0, 0, 0);
    acc2 = __builtin_amdgcn_mfma_f32_16x16x32_bf16(afr, *reinterpret_cast<bf16x8*>(&b2), acc2, 0, 0, 0);
    acc3 = __builtin_amdgcn_mfma_f32_16x16x32_bf16(afr, *reinterpret_cast<bf16x8*>(&b3), acc3, 0, 0, 0);
  }

  int col15 = lane & 15, g4 = lane >> 4;
  float s4[4] = {0.f, 0.f, 0.f, 0.f}, q4[4] = {0.f, 0.f, 0.f, 0.f};
  f32x4 accs[4];
#pragma unroll
  for (int jt = 0; jt < 4; ++jt) {
    f32x4 a = (jt == 0) ? acc0 : (jt == 1) ? acc1 : (jt == 2) ? acc2 : acc3;
#pragma unroll
    for (int reg = 0; reg < 4; ++reg) {
      int e = et * 16 + g4 * 4 + reg;
      int j = jt * 16 + col15;
      unsigned sp = Spd[e][j >> 1];
      float add = (j & 1) ? bfhi(sp) : bflo(sp);
      float v = a[reg] + add;
      a[reg] = v;
      s4[jt] += v;
      q4[jt] = fmaf(v, v, q4[jt]);
    }
    accs[jt] = a;
  }
#pragma unroll
  for (int jt = 0; jt < 4; ++jt) {
#pragma unroll
    for (int reg = 0; reg < 4; ++reg) {
      float v = accs[jt][reg];
      float pv = __shfl_xor(v, 1);
      if (!(col15 & 1)) {
        int e = e0 + et * 16 + g4 * 4 + reg;
        EoutSlots[(size_t)e * 64 + jt * 8 + (col15 >> 1)] = packbf(v, pv);
      }
    }
  }
#pragma unroll
  for (int jt = 0; jt < 4; ++jt) {
    s4[jt] += __shfl_xor(s4[jt], 16);
    q4[jt] += __shfl_xor(q4[jt], 16);
    s4[jt] += __shfl_xor(s4[jt], 32);
    q4[jt] += __shfl_xor(q4[jt], 32);
  }
  if (g4 == 0) {
#pragma unroll
    for (int jt = 0; jt < 4; ++jt) {
      atomicAdd(&ls[jt * 16 + col15], s4[jt]);
      atomicAdd(&ls[64 + jt * 16 + col15], q4[jt]);
    }
  }
  __syncthreads();
  if (tid < 128) partials[(size_t)blockIdx.x * 128 + tid] = ls[tid];
}

// ---- reduce per-block partials ----
__global__ __launch_bounds__(256) void reduce_stats_k(const float* __restrict__ partials,
                                                      float* __restrict__ stats) {
  __shared__ float ls[128];
  int tid = threadIdx.x;
  if (tid < 128) ls[tid] = 0.f;
  __syncthreads();
  int c = tid & 127;
  int half = tid >> 7;
  float s = 0.f;
  for (int r = blockIdx.x * 2 + half; r < NEBLK; r += 2 * gridDim.x) {
    s += partials[(size_t)r * 128 + c];
  }
  atomicAdd(&ls[c], s);
  __syncthreads();
  if (tid < 128) atomicAdd(&stats[tid], ls[tid]);
}

// ---- per-column sum / sumsq (V side) ----
__global__ __launch_bounds__(256) void col_stats_k(
    const float* __restrict__ X, size_t nelem, float* __restrict__ sums) {
  __shared__ float ls[128];
  int tid = threadIdx.x;
  if (tid < 128) ls[tid] = 0.f;
  __syncthreads();
  int j = tid & 63;
  float s = 0.f, ss = 0.f;
  size_t stride = (size_t)gridDim.x * blockDim.x;
  for (size_t i = (size_t)blockIdx.x * blockDim.x + tid; i < nelem; i += stride) {
    float x = X[i];
    s += x;
    ss = fmaf(x, x, ss);
  }
  atomicAdd(&ls[j], s);
  atomicAdd(&ls[64 + j], ss);
  __syncthreads();
  if (tid < 128) atomicAdd(&sums[tid], ls[tid]);
}

__global__ void finalize_k(const float* __restrict__ sums, float inv_n,
                           const float* __restrict__ gamma, const float* __restrict__ beta,
                           float* __restrict__ sc_shift) {
  int j = threadIdx.x;
  float mu = sums[j] * inv_n;
  float var = sums[64 + j] * inv_n - mu * mu;
  float sc = gamma[j] * rsqrtf(var + BN_EPS);
  sc_shift[j] = sc;
  sc_shift[64 + j] = beta[j] - mu * sc;
}

__global__ __launch_bounds__(256) void bn_apply_k(
    float* __restrict__ X, const float* __restrict__ resid,
    const float* __restrict__ sc_shift, int n4) {
  int i = blockIdx.x * blockDim.x + threadIdx.x;
  if (i >= n4) return;
  int jq = i & 15;
  float4 x = reinterpret_cast<float4*>(X)[i];
  float4 r = reinterpret_cast<const float4*>(resid)[i];
  float4 sc = reinterpret_cast<const float4*>(sc_shift)[jq];
  float4 sh = reinterpret_cast<const float4*>(sc_shift + 64)[jq];
  float4 y;
  y.x = leaky(fmaf(x.x, sc.x, sh.x)) + r.x;
  y.y = leaky(fmaf(x.y, sc.y, sh.y)) + r.y;
  y.z = leaky(fmaf(x.z, sc.z, sh.z)) + r.z;
  y.w = leaky(fmaf(x.w, sc.w, sh.w)) + r.w;
  reinterpret_cast<float4*>(X)[i] = y;
}

// ---- E side, coalesced float4-per-thread slot expansion ----
__global__ __launch_bounds__(256) void bn_applyE_k(
    float* __restrict__ EoutF, const float* __restrict__ Eg,
    const float* __restrict__ sc_shift) {
  __shared__ float scs[128];
  int tid = threadIdx.x;
  if (tid < 128) scs[tid] = sc_shift[tid];
  __syncthreads();
  int i = blockIdx.x * 256 + tid;
  int jq = i & 15;
  float2 pr = reinterpret_cast<const float2*>(EoutF)[((size_t)(i >> 4)) * 32 + jq];
  unsigned u0 = __float_as_uint(pr.x);
  unsigned u1 = __float_as_uint(pr.y);
  float v0 = bflo(u0), v1 = bfhi(u0), v2 = bflo(u1), v3 = bfhi(u1);
  float4 eg = reinterpret_cast<const float4*>(Eg)[i];
  int j = jq * 4;
  float4 o;
  o.x = leaky(fmaf(v0, scs[j + 0], scs[64 + j + 0])) + eg.x;
  o.y = leaky(fmaf(v1, scs[j + 1], scs[64 + j + 1])) + eg.y;
  o.z = leaky(fmaf(v2, scs[j + 2], scs[64 + j + 2])) + eg.z;
  o.w = leaky(fmaf(v3, scs[j + 3], scs[64 + j + 3])) + eg.w;
  reinterpret_cast<float4*>(EoutF)[i] = o;
}

extern "C" void kernel_launch(void* const* d_in, const int* in_sizes, int n_in,
                              void* d_out, int out_size, void* d_ws, size_t ws_size,
                              hipStream_t stream) {
  const float* V      = (const float*)d_in[0];
  const float* Eg     = (const float*)d_in[1];
  const int*   src    = (const int*)d_in[2];
  const int*   dst    = (const int*)d_in[3];
  const float* W_ops  = (const float*)d_in[4];
  const float* b_ops  = (const float*)d_in[5];
  const float* W_cat  = (const float*)d_in[6];
  const float* b_cat  = (const float*)d_in[7];
  const float* W_S    = (const float*)d_in[8];
  const float* b_S    = (const float*)d_in[9];
  const float* gammaV = (const float*)d_in[10];
  const float* betaV  = (const float*)d_in[11];
  const float* gammaE = (const float*)d_in[12];
  const float* betaE  = (const float*)d_in[13];

  float* ws = (float*)d_ws;
  const size_t ND = (size_t)N_NODES * 64;
  const size_t NH = (size_t)N_NODES * 32;
  unsigned* Vb  = (unsigned*)ws;
  unsigned* Ab  = (unsigned*)ws + NH;
  unsigned* Cb  = (unsigned*)ws + 2 * NH;
  unsigned* PsP = (unsigned*)ws + 3 * NH;
  unsigned* PdP = (unsigned*)ws + 4 * NH;
  float* xb   = ws + 5 * NH;
  float* W12g  = xb;
  float* Wc12g = xb + 4096;
  float* WAg   = xb + 8192;
  float* WBg   = xb + 12288;
  float* W0Bg  = xb + 16384;
  float* cg    = xb + 20480;
  float* b0Bg  = xb + 20544;
  float* statsV = xb + 20608;
  float* statsE = statsV + 128;
  float* scshV  = statsV + 256;
  float* scshE  = statsV + 384;
  int* counts = (int*)(statsV + 512);
  int* offs   = counts + N_NODES;
  int* cursor = offs + N_NODES + 1;
  int* ssrc   = cursor + N_NODES;
  float* partials = (float*)(ssrc + M_EDGES);
  unsigned* WAF  = (unsigned*)(partials + (size_t)NEBLK * 128);
  unsigned* W0BF = WAF + 2048;
  unsigned* Ws0F = WAF + 4096;
  unsigned* Ws2F = WAF + 6144;
  unsigned* WmF  = WAF + 8192;

  float* Vout  = (float*)d_out;
  float* EoutF = Vout + ND;
  unsigned* EoutSlots = (unsigned*)EoutF;

  hipMemsetAsync(counts, 0, N_NODES * sizeof(int), stream);
  hipMemsetAsync(statsV, 0, 256 * sizeof(float), stream);

  const int eb = (M_EDGES + 255) / 256;
  prep1_k<<<2, 256, 0, stream>>>(W_ops, W_cat, W12g, Wc12g);
  prep2_k<<<2, 256, 0, stream>>>(W_ops, b_ops, W_cat, b_cat, W12g, Wc12g, WAg, WBg, cg);
  prep3_k<<<1, 256, 0, stream>>>(W_ops, b_ops, WBg, W0Bg, b0Bg);
  prepW_k<<<5, 256, 0, stream>>>(WAg, W0Bg, W_S, WAF, W0BF, Ws0F, Ws2F, WmF);
  hist_k<<<eb, 256, 0, stream>>>(dst, counts);
  scan_k<<<1, 256, 0, stream>>>(counts, offs, cursor);
  fill_k<<<eb, 256, 0, stream>>>(src, dst, cursor, ssrc);

  convbf_k<<<(N_NODES * 8 + 255) / 256, 256, 0, stream>>>(V, Vb, N_NODES * 8);
  gatherb_k<<<N_NODES / 4, 256, 0, stream>>>(Vb, offs, ssrc, Ab);
  gatherb_k<<<N_NODES / 4, 256, 0, stream>>>(Ab, offs, ssrc, Cb);
  vnewproj_k<<<NVBLK, 256, 0, stream>>>(Ab, Cb, counts, WAF, W0BF, Ws0F, Ws2F,
                                        cg, b0Bg, b_S, Vout, PsP, PdP);
  edge_k<<<NEBLK, 256, 0, stream>>>(Eg, src, dst, PsP, PdP, WmF, EoutSlots, partials);
  reduce_stats_k<<<64, 256, 0, stream>>>(partials, statsE);
  col_stats_k<<<512, 256, 0, stream>>>(Vout, ND, statsV);
  finalize_k<<<1, 64, 0, stream>>>(statsV, 1.f / N_NODES, gammaV, betaV, scshV);
  finalize_k<<<1, 64, 0, stream>>>(statsE, 1.f / M_EDGES, gammaE, betaE, scshE);
  bn_apply_k<<<(int)((ND / 4 + 255) / 256), 256, 0, stream>>>(Vout, V, scshV, (int)(ND / 4));
  bn_applyE_k<<<M_EDGES * 16 / 256, 256, 0, stream>>>(EoutF, Eg, scshE);
}

// Round 14
// 474.491 us; speedup vs baseline: 1.9154x; 1.2446x over previous
//
#include <hip/hip_runtime.h>
#include <hip/hip_bf16.h>

#define N_NODES 50000
#define M_EDGES 800000
#define LEAKY_F 0.2f
#define BN_EPS 1e-5f
#define NEBLK (M_EDGES / 64)
#define NVBLK ((N_NODES + 63) / 64)
#define NSB ((N_NODES + 255) / 256)

typedef short bf16x8 __attribute__((ext_vector_type(8)));
typedef float f32x4 __attribute__((ext_vector_type(4)));

__device__ __forceinline__ float leaky(float x) { return x >= 0.f ? x : LEAKY_F * x; }

__device__ __forceinline__ unsigned f2bf(float f) {
  unsigned u = __float_as_uint(f);
  return (u + 0x7fffu + ((u >> 16) & 1u)) >> 16;
}
__device__ __forceinline__ unsigned packbf(float a, float b) {
  return (f2bf(b) << 16) | f2bf(a);
}
__device__ __forceinline__ float bflo(unsigned u) { return __uint_as_float(u << 16); }
__device__ __forceinline__ float bfhi(unsigned u) { return __uint_as_float(u & 0xffff0000u); }

// ================= CSR build =================
__global__ __launch_bounds__(256) void hist_k(const int* __restrict__ dst,
                                              int* __restrict__ counts) {
  int e = blockIdx.x * 256 + threadIdx.x;
  if (e < M_EDGES) atomicAdd(&counts[dst[e]], 1);
}

// parallel hierarchical exclusive scan of counts -> offs, cursor
__global__ __launch_bounds__(256) void blocksum_k(const int* __restrict__ counts,
                                                  int* __restrict__ bsum) {
  __shared__ int wsum[4];
  int tid = threadIdx.x;
  int i = blockIdx.x * 256 + tid;
  int v = (i < N_NODES) ? counts[i] : 0;
#pragma unroll
  for (int off = 32; off; off >>= 1) v += __shfl_down(v, off);
  if ((tid & 63) == 0) wsum[tid >> 6] = v;
  __syncthreads();
  if (tid == 0) bsum[blockIdx.x] = wsum[0] + wsum[1] + wsum[2] + wsum[3];
}

__global__ __launch_bounds__(256) void scanb_k(int* __restrict__ bsum) {
  __shared__ int s[256];
  int tid = threadIdx.x;
  s[tid] = (tid < NSB) ? bsum[tid] : 0;
  __syncthreads();
  for (int off = 1; off < 256; off <<= 1) {
    int v = 0;
    if (tid >= off) v = s[tid - off];
    __syncthreads();
    if (tid >= off) s[tid] += v;
    __syncthreads();
  }
  if (tid < NSB) bsum[tid] = (tid == 0) ? 0 : s[tid - 1];
}

__global__ __launch_bounds__(256) void offs_k(const int* __restrict__ counts,
                                              const int* __restrict__ bsum,
                                              int* __restrict__ offs,
                                              int* __restrict__ cursor) {
  __shared__ int s[256];
  int tid = threadIdx.x;
  int i = blockIdx.x * 256 + tid;
  int c = (i < N_NODES) ? counts[i] : 0;
  s[tid] = c;
  __syncthreads();
  for (int off = 1; off < 256; off <<= 1) {
    int v = 0;
    if (tid >= off) v = s[tid - off];
    __syncthreads();
    if (tid >= off) s[tid] += v;
    __syncthreads();
  }
  int excl = s[tid] - c + bsum[blockIdx.x];
  if (i < N_NODES) {
    offs[i] = excl;
    cursor[i] = excl;
  }
  if (i == N_NODES - 1) offs[N_NODES] = M_EDGES;
}

__global__ __launch_bounds__(256) void fill_k(const int* __restrict__ src,
                                              const int* __restrict__ dst,
                                              int* __restrict__ cursor,
                                              int* __restrict__ ssrc) {
  int e = blockIdx.x * 256 + threadIdx.x;
  if (e >= M_EDGES) return;
  int p = atomicAdd(&cursor[dst[e]], 1);
  ssrc[p] = src[e];
}

// ---- f32 rows -> packed bf16 rows ----
__global__ __launch_bounds__(256) void convbf_k(const float* __restrict__ X,
                                                unsigned* __restrict__ Xb, int n4) {
  int i = blockIdx.x * 256 + threadIdx.x;
  if (i >= n4) return;
  const float4* s4 = reinterpret_cast<const float4*>(X) + (size_t)i * 2;
  float4 a = s4[0], b = s4[1];
  uint4 o;
  o.x = packbf(a.x, a.y);
  o.y = packbf(a.z, a.w);
  o.z = packbf(b.x, b.y);
  o.w = packbf(b.z, b.w);
  reinterpret_cast<uint4*>(Xb)[i] = o;
}

// ---- segment gather-sum over packed-bf16 rows; wave/node, half-wave/edge, 4x MLP ----
__global__ __launch_bounds__(256) void gatherb_k(const unsigned* __restrict__ Xb,
                                                 const int* __restrict__ offs,
                                                 const int* __restrict__ ssrc,
                                                 unsigned* __restrict__ Ob) {
  int n = blockIdx.x * 4 + (threadIdx.x >> 6);
  int lane = threadIdx.x & 63;
  int half = lane >> 5, col = lane & 31;
  int beg = offs[n], end = offs[n + 1];
  float a0 = 0.f, a1 = 0.f;
  int i = beg + half;
  for (; i + 6 < end; i += 8) {
    int s0 = ssrc[i], s1 = ssrc[i + 2], s2 = ssrc[i + 4], s3 = ssrc[i + 6];
    unsigned u0 = Xb[(size_t)s0 * 32 + col];
    unsigned u1 = Xb[(size_t)s1 * 32 + col];
    unsigned u2 = Xb[(size_t)s2 * 32 + col];
    unsigned u3 = Xb[(size_t)s3 * 32 + col];
    a0 += (bflo(u0) + bflo(u1)) + (bflo(u2) + bflo(u3));
    a1 += (bfhi(u0) + bfhi(u1)) + (bfhi(u2) + bfhi(u3));
  }
  for (; i < end; i += 2) {
    unsigned u = Xb[(size_t)ssrc[i] * 32 + col];
    a0 += bflo(u);
    a1 += bfhi(u);
  }
  a0 += __shfl_xor(a0, 32);
  a1 += __shfl_xor(a1, 32);
  if (half == 0) Ob[(size_t)n * 32 + col] = packbf(a0, a1);
}

// ================= weight-prep (algebraic collapse) =================
__global__ __launch_bounds__(256) void prep1_k(const float* __restrict__ W_ops,
                                               const float* __restrict__ W_cat,
                                               float* __restrict__ W12g,
                                               float* __restrict__ Wc12g) {
  __shared__ float Wa[4096], Wb[4096];
  int tid = threadIdx.x;
  const float *Am, *Bm, *Add;
  float* Out;
  if (blockIdx.x == 0) { Am = W_ops; Bm = W_ops + 8192; Add = W_ops + 4096; Out = W12g; }
  else { Am = W_ops + 16384; Bm = W_cat + 8192; Add = W_cat + 4096; Out = Wc12g; }
  for (int i = tid; i < 4096; i += 256) { Wa[i] = Am[i]; Wb[i] = Bm[i]; }
  __syncthreads();
  for (int t = 0; t < 16; ++t) {
    int o = tid + t * 256;
    int r = o >> 6, j = o & 63;
    float acc = Add[o];
#pragma unroll
    for (int k = 0; k < 64; ++k) acc = fmaf(Wa[r * 64 + k], Wb[k * 64 + j], acc);
    Out[o] = acc;
  }
}

__global__ __launch_bounds__(256) void prep2_k(const float* __restrict__ W_ops,
                                               const float* __restrict__ b_ops,
                                               const float* __restrict__ W_cat,
                                               const float* __restrict__ b_cat,
                                               const float* __restrict__ W12g,
                                               const float* __restrict__ Wc12g,
                                               float* __restrict__ WAg,
                                               float* __restrict__ WBg,
                                               float* __restrict__ cg) {
  __shared__ float M0[4096], M1[4096], M2[4096], M3[4096], M4[4096];
  __shared__ float bb[64];
  int tid = threadIdx.x;
  if (blockIdx.x == 0) {
    for (int i = tid; i < 4096; i += 256) {
      M0[i] = W_ops[i];
      M1[i] = W_cat[i];
      M2[i] = W12g[i];
      M3[i] = Wc12g[i];
    }
    __syncthreads();
    for (int t = 0; t < 16; ++t) {
      int o = tid + t * 256;
      int r = o >> 6, j = o & 63;
      float acc = 0.f;
#pragma unroll
      for (int k = 0; k < 64; ++k) {
        acc = fmaf(M0[r * 64 + k], M1[k * 64 + j], acc);
        acc = fmaf(M2[r * 64 + k], M3[k * 64 + j], acc);
      }
      WAg[o] = acc;
    }
  } else {
    for (int i = tid; i < 4096; i += 256) {
      M0[i] = W_ops[3 * 4096 + i];
      M1[i] = W_cat[8192 + i];
      M2[i] = W_ops[2 * 4096 + i];
      M3[i] = W_cat[i];
      M4[i] = Wc12g[i];
    }
    __syncthreads();
    for (int t = 0; t < 16; ++t) {
      int o = tid + t * 256;
      int r = o >> 6, j = o & 63;
      float acc = 0.f;
#pragma unroll
      for (int k = 0; k < 64; ++k) acc = fmaf(M0[r * 64 + k], M1[k * 64 + j], acc);
      WBg[o] = acc;
    }
    if (tid < 64) {
      int j = tid;
      float acc = b_ops[64 + j] + b_ops[128 + j];
#pragma unroll
      for (int k = 0; k < 64; ++k) acc = fmaf(b_ops[k], M2[k * 64 + j], acc);
      bb[j] = acc;
    }
    __syncthreads();
    if (tid < 64) {
      int j = tid;
      float acc = b_cat[j];
#pragma unroll
      for (int k = 0; k < 64; ++k) {
        acc = fmaf(b_ops[k], M3[k * 64 + j], acc);
        acc = fmaf(bb[k], M4[k * 64 + j], acc);
        acc = fmaf(b_ops[192 + k] + b_ops[256 + k], M1[k * 64 + j], acc);
      }
      cg[j] = acc;
    }
  }
}

// prep3: W0B = W0@WB ; b0B = b0@WB
__global__ __launch_bounds__(256) void prep3_k(const float* __restrict__ W_ops,
                                               const float* __restrict__ b_ops,
                                               const float* __restrict__ WBg,
                                               float* __restrict__ W0Bg,
                                               float* __restrict__ b0Bg) {
  __shared__ float Wa[4096], Wb[4096];
  int tid = threadIdx.x;
  for (int i = tid; i < 4096; i += 256) { Wa[i] = W_ops[i]; Wb[i] = WBg[i]; }
  __syncthreads();
  for (int t = 0; t < 16; ++t) {
    int o = tid + t * 256;
    int r = o >> 6, j = o & 63;
    float acc = 0.f;
#pragma unroll
    for (int k = 0; k < 64; ++k) acc = fmaf(Wa[r * 64 + k], Wb[k * 64 + j], acc);
    W0Bg[o] = acc;
  }
  if (tid < 64) {
    float acc = 0.f;
#pragma unroll
    for (int k = 0; k < 64; ++k) acc = fmaf(b_ops[k], Wb[k * 64 + tid], acc);
    b0Bg[tid] = acc;
  }
}

// prepW: fragment-ordered packed-bf16 weight tables
__global__ __launch_bounds__(256) void prepW_k(
    const float* __restrict__ WAg, const float* __restrict__ W0Bg,
    const float* __restrict__ W_S,
    unsigned* __restrict__ WAF, unsigned* __restrict__ W0BF,
    unsigned* __restrict__ Ws0F, unsigned* __restrict__ Ws2F,
    unsigned* __restrict__ WmF) {
  const float* src;
  unsigned* dst;
  switch (blockIdx.x) {
    case 0: src = WAg; dst = WAF; break;
    case 1: src = W0Bg; dst = W0BF; break;
    case 2: src = W_S; dst = Ws0F; break;
    case 3: src = W_S + 8192; dst = Ws2F; break;
    default: src = W_S + 4096; dst = WmF; break;
  }
  for (int q = threadIdx.x; q < 2048; q += 256) {
    int ui = q & 3, ln = (q >> 2) & 63, t = q >> 8;
    int jt = t >> 1, kh = t & 1;
    int j = jt * 16 + (ln & 15);
    int k2 = kh * 16 + (ln >> 4) * 4 + ui;
    dst[q] = packbf(src[(2 * k2) * 64 + j], src[(2 * k2 + 1) * 64 + j]);
  }
}

// ---- node MFMA kernel ----
__global__ __launch_bounds__(256) void vnewproj_k(
    const unsigned* __restrict__ Ab, const unsigned* __restrict__ Cb,
    const int* __restrict__ counts,
    const unsigned* __restrict__ WAF, const unsigned* __restrict__ W0BF,
    const unsigned* __restrict__ Ws0F, const unsigned* __restrict__ Ws2F,
    const float* __restrict__ cg, const float* __restrict__ b0Bg,
    const float* __restrict__ b_S,
    float* __restrict__ Vnew, unsigned* __restrict__ PsP, unsigned* __restrict__ PdP) {
  __shared__ __align__(16) unsigned AF[2048], CF[2048], VF[2048];
  __shared__ float cb[64], b0v[64], bsv[64];
  int tid = threadIdx.x;
  int n0 = blockIdx.x * 64;
  for (int q = tid; q < 2048; q += 256) {
    int r = q >> 5, k2 = q & 31;
    int row = n0 + r;
    if (row >= N_NODES) row = N_NODES - 1;
    unsigned ua = Ab[(size_t)row * 32 + k2];
    unsigned uc = Cb[(size_t)row * 32 + k2];
    int kh = k2 >> 4, k2h = k2 & 15;
    int ln = (r & 15) + 16 * (k2h >> 2);
    int idx = ((((r >> 4) << 1) + kh) * 64 + ln) * 4 + (k2h & 3);
    AF[idx] = ua;
    CF[idx] = uc;
  }
  if (tid < 64) { cb[tid] = cg[tid]; b0v[tid] = b0Bg[tid]; bsv[tid] = b_S[tid]; }
  __syncthreads();

  int lane = tid & 63, et = tid >> 6;
  int col15 = lane & 15, g4 = lane >> 4;
  float deg[4];
#pragma unroll
  for (int reg = 0; reg < 4; ++reg) {
    int rg = n0 + et * 16 + g4 * 4 + reg;
    deg[reg] = (float)counts[rg < N_NODES ? rg : N_NODES - 1];
  }
  f32x4 a0 = {0.f, 0.f, 0.f, 0.f}, a1 = a0, a2 = a0, a3 = a0;
#pragma unroll
  for (int kh = 0; kh < 2; ++kh) {
    uint4 au = *reinterpret_cast<const uint4*>(&AF[(((et << 1) + kh) * 64 + lane) * 4]);
    uint4 cu = *reinterpret_cast<const uint4*>(&CF[(((et << 1) + kh) * 64 + lane) * 4]);
    bf16x8 afr = *reinterpret_cast<bf16x8*>(&au);
    bf16x8 cfr = *reinterpret_cast<bf16x8*>(&cu);
    uint4 wa0 = *reinterpret_cast<const uint4*>(&WAF[((0 * 2 + kh) * 64 + lane) * 4]);
    uint4 wa1 = *reinterpret_cast<const uint4*>(&WAF[((1 * 2 + kh) * 64 + lane) * 4]);
    uint4 wa2 = *reinterpret_cast<const uint4*>(&WAF[((2 * 2 + kh) * 64 + lane) * 4]);
    uint4 wa3 = *reinterpret_cast<const uint4*>(&WAF[((3 * 2 + kh) * 64 + lane) * 4]);
    uint4 wc0 = *reinterpret_cast<const uint4*>(&W0BF[((0 * 2 + kh) * 64 + lane) * 4]);
    uint4 wc1 = *reinterpret_cast<const uint4*>(&W0BF[((1 * 2 + kh) * 64 + lane) * 4]);
    uint4 wc2 = *reinterpret_cast<const uint4*>(&W0BF[((2 * 2 + kh) * 64 + lane) * 4]);
    uint4 wc3 = *reinterpret_cast<const uint4*>(&W0BF[((3 * 2 + kh) * 64 + lane) * 4]);
    a0 = __builtin_amdgcn_mfma_f32_16x16x32_bf16(afr, *reinterpret_cast<bf16x8*>(&wa0), a0, 0, 0, 0);
    a1 = __builtin_amdgcn_mfma_f32_16x16x32_bf16(afr, *reinterpret_cast<bf16x8*>(&wa1), a1, 0, 0, 0);
    a2 = __builtin_amdgcn_mfma_f32_16x16x32_bf16(afr, *reinterpret_cast<bf16x8*>(&wa2), a2, 0, 0, 0);
    a3 = __builtin_amdgcn_mfma_f32_16x16x32_bf16(afr, *reinterpret_cast<bf16x8*>(&wa3), a3, 0, 0, 0);
    a0 = __builtin_amdgcn_mfma_f32_16x16x32_bf16(cfr, *reinterpret_cast<bf16x8*>(&wc0), a0, 0, 0, 0);
    a1 = __builtin_amdgcn_mfma_f32_16x16x32_bf16(cfr, *reinterpret_cast<bf16x8*>(&wc1), a1, 0, 0, 0);
    a2 = __builtin_amdgcn_mfma_f32_16x16x32_bf16(cfr, *reinterpret_cast<bf16x8*>(&wc2), a2, 0, 0, 0);
    a3 = __builtin_amdgcn_mfma_f32_16x16x32_bf16(cfr, *reinterpret_cast<bf16x8*>(&wc3), a3, 0, 0, 0);
  }
#pragma unroll
  for (int jt = 0; jt < 4; ++jt) {
    f32x4 a = (jt == 0) ? a0 : (jt == 1) ? a1 : (jt == 2) ? a2 : a3;
    int j = jt * 16 + col15;
#pragma unroll
    for (int reg = 0; reg < 4; ++reg) {
      float v = a[reg] + fmaf(deg[reg], b0v[j], cb[j]);
      a[reg] = v;
      int rg = n0 + et * 16 + g4 * 4 + reg;
      if (rg < N_NODES) Vnew[(size_t)rg * 64 + j] = v;
    }
#pragma unroll
    for (int reg = 0; reg < 4; ++reg) {
      float v = a[reg];
      float pv = __shfl_xor(v, 1);
      if (!(col15 & 1)) {
        int k2p = jt * 8 + (col15 >> 1);
        int kh2 = k2p >> 4, k2h = k2p & 15;
        int ln = (g4 * 4 + reg) + 16 * (k2h >> 2);
        VF[(((et << 1) + kh2) * 64 + ln) * 4 + (k2h & 3)] = packbf(v, pv);
      }
    }
  }
  __syncthreads();
  f32x4 p0 = {0.f, 0.f, 0.f, 0.f}, p1 = p0, p2 = p0, p3 = p0;
  f32x4 d0 = p0, d1 = p0, d2 = p0, d3 = p0;
#pragma unroll
  for (int kh = 0; kh < 2; ++kh) {
    uint4 vu = *reinterpret_cast<const uint4*>(&VF[(((et << 1) + kh) * 64 + lane) * 4]);
    bf16x8 vfr = *reinterpret_cast<bf16x8*>(&vu);
    uint4 w00 = *reinterpret_cast<const uint4*>(&Ws0F[((0 * 2 + kh) * 64 + lane) * 4]);
    uint4 w01 = *reinterpret_cast<const uint4*>(&Ws0F[((1 * 2 + kh) * 64 + lane) * 4]);
    uint4 w02 = *reinterpret_cast<const uint4*>(&Ws0F[((2 * 2 + kh) * 64 + lane) * 4]);
    uint4 w03 = *reinterpret_cast<const uint4*>(&Ws0F[((3 * 2 + kh) * 64 + lane) * 4]);
    uint4 w20 = *reinterpret_cast<const uint4*>(&Ws2F[((0 * 2 + kh) * 64 + lane) * 4]);
    uint4 w21 = *reinterpret_cast<const uint4*>(&Ws2F[((1 * 2 + kh) * 64 + lane) * 4]);
    uint4 w22 = *reinterpret_cast<const uint4*>(&Ws2F[((2 * 2 + kh) * 64 + lane) * 4]);
    uint4 w23 = *reinterpret_cast<const uint4*>(&Ws2F[((3 * 2 + kh) * 64 + lane) * 4]);
    p0 = __builtin_amdgcn_mfma_f32_16x16x32_bf16(vfr, *reinterpret_cast<bf16x8*>(&w00), p0, 0, 0, 0);
    p1 = __builtin_amdgcn_mfma_f32_16x16x32_bf16(vfr, *reinterpret_cast<bf16x8*>(&w01), p1, 0, 0, 0);
    p2 = __builtin_amdgcn_mfma_f32_16x16x32_bf16(vfr, *reinterpret_cast<bf16x8*>(&w02), p2, 0, 0, 0);
    p3 = __builtin_amdgcn_mfma_f32_16x16x32_bf16(vfr, *reinterpret_cast<bf16x8*>(&w03), p3, 0, 0, 0);
    d0 = __builtin_amdgcn_mfma_f32_16x16x32_bf16(vfr, *reinterpret_cast<bf16x8*>(&w20), d0, 0, 0, 0);
    d1 = __builtin_amdgcn_mfma_f32_16x16x32_bf16(vfr, *reinterpret_cast<bf16x8*>(&w21), d1, 0, 0, 0);
    d2 = __builtin_amdgcn_mfma_f32_16x16x32_bf16(vfr, *reinterpret_cast<bf16x8*>(&w22), d2, 0, 0, 0);
    d3 = __builtin_amdgcn_mfma_f32_16x16x32_bf16(vfr, *reinterpret_cast<bf16x8*>(&w23), d3, 0, 0, 0);
  }
#pragma unroll
  for (int pt = 0; pt < 4; ++pt) {
    f32x4 p = (pt == 0) ? p0 : (pt == 1) ? p1 : (pt == 2) ? p2 : p3;
    f32x4 d = (pt == 0) ? d0 : (pt == 1) ? d1 : (pt == 2) ? d2 : d3;
    int pj = pt * 16 + col15;
#pragma unroll
    for (int reg = 0; reg < 4; ++reg) {
      float vp = p[reg] + bsv[pj];
      float vd = d[reg];
      float pvp = __shfl_xor(vp, 1);
      float pvd = __shfl_xor(vd, 1);
      if (!(col15 & 1)) {
        int rg = n0 + et * 16 + g4 * 4 + reg;
        if (rg < N_NODES) {
          PsP[(size_t)rg * 32 + pt * 8 + (col15 >> 1)] = packbf(vp, pvp);
          PdP[(size_t)rg * 32 + pt * 8 + (col15 >> 1)] = packbf(vd, pvd);
        }
      }
    }
  }
}

// ---- edge MFMA kernel ----
__global__ __launch_bounds__(256) void edge_k(
    const float* __restrict__ Eg, const int* __restrict__ src, const int* __restrict__ dst,
    const unsigned* __restrict__ PsP, const unsigned* __restrict__ PdP,
    const unsigned* __restrict__ WmF, unsigned* __restrict__ EoutSlots,
    float* __restrict__ partials) {
  __shared__ __align__(16) unsigned EaF[2048];
  __shared__ unsigned Spd[64][34];
  __shared__ float ls[128];
  int tid = threadIdx.x;
  int e0 = blockIdx.x * 64;
  int l16 = tid & 15, g16 = tid >> 4;

  uint2 pa[4], pb[4];
#pragma unroll
  for (int rr = 0; rr < 4; ++rr) {
    int p = e0 + rr * 16 + g16;
    int s = src[p], d = dst[p];
    pa[rr] = *reinterpret_cast<const uint2*>(&PsP[(size_t)s * 32 + 2 * l16]);
    pb[rr] = *reinterpret_cast<const uint2*>(&PdP[(size_t)d * 32 + 2 * l16]);
  }
  if (tid < 128) ls[tid] = 0.f;
  for (int q = tid; q < 1024; q += 256) {
    int e = q >> 4, kq = q & 15;
    float4 vv = reinterpret_cast<const float4*>(Eg)[(size_t)(e0 + e) * 16 + kq];
    unsigned u0 = packbf(leaky(vv.x), leaky(vv.y));
    unsigned u1 = packbf(leaky(vv.z), leaky(vv.w));
    int k2a = 2 * kq;
    int kh = k2a >> 4, k2h = k2a & 15;
    int lane = (e & 15) + 16 * (k2h >> 2);
    int base = ((((e >> 4) << 1) + kh) * 64 + lane) * 4 + (k2h & 3);
    EaF[base] = u0;
    EaF[base + 1] = u1;
  }
#pragma unroll
  for (int rr = 0; rr < 4; ++rr) {
    int r = rr * 16 + g16;
    float fx = bflo(pa[rr].x) + bflo(pb[rr].x);
    float fy = bfhi(pa[rr].x) + bfhi(pb[rr].x);
    float fz = bflo(pa[rr].y) + bflo(pb[rr].y);
    float fw = bfhi(pa[rr].y) + bfhi(pb[rr].y);
    *reinterpret_cast<uint2*>(&Spd[r][l16 * 2]) = make_uint2(packbf(fx, fy), packbf(fz, fw));
  }
  __syncthreads();

  int lane = tid & 63;
  int et = tid >> 6;
  f32x4 acc0 = {0.f, 0.f, 0.f, 0.f};
  f32x4 acc1 = acc0, acc2 = acc0, acc3 = acc0;
#pragma unroll
  for (int kh = 0; kh < 2; ++kh) {
    uint4 au = *reinterpret_cast<const uint4*>(&EaF[(((et << 1) + kh) * 64 + lane) * 4]);
    bf16x8 afr = *reinterpret_cast<bf16x8*>(&au);
    uint4 b0 = *reinterpret_cast<const uint4*>(&WmF[((0 * 2 + kh) * 64 + lane) * 4]);
    uint4 b1 = *reinterpret_cast<const uint4*>(&WmF[((1 * 2 + kh) * 64 + lane) * 4]);
    uint4 b2 = *reinterpret_cast<const uint4*>(&WmF[((2 * 2 + kh) * 64 + lane) * 4]);
    uint4 b3 = *reinterpret_cast<const uint4*>(&WmF[((3 * 2 + kh) * 64 + lane) * 4]);
    acc0 = __builtin_amdgcn_mfma_f32_16x16x32_bf16(afr, *reinterpret_cast<bf16x8*>(&b0), acc0, 0, 0, 0);
    acc1 = __builtin_amdgcn_mfma_f32_16x16x32_bf16(afr, *reinterpret_cast<bf16x8*>(&b1), acc1, 0, 0, 0);
    acc2 = __builtin_amdgcn_mfma_f32_16x16x32_bf16(afr, *reinterpret_cast<bf16x8*>(&b2), acc2, 0, 0, 0);
    acc3 = __builtin_amdgcn_mfma_f32_16x16x32_bf16(afr, *reinterpret_cast<bf16x8*>(&b3), acc3, 0, 0, 0);
  }

  int col15 = lane & 15, g4 = lane >> 4;
  float s4[4] = {0.f, 0.f, 0.f, 0.f}, q4[4] = {0.f, 0.f, 0.f, 0.f};
  f32x4 accs[4];
#pragma unroll
  for (int jt = 0; jt < 4; ++jt) {
    f32x4 a = (jt == 0) ? acc0 : (jt == 1) ? acc1 : (jt == 2) ? acc2 : acc3;
#pragma unroll
    for (int reg = 0; reg < 4; ++reg) {
      int e = et * 16 + g4 * 4 + reg;
      int j = jt * 16 + col15;
      unsigned sp = Spd[e][j >> 1];
      float add = (j & 1) ? bfhi(sp) : bflo(sp);
      float v = a[reg] + add;
      a[reg] = v;
      s4[jt] += v;
      q4[jt] = fmaf(v, v, q4[jt]);
    }
    accs[jt] = a;
  }
#pragma unroll
  for (int jt = 0; jt < 4; ++jt) {
#pragma unroll
    for (int reg = 0; reg < 4; ++reg) {
      float v = accs[jt][reg];
      float pv = __shfl_xor(v, 1);
      if (!(col15 & 1)) {
        int e = e0 + et * 16 + g4 * 4 + reg;
        EoutSlots[(size_t)e * 64 + jt * 8 + (col15 >> 1)] = packbf(v, pv);
      }
    }
  }
#pragma unroll
  for (int jt = 0; jt < 4; ++jt) {
    s4[jt] += __shfl_xor(s4[jt], 16);
    q4[jt] += __shfl_xor(q4[jt], 16);
    s4[jt] += __shfl_xor(s4[jt], 32);
    q4[jt] += __shfl_xor(q4[jt], 32);
  }
  if (g4 == 0) {
#pragma unroll
    for (int jt = 0; jt < 4; ++jt) {
      atomicAdd(&ls[jt * 16 + col15], s4[jt]);
      atomicAdd(&ls[64 + jt * 16 + col15], q4[jt]);
    }
  }
  __syncthreads();
  if (tid < 128) partials[(size_t)blockIdx.x * 128 + tid] = ls[tid];
}

// ---- reduce per-block partials ----
__global__ __launch_bounds__(256) void reduce_stats_k(const float* __restrict__ partials,
                                                      float* __restrict__ stats) {
  __shared__ float ls[128];
  int tid = threadIdx.x;
  if (tid < 128) ls[tid] = 0.f;
  __syncthreads();
  int c = tid & 127;
  int half = tid >> 7;
  float s = 0.f;
  for (int r = blockIdx.x * 2 + half; r < NEBLK; r += 2 * gridDim.x) {
    s += partials[(size_t)r * 128 + c];
  }
  atomicAdd(&ls[c], s);
  __syncthreads();
  if (tid < 128) atomicAdd(&stats[tid], ls[tid]);
}

// ---- per-column sum / sumsq (V side) ----
__global__ __launch_bounds__(256) void col_stats_k(
    const float* __restrict__ X, size_t nelem, float* __restrict__ sums) {
  __shared__ float ls[128];
  int tid = threadIdx.x;
  if (tid < 128) ls[tid] = 0.f;
  __syncthreads();
  int j = tid & 63;
  float s = 0.f, ss = 0.f;
  size_t stride = (size_t)gridDim.x * blockDim.x;
  for (size_t i = (size_t)blockIdx.x * blockDim.x + tid; i < nelem; i += stride) {
    float x = X[i];
    s += x;
    ss = fmaf(x, x, ss);
  }
  atomicAdd(&ls[j], s);
  atomicAdd(&ls[64 + j], ss);
  __syncthreads();
  if (tid < 128) atomicAdd(&sums[tid], ls[tid]);
}

__global__ void finalize_k(const float* __restrict__ sums, float inv_n,
                           const float* __restrict__ gamma, const float* __restrict__ beta,
                           float* __restrict__ sc_shift) {
  int j = threadIdx.x;
  float mu = sums[j] * inv_n;
  float var = sums[64 + j] * inv_n - mu * mu;
  float sc = gamma[j] * rsqrtf(var + BN_EPS);
  sc_shift[j] = sc;
  sc_shift[64 + j] = beta[j] - mu * sc;
}

__global__ __launch_bounds__(256) void bn_apply_k(
    float* __restrict__ X, const float* __restrict__ resid,
    const float* __restrict__ sc_shift, int n4) {
  int i = blockIdx.x * blockDim.x + threadIdx.x;
  if (i >= n4) return;
  int jq = i & 15;
  float4 x = reinterpret_cast<float4*>(X)[i];
  float4 r = reinterpret_cast<const float4*>(resid)[i];
  float4 sc = reinterpret_cast<const float4*>(sc_shift)[jq];
  float4 sh = reinterpret_cast<const float4*>(sc_shift + 64)[jq];
  float4 y;
  y.x = leaky(fmaf(x.x, sc.x, sh.x)) + r.x;
  y.y = leaky(fmaf(x.y, sc.y, sh.y)) + r.y;
  y.z = leaky(fmaf(x.z, sc.z, sh.z)) + r.z;
  y.w = leaky(fmaf(x.w, sc.w, sh.w)) + r.w;
  reinterpret_cast<float4*>(X)[i] = y;
}

// ---- E side, coalesced float4-per-thread slot expansion ----
__global__ __launch_bounds__(256) void bn_applyE_k(
    float* __restrict__ EoutF, const float* __restrict__ Eg,
    const float* __restrict__ sc_shift) {
  __shared__ float scs[128];
  int tid = threadIdx.x;
  if (tid < 128) scs[tid] = sc_shift[tid];
  __syncthreads();
  int i = blockIdx.x * 256 + tid;
  int jq = i & 15;
  float2 pr = reinterpret_cast<const float2*>(EoutF)[((size_t)(i >> 4)) * 32 + jq];
  unsigned u0 = __float_as_uint(pr.x);
  unsigned u1 = __float_as_uint(pr.y);
  float v0 = bflo(u0), v1 = bfhi(u0), v2 = bflo(u1), v3 = bfhi(u1);
  float4 eg = reinterpret_cast<const float4*>(Eg)[i];
  int j = jq * 4;
  float4 o;
  o.x = leaky(fmaf(v0, scs[j + 0], scs[64 + j + 0])) + eg.x;
  o.y = leaky(fmaf(v1, scs[j + 1], scs[64 + j + 1])) + eg.y;
  o.z = leaky(fmaf(v2, scs[j + 2], scs[64 + j + 2])) + eg.z;
  o.w = leaky(fmaf(v3, scs[j + 3], scs[64 + j + 3])) + eg.w;
  reinterpret_cast<float4*>(EoutF)[i] = o;
}

extern "C" void kernel_launch(void* const* d_in, const int* in_sizes, int n_in,
                              void* d_out, int out_size, void* d_ws, size_t ws_size,
                              hipStream_t stream) {
  const float* V      = (const float*)d_in[0];
  const float* Eg     = (const float*)d_in[1];
  const int*   src    = (const int*)d_in[2];
  const int*   dst    = (const int*)d_in[3];
  const float* W_ops  = (const float*)d_in[4];
  const float* b_ops  = (const float*)d_in[5];
  const float* W_cat  = (const float*)d_in[6];
  const float* b_cat  = (const float*)d_in[7];
  const float* W_S    = (const float*)d_in[8];
  const float* b_S    = (const float*)d_in[9];
  const float* gammaV = (const float*)d_in[10];
  const float* betaV  = (const float*)d_in[11];
  const float* gammaE = (const float*)d_in[12];
  const float* betaE  = (const float*)d_in[13];

  float* ws = (float*)d_ws;
  const size_t ND = (size_t)N_NODES * 64;
  const size_t NH = (size_t)N_NODES * 32;
  unsigned* Vb  = (unsigned*)ws;
  unsigned* Ab  = (unsigned*)ws + NH;
  unsigned* Cb  = (unsigned*)ws + 2 * NH;
  unsigned* PsP = (unsigned*)ws + 3 * NH;
  unsigned* PdP = (unsigned*)ws + 4 * NH;
  float* xb   = ws + 5 * NH;
  float* W12g  = xb;
  float* Wc12g = xb + 4096;
  float* WAg   = xb + 8192;
  float* WBg   = xb + 12288;
  float* W0Bg  = xb + 16384;
  float* cg    = xb + 20480;
  float* b0Bg  = xb + 20544;
  float* statsV = xb + 20608;
  float* statsE = statsV + 128;
  float* scshV  = statsV + 256;
  float* scshE  = statsV + 384;
  int* counts = (int*)(statsV + 512);
  int* offs   = counts + N_NODES;
  int* cursor = offs + N_NODES + 1;
  int* ssrc   = cursor + N_NODES;
  float* partials = (float*)(ssrc + M_EDGES);
  unsigned* WAF  = (unsigned*)(partials + (size_t)NEBLK * 128);
  unsigned* W0BF = WAF + 2048;
  unsigned* Ws0F = WAF + 4096;
  unsigned* Ws2F = WAF + 6144;
  unsigned* WmF  = WAF + 8192;
  int* bsum = (int*)(WAF + 10240);   // NSB ints

  float* Vout  = (float*)d_out;
  float* EoutF = Vout + ND;
  unsigned* EoutSlots = (unsigned*)EoutF;

  hipMemsetAsync(counts, 0, N_NODES * sizeof(int), stream);
  hipMemsetAsync(statsV, 0, 256 * sizeof(float), stream);

  const int eb = (M_EDGES + 255) / 256;
  prep1_k<<<2, 256, 0, stream>>>(W_ops, W_cat, W12g, Wc12g);
  prep2_k<<<2, 256, 0, stream>>>(W_ops, b_ops, W_cat, b_cat, W12g, Wc12g, WAg, WBg, cg);
  prep3_k<<<1, 256, 0, stream>>>(W_ops, b_ops, WBg, W0Bg, b0Bg);
  prepW_k<<<5, 256, 0, stream>>>(WAg, W0Bg, W_S, WAF, W0BF, Ws0F, Ws2F, WmF);
  hist_k<<<eb, 256, 0, stream>>>(dst, counts);
  blocksum_k<<<NSB, 256, 0, stream>>>(counts, bsum);
  scanb_k<<<1, 256, 0, stream>>>(bsum);
  offs_k<<<NSB, 256, 0, stream>>>(counts, bsum, offs, cursor);
  fill_k<<<eb, 256, 0, stream>>>(src, dst, cursor, ssrc);

  convbf_k<<<(N_NODES * 8 + 255) / 256, 256, 0, stream>>>(V, Vb, N_NODES * 8);
  gatherb_k<<<N_NODES / 4, 256, 0, stream>>>(Vb, offs, ssrc, Ab);
  gatherb_k<<<N_NODES / 4, 256, 0, stream>>>(Ab, offs, ssrc, Cb);
  vnewproj_k<<<NVBLK, 256, 0, stream>>>(Ab, Cb, counts, WAF, W0BF, Ws0F, Ws2F,
                                        cg, b0Bg, b_S, Vout, PsP, PdP);
  edge_k<<<NEBLK, 256, 0, stream>>>(Eg, src, dst, PsP, PdP, WmF, EoutSlots, partials);
  reduce_stats_k<<<64, 256, 0, stream>>>(partials, statsE);
  col_stats_k<<<512, 256, 0, stream>>>(Vout, ND, statsV);
  finalize_k<<<1, 64, 0, stream>>>(statsV, 1.f / N_NODES, gammaV, betaV, scshV);
  finalize_k<<<1, 64, 0, stream>>>(statsE, 1.f / M_EDGES, gammaE, betaE, scshE);
  bn_apply_k<<<(int)((ND / 4 + 255) / 256), 256, 0, stream>>>(Vout, V, scshV, (int)(ND / 4));
  bn_applyE_k<<<M_EDGES * 16 / 256, 256, 0, stream>>>(EoutF, Eg, scshE);
}

// Round 15
// 457.105 us; speedup vs baseline: 1.9882x; 1.0380x over previous
//
#include <hip/hip_runtime.h>
#include <hip/hip_bf16.h>

#define N_NODES 50000
#define M_EDGES 800000
#define LEAKY_F 0.2f
#define BN_EPS 1e-5f
#define NEBLK (M_EDGES / 64)
#define NVBLK ((N_NODES + 63) / 64)
#define NSB ((N_NODES + 255) / 256)

typedef short bf16x8 __attribute__((ext_vector_type(8)));
typedef float f32x4 __attribute__((ext_vector_type(4)));

__device__ __forceinline__ float leaky(float x) { return x >= 0.f ? x : LEAKY_F * x; }

__device__ __forceinline__ unsigned f2bf(float f) {
  unsigned u = __float_as_uint(f);
  return (u + 0x7fffu + ((u >> 16) & 1u)) >> 16;
}
__device__ __forceinline__ unsigned packbf(float a, float b) {
  return (f2bf(b) << 16) | f2bf(a);
}
__device__ __forceinline__ float bflo(unsigned u) { return __uint_as_float(u << 16); }
__device__ __forceinline__ float bfhi(unsigned u) { return __uint_as_float(u & 0xffff0000u); }

// ================= CSR build =================
__global__ __launch_bounds__(256) void hist_k(const int* __restrict__ dst,
                                              int* __restrict__ counts) {
  int e = blockIdx.x * 256 + threadIdx.x;
  if (e < M_EDGES) atomicAdd(&counts[dst[e]], 1);
}

__global__ __launch_bounds__(256) void blocksum_k(const int* __restrict__ counts,
                                                  int* __restrict__ bsum) {
  __shared__ int wsum[4];
  int tid = threadIdx.x;
  int i = blockIdx.x * 256 + tid;
  int v = (i < N_NODES) ? counts[i] : 0;
#pragma unroll
  for (int off = 32; off; off >>= 1) v += __shfl_down(v, off);
  if ((tid & 63) == 0) wsum[tid >> 6] = v;
  __syncthreads();
  if (tid == 0) bsum[blockIdx.x] = wsum[0] + wsum[1] + wsum[2] + wsum[3];
}

__global__ __launch_bounds__(256) void scanb_k(int* __restrict__ bsum) {
  __shared__ int s[256];
  int tid = threadIdx.x;
  s[tid] = (tid < NSB) ? bsum[tid] : 0;
  __syncthreads();
  for (int off = 1; off < 256; off <<= 1) {
    int v = 0;
    if (tid >= off) v = s[tid - off];
    __syncthreads();
    if (tid >= off) s[tid] += v;
    __syncthreads();
  }
  if (tid < NSB) bsum[tid] = (tid == 0) ? 0 : s[tid - 1];
}

__global__ __launch_bounds__(256) void offs_k(const int* __restrict__ counts,
                                              const int* __restrict__ bsum,
                                              int* __restrict__ offs,
                                              int* __restrict__ cursor) {
  __shared__ int s[256];
  int tid = threadIdx.x;
  int i = blockIdx.x * 256 + tid;
  int c = (i < N_NODES) ? counts[i] : 0;
  s[tid] = c;
  __syncthreads();
  for (int off = 1; off < 256; off <<= 1) {
    int v = 0;
    if (tid >= off) v = s[tid - off];
    __syncthreads();
    if (tid >= off) s[tid] += v;
    __syncthreads();
  }
  int excl = s[tid] - c + bsum[blockIdx.x];
  if (i < N_NODES) {
    offs[i] = excl;
    cursor[i] = excl;
  }
  if (i == N_NODES - 1) offs[N_NODES] = M_EDGES;
}

__global__ __launch_bounds__(256) void fill_k(const int* __restrict__ src,
                                              const int* __restrict__ dst,
                                              int* __restrict__ cursor,
                                              int* __restrict__ ssrc) {
  int e = blockIdx.x * 256 + threadIdx.x;
  if (e >= M_EDGES) return;
  int p = atomicAdd(&cursor[dst[e]], 1);
  ssrc[p] = src[e];
}

// ---- f32 rows -> packed bf16 rows ----
__global__ __launch_bounds__(256) void convbf_k(const float* __restrict__ X,
                                                unsigned* __restrict__ Xb, int n4) {
  int i = blockIdx.x * 256 + threadIdx.x;
  if (i >= n4) return;
  const float4* s4 = reinterpret_cast<const float4*>(X) + (size_t)i * 2;
  float4 a = s4[0], b = s4[1];
  uint4 o;
  o.x = packbf(a.x, a.y);
  o.y = packbf(a.z, a.w);
  o.z = packbf(b.x, b.y);
  o.w = packbf(b.z, b.w);
  reinterpret_cast<uint4*>(Xb)[i] = o;
}

// ---- segment gather-sum; wave per node, 4x 16-lane groups with uint2 loads ----
__global__ __launch_bounds__(256) void gatherb_k(const unsigned* __restrict__ Xb,
                                                 const int* __restrict__ offs,
                                                 const int* __restrict__ ssrc,
                                                 unsigned* __restrict__ Ob) {
  int n = blockIdx.x * 4 + (threadIdx.x >> 6);
  int lane = threadIdx.x & 63;
  int grp = lane >> 4, col = lane & 15;
  int beg = offs[n], end = offs[n + 1];
  float a0 = 0.f, a1 = 0.f, a2 = 0.f, a3 = 0.f;
  int i = beg + grp;
  for (; i + 4 < end; i += 8) {
    int s0 = ssrc[i], s1 = ssrc[i + 4];
    uint2 u0 = *reinterpret_cast<const uint2*>(&Xb[(size_t)s0 * 32 + col * 2]);
    uint2 u1 = *reinterpret_cast<const uint2*>(&Xb[(size_t)s1 * 32 + col * 2]);
    a0 += bflo(u0.x) + bflo(u1.x);
    a1 += bfhi(u0.x) + bfhi(u1.x);
    a2 += bflo(u0.y) + bflo(u1.y);
    a3 += bfhi(u0.y) + bfhi(u1.y);
  }
  for (; i < end; i += 4) {
    uint2 u = *reinterpret_cast<const uint2*>(&Xb[(size_t)ssrc[i] * 32 + col * 2]);
    a0 += bflo(u.x);
    a1 += bfhi(u.x);
    a2 += bflo(u.y);
    a3 += bfhi(u.y);
  }
#pragma unroll
  for (int off = 16; off <= 32; off <<= 1) {
    a0 += __shfl_xor(a0, off);
    a1 += __shfl_xor(a1, off);
    a2 += __shfl_xor(a2, off);
    a3 += __shfl_xor(a3, off);
  }
  if (grp == 0) {
    uint2 o = make_uint2(packbf(a0, a1), packbf(a2, a3));
    *reinterpret_cast<uint2*>(&Ob[(size_t)n * 32 + col * 2]) = o;
  }
}

// ================= weight-prep (algebraic collapse) =================
__global__ __launch_bounds__(256) void prep1_k(const float* __restrict__ W_ops,
                                               const float* __restrict__ W_cat,
                                               float* __restrict__ W12g,
                                               float* __restrict__ Wc12g) {
  __shared__ float Wa[4096], Wb[4096];
  int tid = threadIdx.x;
  const float *Am, *Bm, *Add;
  float* Out;
  if (blockIdx.x == 0) { Am = W_ops; Bm = W_ops + 8192; Add = W_ops + 4096; Out = W12g; }
  else { Am = W_ops + 16384; Bm = W_cat + 8192; Add = W_cat + 4096; Out = Wc12g; }
  for (int i = tid; i < 4096; i += 256) { Wa[i] = Am[i]; Wb[i] = Bm[i]; }
  __syncthreads();
  for (int t = 0; t < 16; ++t) {
    int o = tid + t * 256;
    int r = o >> 6, j = o & 63;
    float acc = Add[o];
#pragma unroll
    for (int k = 0; k < 64; ++k) acc = fmaf(Wa[r * 64 + k], Wb[k * 64 + j], acc);
    Out[o] = acc;
  }
}

__global__ __launch_bounds__(256) void prep2_k(const float* __restrict__ W_ops,
                                               const float* __restrict__ b_ops,
                                               const float* __restrict__ W_cat,
                                               const float* __restrict__ b_cat,
                                               const float* __restrict__ W12g,
                                               const float* __restrict__ Wc12g,
                                               float* __restrict__ WAg,
                                               float* __restrict__ WBg,
                                               float* __restrict__ cg) {
  __shared__ float M0[4096], M1[4096], M2[4096], M3[4096], M4[4096];
  __shared__ float bb[64];
  int tid = threadIdx.x;
  if (blockIdx.x == 0) {
    for (int i = tid; i < 4096; i += 256) {
      M0[i] = W_ops[i];
      M1[i] = W_cat[i];
      M2[i] = W12g[i];
      M3[i] = Wc12g[i];
    }
    __syncthreads();
    for (int t = 0; t < 16; ++t) {
      int o = tid + t * 256;
      int r = o >> 6, j = o & 63;
      float acc = 0.f;
#pragma unroll
      for (int k = 0; k < 64; ++k) {
        acc = fmaf(M0[r * 64 + k], M1[k * 64 + j], acc);
        acc = fmaf(M2[r * 64 + k], M3[k * 64 + j], acc);
      }
      WAg[o] = acc;
    }
  } else {
    for (int i = tid; i < 4096; i += 256) {
      M0[i] = W_ops[3 * 4096 + i];
      M1[i] = W_cat[8192 + i];
      M2[i] = W_ops[2 * 4096 + i];
      M3[i] = W_cat[i];
      M4[i] = Wc12g[i];
    }
    __syncthreads();
    for (int t = 0; t < 16; ++t) {
      int o = tid + t * 256;
      int r = o >> 6, j = o & 63;
      float acc = 0.f;
#pragma unroll
      for (int k = 0; k < 64; ++k) acc = fmaf(M0[r * 64 + k], M1[k * 64 + j], acc);
      WBg[o] = acc;
    }
    if (tid < 64) {
      int j = tid;
      float acc = b_ops[64 + j] + b_ops[128 + j];
#pragma unroll
      for (int k = 0; k < 64; ++k) acc = fmaf(b_ops[k], M2[k * 64 + j], acc);
      bb[j] = acc;
    }
    __syncthreads();
    if (tid < 64) {
      int j = tid;
      float acc = b_cat[j];
#pragma unroll
      for (int k = 0; k < 64; ++k) {
        acc = fmaf(b_ops[k], M3[k * 64 + j], acc);
        acc = fmaf(bb[k], M4[k * 64 + j], acc);
        acc = fmaf(b_ops[192 + k] + b_ops[256 + k], M1[k * 64 + j], acc);
      }
      cg[j] = acc;
    }
  }
}

__global__ __launch_bounds__(256) void prep3_k(const float* __restrict__ W_ops,
                                               const float* __restrict__ b_ops,
                                               const float* __restrict__ WBg,
                                               float* __restrict__ W0Bg,
                                               float* __restrict__ b0Bg) {
  __shared__ float Wa[4096], Wb[4096];
  int tid = threadIdx.x;
  for (int i = tid; i < 4096; i += 256) { Wa[i] = W_ops[i]; Wb[i] = WBg[i]; }
  __syncthreads();
  for (int t = 0; t < 16; ++t) {
    int o = tid + t * 256;
    int r = o >> 6, j = o & 63;
    float acc = 0.f;
#pragma unroll
    for (int k = 0; k < 64; ++k) acc = fmaf(Wa[r * 64 + k], Wb[k * 64 + j], acc);
    W0Bg[o] = acc;
  }
  if (tid < 64) {
    float acc = 0.f;
#pragma unroll
    for (int k = 0; k < 64; ++k) acc = fmaf(b_ops[k], Wb[k * 64 + tid], acc);
    b0Bg[tid] = acc;
  }
}

// prepW: fragment-ordered packed-bf16 weight tables
__global__ __launch_bounds__(256) void prepW_k(
    const float* __restrict__ WAg, const float* __restrict__ W0Bg,
    const float* __restrict__ W_S,
    unsigned* __restrict__ WAF, unsigned* __restrict__ W0BF,
    unsigned* __restrict__ Ws0F, unsigned* __restrict__ Ws2F,
    unsigned* __restrict__ WmF) {
  const float* src;
  unsigned* dst;
  switch (blockIdx.x) {
    case 0: src = WAg; dst = WAF; break;
    case 1: src = W0Bg; dst = W0BF; break;
    case 2: src = W_S; dst = Ws0F; break;
    case 3: src = W_S + 8192; dst = Ws2F; break;
    default: src = W_S + 4096; dst = WmF; break;
  }
  for (int q = threadIdx.x; q < 2048; q += 256) {
    int ui = q & 3, ln = (q >> 2) & 63, t = q >> 8;
    int jt = t >> 1, kh = t & 1;
    int j = jt * 16 + (ln & 15);
    int k2 = kh * 16 + (ln >> 4) * 4 + ui;
    dst[q] = packbf(src[(2 * k2) * 64 + j], src[(2 * k2 + 1) * 64 + j]);
  }
}

// ---- node MFMA kernel: fused C-gather + Vnew + V-stats + proj ----
__global__ __launch_bounds__(256) void vnewproj_k(
    const unsigned* __restrict__ Ab,
    const int* __restrict__ offs, const int* __restrict__ ssrc,
    const int* __restrict__ counts,
    const unsigned* __restrict__ WAF, const unsigned* __restrict__ W0BF,
    const unsigned* __restrict__ Ws0F, const unsigned* __restrict__ Ws2F,
    const float* __restrict__ cg, const float* __restrict__ b0Bg,
    const float* __restrict__ b_S,
    float* __restrict__ Vnew, unsigned* __restrict__ PsP, unsigned* __restrict__ PdP,
    float* __restrict__ partialsV) {
  __shared__ __align__(16) unsigned AF[2048], CF[2048], VF[2048];
  __shared__ float cb[64], b0v[64], bsv[64];
  __shared__ float lsv[128];
  int tid = threadIdx.x;
  int n0 = blockIdx.x * 64;
  int l16 = tid & 15, g16 = tid >> 4;
  // gather C fragments directly via CSR (group of 16 lanes per row)
#pragma unroll
  for (int rr = 0; rr < 4; ++rr) {
    int r = g16 + 16 * rr;
    int n = n0 + r;
    float a0 = 0.f, a1 = 0.f, a2 = 0.f, a3 = 0.f;
    if (n < N_NODES) {
      int beg = offs[n], end = offs[n + 1];
      int i = beg;
      for (; i + 1 < end; i += 2) {
        int s0 = ssrc[i], s1 = ssrc[i + 1];
        uint2 u0 = *reinterpret_cast<const uint2*>(&Ab[(size_t)s0 * 32 + l16 * 2]);
        uint2 u1 = *reinterpret_cast<const uint2*>(&Ab[(size_t)s1 * 32 + l16 * 2]);
        a0 += bflo(u0.x) + bflo(u1.x);
        a1 += bfhi(u0.x) + bfhi(u1.x);
        a2 += bflo(u0.y) + bflo(u1.y);
        a3 += bfhi(u0.y) + bfhi(u1.y);
      }
      if (i < end) {
        uint2 u = *reinterpret_cast<const uint2*>(&Ab[(size_t)ssrc[i] * 32 + l16 * 2]);
        a0 += bflo(u.x);
        a1 += bfhi(u.x);
        a2 += bflo(u.y);
        a3 += bfhi(u.y);
      }
    }
    unsigned pu0 = packbf(a0, a1), pu1 = packbf(a2, a3);
    int k2 = 2 * l16;
    int kh = k2 >> 4, k2h = k2 & 15;
    int ln = (r & 15) + 16 * (k2h >> 2);
    int base = ((((r >> 4) << 1) + kh) * 64 + ln) * 4 + (k2h & 3);
    CF[base] = pu0;
    CF[base + 1] = pu1;
  }
  // stage A fragments (coalesced rows)
  for (int q = tid; q < 2048; q += 256) {
    int r = q >> 5, k2 = q & 31;
    int row = n0 + r;
    if (row >= N_NODES) row = N_NODES - 1;
    unsigned ua = Ab[(size_t)row * 32 + k2];
    int kh = k2 >> 4, k2h = k2 & 15;
    int ln = (r & 15) + 16 * (k2h >> 2);
    AF[((((r >> 4) << 1) + kh) * 64 + ln) * 4 + (k2h & 3)] = ua;
  }
  if (tid < 64) { cb[tid] = cg[tid]; b0v[tid] = b0Bg[tid]; bsv[tid] = b_S[tid]; }
  if (tid < 128) lsv[tid] = 0.f;
  __syncthreads();

  int lane = tid & 63, et = tid >> 6;
  int col15 = lane & 15, g4 = lane >> 4;
  float deg[4];
#pragma unroll
  for (int reg = 0; reg < 4; ++reg) {
    int rg = n0 + et * 16 + g4 * 4 + reg;
    deg[reg] = (float)counts[rg < N_NODES ? rg : N_NODES - 1];
  }
  f32x4 a0 = {0.f, 0.f, 0.f, 0.f}, a1 = a0, a2 = a0, a3 = a0;
#pragma unroll
  for (int kh = 0; kh < 2; ++kh) {
    uint4 au = *reinterpret_cast<const uint4*>(&AF[(((et << 1) + kh) * 64 + lane) * 4]);
    uint4 cu = *reinterpret_cast<const uint4*>(&CF[(((et << 1) + kh) * 64 + lane) * 4]);
    bf16x8 afr = *reinterpret_cast<bf16x8*>(&au);
    bf16x8 cfr = *reinterpret_cast<bf16x8*>(&cu);
    uint4 wa0 = *reinterpret_cast<const uint4*>(&WAF[((0 * 2 + kh) * 64 + lane) * 4]);
    uint4 wa1 = *reinterpret_cast<const uint4*>(&WAF[((1 * 2 + kh) * 64 + lane) * 4]);
    uint4 wa2 = *reinterpret_cast<const uint4*>(&WAF[((2 * 2 + kh) * 64 + lane) * 4]);
    uint4 wa3 = *reinterpret_cast<const uint4*>(&WAF[((3 * 2 + kh) * 64 + lane) * 4]);
    uint4 wc0 = *reinterpret_cast<const uint4*>(&W0BF[((0 * 2 + kh) * 64 + lane) * 4]);
    uint4 wc1 = *reinterpret_cast<const uint4*>(&W0BF[((1 * 2 + kh) * 64 + lane) * 4]);
    uint4 wc2 = *reinterpret_cast<const uint4*>(&W0BF[((2 * 2 + kh) * 64 + lane) * 4]);
    uint4 wc3 = *reinterpret_cast<const uint4*>(&W0BF[((3 * 2 + kh) * 64 + lane) * 4]);
    a0 = __builtin_amdgcn_mfma_f32_16x16x32_bf16(afr, *reinterpret_cast<bf16x8*>(&wa0), a0, 0, 0, 0);
    a1 = __builtin_amdgcn_mfma_f32_16x16x32_bf16(afr, *reinterpret_cast<bf16x8*>(&wa1), a1, 0, 0, 0);
    a2 = __builtin_amdgcn_mfma_f32_16x16x32_bf16(afr, *reinterpret_cast<bf16x8*>(&wa2), a2, 0, 0, 0);
    a3 = __builtin_amdgcn_mfma_f32_16x16x32_bf16(afr, *reinterpret_cast<bf16x8*>(&wa3), a3, 0, 0, 0);
    a0 = __builtin_amdgcn_mfma_f32_16x16x32_bf16(cfr, *reinterpret_cast<bf16x8*>(&wc0), a0, 0, 0, 0);
    a1 = __builtin_amdgcn_mfma_f32_16x16x32_bf16(cfr, *reinterpret_cast<bf16x8*>(&wc1), a1, 0, 0, 0);
    a2 = __builtin_amdgcn_mfma_f32_16x16x32_bf16(cfr, *reinterpret_cast<bf16x8*>(&wc2), a2, 0, 0, 0);
    a3 = __builtin_amdgcn_mfma_f32_16x16x32_bf16(cfr, *reinterpret_cast<bf16x8*>(&wc3), a3, 0, 0, 0);
  }
  float s4[4] = {0.f, 0.f, 0.f, 0.f}, q4[4] = {0.f, 0.f, 0.f, 0.f};
#pragma unroll
  for (int jt = 0; jt < 4; ++jt) {
    f32x4 a = (jt == 0) ? a0 : (jt == 1) ? a1 : (jt == 2) ? a2 : a3;
    int j = jt * 16 + col15;
#pragma unroll
    for (int reg = 0; reg < 4; ++reg) {
      float v = a[reg] + fmaf(deg[reg], b0v[j], cb[j]);
      a[reg] = v;
      int rg = n0 + et * 16 + g4 * 4 + reg;
      if (rg < N_NODES) {
        Vnew[(size_t)rg * 64 + j] = v;
        s4[jt] += v;
        q4[jt] = fmaf(v, v, q4[jt]);
      }
    }
#pragma unroll
    for (int reg = 0; reg < 4; ++reg) {
      float v = a[reg];
      float pv = __shfl_xor(v, 1);
      if (!(col15 & 1)) {
        int k2p = jt * 8 + (col15 >> 1);
        int kh2 = k2p >> 4, k2h = k2p & 15;
        int ln = (g4 * 4 + reg) + 16 * (k2h >> 2);
        VF[(((et << 1) + kh2) * 64 + ln) * 4 + (k2h & 3)] = packbf(v, pv);
      }
    }
  }
  // V-stats reduce (same scheme as edge_k)
#pragma unroll
  for (int jt = 0; jt < 4; ++jt) {
    s4[jt] += __shfl_xor(s4[jt], 16);
    q4[jt] += __shfl_xor(q4[jt], 16);
    s4[jt] += __shfl_xor(s4[jt], 32);
    q4[jt] += __shfl_xor(q4[jt], 32);
  }
  if (g4 == 0) {
#pragma unroll
    for (int jt = 0; jt < 4; ++jt) {
      atomicAdd(&lsv[jt * 16 + col15], s4[jt]);
      atomicAdd(&lsv[64 + jt * 16 + col15], q4[jt]);
    }
  }
  __syncthreads();
  if (tid < 128) partialsV[(size_t)blockIdx.x * 128 + tid] = lsv[tid];

  // stage 2: Ps = VF@Ws0 + bS ; Pd = VF@Ws2
  f32x4 p0 = {0.f, 0.f, 0.f, 0.f}, p1 = p0, p2 = p0, p3 = p0;
  f32x4 d0 = p0, d1 = p0, d2 = p0, d3 = p0;
#pragma unroll
  for (int kh = 0; kh < 2; ++kh) {
    uint4 vu = *reinterpret_cast<const uint4*>(&VF[(((et << 1) + kh) * 64 + lane) * 4]);
    bf16x8 vfr = *reinterpret_cast<bf16x8*>(&vu);
    uint4 w00 = *reinterpret_cast<const uint4*>(&Ws0F[((0 * 2 + kh) * 64 + lane) * 4]);
    uint4 w01 = *reinterpret_cast<const uint4*>(&Ws0F[((1 * 2 + kh) * 64 + lane) * 4]);
    uint4 w02 = *reinterpret_cast<const uint4*>(&Ws0F[((2 * 2 + kh) * 64 + lane) * 4]);
    uint4 w03 = *reinterpret_cast<const uint4*>(&Ws0F[((3 * 2 + kh) * 64 + lane) * 4]);
    uint4 w20 = *reinterpret_cast<const uint4*>(&Ws2F[((0 * 2 + kh) * 64 + lane) * 4]);
    uint4 w21 = *reinterpret_cast<const uint4*>(&Ws2F[((1 * 2 + kh) * 64 + lane) * 4]);
    uint4 w22 = *reinterpret_cast<const uint4*>(&Ws2F[((2 * 2 + kh) * 64 + lane) * 4]);
    uint4 w23 = *reinterpret_cast<const uint4*>(&Ws2F[((3 * 2 + kh) * 64 + lane) * 4]);
    p0 = __builtin_amdgcn_mfma_f32_16x16x32_bf16(vfr, *reinterpret_cast<bf16x8*>(&w00), p0, 0, 0, 0);
    p1 = __builtin_amdgcn_mfma_f32_16x16x32_bf16(vfr, *reinterpret_cast<bf16x8*>(&w01), p1, 0, 0, 0);
    p2 = __builtin_amdgcn_mfma_f32_16x16x32_bf16(vfr, *reinterpret_cast<bf16x8*>(&w02), p2, 0, 0, 0);
    p3 = __builtin_amdgcn_mfma_f32_16x16x32_bf16(vfr, *reinterpret_cast<bf16x8*>(&w03), p3, 0, 0, 0);
    d0 = __builtin_amdgcn_mfma_f32_16x16x32_bf16(vfr, *reinterpret_cast<bf16x8*>(&w20), d0, 0, 0, 0);
    d1 = __builtin_amdgcn_mfma_f32_16x16x32_bf16(vfr, *reinterpret_cast<bf16x8*>(&w21), d1, 0, 0, 0);
    d2 = __builtin_amdgcn_mfma_f32_16x16x32_bf16(vfr, *reinterpret_cast<bf16x8*>(&w22), d2, 0, 0, 0);
    d3 = __builtin_amdgcn_mfma_f32_16x16x32_bf16(vfr, *reinterpret_cast<bf16x8*>(&w23), d3, 0, 0, 0);
  }
#pragma unroll
  for (int pt = 0; pt < 4; ++pt) {
    f32x4 p = (pt == 0) ? p0 : (pt == 1) ? p1 : (pt == 2) ? p2 : p3;
    f32x4 d = (pt == 0) ? d0 : (pt == 1) ? d1 : (pt == 2) ? d2 : d3;
    int pj = pt * 16 + col15;
#pragma unroll
    for (int reg = 0; reg < 4; ++reg) {
      float vp = p[reg] + bsv[pj];
      float vd = d[reg];
      float pvp = __shfl_xor(vp, 1);
      float pvd = __shfl_xor(vd, 1);
      if (!(col15 & 1)) {
        int rg = n0 + et * 16 + g4 * 4 + reg;
        if (rg < N_NODES) {
          PsP[(size_t)rg * 32 + pt * 8 + (col15 >> 1)] = packbf(vp, pvp);
          PdP[(size_t)rg * 32 + pt * 8 + (col15 >> 1)] = packbf(vd, pvd);
        }
      }
    }
  }
}

// ---- edge MFMA kernel ----
__global__ __launch_bounds__(256) void edge_k(
    const float* __restrict__ Eg, const int* __restrict__ src, const int* __restrict__ dst,
    const unsigned* __restrict__ PsP, const unsigned* __restrict__ PdP,
    const unsigned* __restrict__ WmF, unsigned* __restrict__ EoutSlots,
    float* __restrict__ partials) {
  __shared__ __align__(16) unsigned EaF[2048];
  __shared__ unsigned Spd[64][34];
  __shared__ float ls[128];
  int tid = threadIdx.x;
  int e0 = blockIdx.x * 64;
  int l16 = tid & 15, g16 = tid >> 4;

  uint2 pa[4], pb[4];
#pragma unroll
  for (int rr = 0; rr < 4; ++rr) {
    int p = e0 + rr * 16 + g16;
    int s = src[p], d = dst[p];
    pa[rr] = *reinterpret_cast<const uint2*>(&PsP[(size_t)s * 32 + 2 * l16]);
    pb[rr] = *reinterpret_cast<const uint2*>(&PdP[(size_t)d * 32 + 2 * l16]);
  }
  if (tid < 128) ls[tid] = 0.f;
  for (int q = tid; q < 1024; q += 256) {
    int e = q >> 4, kq = q & 15;
    float4 vv = reinterpret_cast<const float4*>(Eg)[(size_t)(e0 + e) * 16 + kq];
    unsigned u0 = packbf(leaky(vv.x), leaky(vv.y));
    unsigned u1 = packbf(leaky(vv.z), leaky(vv.w));
    int k2a = 2 * kq;
    int kh = k2a >> 4, k2h = k2a & 15;
    int lane = (e & 15) + 16 * (k2h >> 2);
    int base = ((((e >> 4) << 1) + kh) * 64 + lane) * 4 + (k2h & 3);
    EaF[base] = u0;
    EaF[base + 1] = u1;
  }
#pragma unroll
  for (int rr = 0; rr < 4; ++rr) {
    int r = rr * 16 + g16;
    float fx = bflo(pa[rr].x) + bflo(pb[rr].x);
    float fy = bfhi(pa[rr].x) + bfhi(pb[rr].x);
    float fz = bflo(pa[rr].y) + bflo(pb[rr].y);
    float fw = bfhi(pa[rr].y) + bfhi(pb[rr].y);
    *reinterpret_cast<uint2*>(&Spd[r][l16 * 2]) = make_uint2(packbf(fx, fy), packbf(fz, fw));
  }
  __syncthreads();

  int lane = tid & 63;
  int et = tid >> 6;
  f32x4 acc0 = {0.f, 0.f, 0.f, 0.f};
  f32x4 acc1 = acc0, acc2 = acc0, acc3 = acc0;
#pragma unroll
  for (int kh = 0; kh < 2; ++kh) {
    uint4 au = *reinterpret_cast<const uint4*>(&EaF[(((et << 1) + kh) * 64 + lane) * 4]);
    bf16x8 afr = *reinterpret_cast<bf16x8*>(&au);
    uint4 b0 = *reinterpret_cast<const uint4*>(&WmF[((0 * 2 + kh) * 64 + lane) * 4]);
    uint4 b1 = *reinterpret_cast<const uint4*>(&WmF[((1 * 2 + kh) * 64 + lane) * 4]);
    uint4 b2 = *reinterpret_cast<const uint4*>(&WmF[((2 * 2 + kh) * 64 + lane) * 4]);
    uint4 b3 = *reinterpret_cast<const uint4*>(&WmF[((3 * 2 + kh) * 64 + lane) * 4]);
    acc0 = __builtin_amdgcn_mfma_f32_16x16x32_bf16(afr, *reinterpret_cast<bf16x8*>(&b0), acc0, 0, 0, 0);
    acc1 = __builtin_amdgcn_mfma_f32_16x16x32_bf16(afr, *reinterpret_cast<bf16x8*>(&b1), acc1, 0, 0, 0);
    acc2 = __builtin_amdgcn_mfma_f32_16x16x32_bf16(afr, *reinterpret_cast<bf16x8*>(&b2), acc2, 0, 0, 0);
    acc3 = __builtin_amdgcn_mfma_f32_16x16x32_bf16(afr, *reinterpret_cast<bf16x8*>(&b3), acc3, 0, 0, 0);
  }

  int col15 = lane & 15, g4 = lane >> 4;
  float s4[4] = {0.f, 0.f, 0.f, 0.f}, q4[4] = {0.f, 0.f, 0.f, 0.f};
  f32x4 accs[4];
#pragma unroll
  for (int jt = 0; jt < 4; ++jt) {
    f32x4 a = (jt == 0) ? acc0 : (jt == 1) ? acc1 : (jt == 2) ? acc2 : acc3;
#pragma unroll
    for (int reg = 0; reg < 4; ++reg) {
      int e = et * 16 + g4 * 4 + reg;
      int j = jt * 16 + col15;
      unsigned sp = Spd[e][j >> 1];
      float add = (j & 1) ? bfhi(sp) : bflo(sp);
      float v = a[reg] + add;
      a[reg] = v;
      s4[jt] += v;
      q4[jt] = fmaf(v, v, q4[jt]);
    }
    accs[jt] = a;
  }
#pragma unroll
  for (int jt = 0; jt < 4; ++jt) {
#pragma unroll
    for (int reg = 0; reg < 4; ++reg) {
      float v = accs[jt][reg];
      float pv = __shfl_xor(v, 1);
      if (!(col15 & 1)) {
        int e = e0 + et * 16 + g4 * 4 + reg;
        EoutSlots[(size_t)e * 64 + jt * 8 + (col15 >> 1)] = packbf(v, pv);
      }
    }
  }
#pragma unroll
  for (int jt = 0; jt < 4; ++jt) {
    s4[jt] += __shfl_xor(s4[jt], 16);
    q4[jt] += __shfl_xor(q4[jt], 16);
    s4[jt] += __shfl_xor(s4[jt], 32);
    q4[jt] += __shfl_xor(q4[jt], 32);
  }
  if (g4 == 0) {
#pragma unroll
    for (int jt = 0; jt < 4; ++jt) {
      atomicAdd(&ls[jt * 16 + col15], s4[jt]);
      atomicAdd(&ls[64 + jt * 16 + col15], q4[jt]);
    }
  }
  __syncthreads();
  if (tid < 128) partials[(size_t)blockIdx.x * 128 + tid] = ls[tid];
}

// ---- merged reduce: blocks 0..63 -> E partials; 64..71 -> V partials ----
__global__ __launch_bounds__(256) void reduce2_k(const float* __restrict__ pE,
                                                 const float* __restrict__ pV,
                                                 float* __restrict__ statsE,
                                                 float* __restrict__ statsV) {
  __shared__ float ls[128];
  int tid = threadIdx.x;
  if (tid < 128) ls[tid] = 0.f;
  __syncthreads();
  bool isV = blockIdx.x >= 64;
  const float* p = isV ? pV : pE;
  float* out = isV ? statsV : statsE;
  int nrows = isV ? NVBLK : NEBLK;
  int b = isV ? (int)blockIdx.x - 64 : (int)blockIdx.x;
  int nb = isV ? 8 : 64;
  int c = tid & 127;
  int half = tid >> 7;
  float s = 0.f;
  for (int r = b * 2 + half; r < nrows; r += 2 * nb) {
    s += p[(size_t)r * 128 + c];
  }
  atomicAdd(&ls[c], s);
  __syncthreads();
  if (tid < 128) atomicAdd(&out[tid], ls[tid]);
}

// ---- merged finalize: tid<64 -> V, else E ----
__global__ void finalize2_k(const float* __restrict__ statsV, const float* __restrict__ statsE,
                            const float* __restrict__ gammaV, const float* __restrict__ betaV,
                            const float* __restrict__ gammaE, const float* __restrict__ betaE,
                            float* __restrict__ scshV, float* __restrict__ scshE) {
  int tid = threadIdx.x;   // 128 threads
  int j = tid & 63;
  const float* sums = (tid < 64) ? statsV : statsE;
  const float* gamma = (tid < 64) ? gammaV : gammaE;
  const float* beta = (tid < 64) ? betaV : betaE;
  float* scsh = (tid < 64) ? scshV : scshE;
  float inv_n = (tid < 64) ? (1.f / N_NODES) : (1.f / M_EDGES);
  float mu = sums[j] * inv_n;
  float var = sums[64 + j] * inv_n - mu * mu;
  float sc = gamma[j] * rsqrtf(var + BN_EPS);
  scsh[j] = sc;
  scsh[64 + j] = beta[j] - mu * sc;
}

__global__ __launch_bounds__(256) void bn_apply_k(
    float* __restrict__ X, const float* __restrict__ resid,
    const float* __restrict__ sc_shift, int n4) {
  int i = blockIdx.x * blockDim.x + threadIdx.x;
  if (i >= n4) return;
  int jq = i & 15;
  float4 x = reinterpret_cast<float4*>(X)[i];
  float4 r = reinterpret_cast<const float4*>(resid)[i];
  float4 sc = reinterpret_cast<const float4*>(sc_shift)[jq];
  float4 sh = reinterpret_cast<const float4*>(sc_shift + 64)[jq];
  float4 y;
  y.x = leaky(fmaf(x.x, sc.x, sh.x)) + r.x;
  y.y = leaky(fmaf(x.y, sc.y, sh.y)) + r.y;
  y.z = leaky(fmaf(x.z, sc.z, sh.z)) + r.z;
  y.w = leaky(fmaf(x.w, sc.w, sh.w)) + r.w;
  reinterpret_cast<float4*>(X)[i] = y;
}

__global__ __launch_bounds__(256) void bn_applyE_k(
    float* __restrict__ EoutF, const float* __restrict__ Eg,
    const float* __restrict__ sc_shift) {
  __shared__ float scs[128];
  int tid = threadIdx.x;
  if (tid < 128) scs[tid] = sc_shift[tid];
  __syncthreads();
  int i = blockIdx.x * 256 + tid;
  int jq = i & 15;
  float2 pr = reinterpret_cast<const float2*>(EoutF)[((size_t)(i >> 4)) * 32 + jq];
  unsigned u0 = __float_as_uint(pr.x);
  unsigned u1 = __float_as_uint(pr.y);
  float v0 = bflo(u0), v1 = bfhi(u0), v2 = bflo(u1), v3 = bfhi(u1);
  float4 eg = reinterpret_cast<const float4*>(Eg)[i];
  int j = jq * 4;
  float4 o;
  o.x = leaky(fmaf(v0, scs[j + 0], scs[64 + j + 0])) + eg.x;
  o.y = leaky(fmaf(v1, scs[j + 1], scs[64 + j + 1])) + eg.y;
  o.z = leaky(fmaf(v2, scs[j + 2], scs[64 + j + 2])) + eg.z;
  o.w = leaky(fmaf(v3, scs[j + 3], scs[64 + j + 3])) + eg.w;
  reinterpret_cast<float4*>(EoutF)[i] = o;
}

extern "C" void kernel_launch(void* const* d_in, const int* in_sizes, int n_in,
                              void* d_out, int out_size, void* d_ws, size_t ws_size,
                              hipStream_t stream) {
  const float* V      = (const float*)d_in[0];
  const float* Eg     = (const float*)d_in[1];
  const int*   src    = (const int*)d_in[2];
  const int*   dst    = (const int*)d_in[3];
  const float* W_ops  = (const float*)d_in[4];
  const float* b_ops  = (const float*)d_in[5];
  const float* W_cat  = (const float*)d_in[6];
  const float* b_cat  = (const float*)d_in[7];
  const float* W_S    = (const float*)d_in[8];
  const float* b_S    = (const float*)d_in[9];
  const float* gammaV = (const float*)d_in[10];
  const float* betaV  = (const float*)d_in[11];
  const float* gammaE = (const float*)d_in[12];
  const float* betaE  = (const float*)d_in[13];

  float* ws = (float*)d_ws;
  const size_t ND = (size_t)N_NODES * 64;
  const size_t NH = (size_t)N_NODES * 32;
  unsigned* Vb  = (unsigned*)ws;
  unsigned* Ab  = (unsigned*)ws + NH;
  unsigned* PsP = (unsigned*)ws + 2 * NH;
  unsigned* PdP = (unsigned*)ws + 3 * NH;
  float* xb   = ws + 4 * NH;
  float* W12g  = xb;
  float* Wc12g = xb + 4096;
  float* WAg   = xb + 8192;
  float* WBg   = xb + 12288;
  float* W0Bg  = xb + 16384;
  float* cg    = xb + 20480;
  float* b0Bg  = xb + 20544;
  float* statsV = xb + 20608;
  float* statsE = statsV + 128;
  float* scshV  = statsV + 256;
  float* scshE  = statsV + 384;
  int* counts = (int*)(statsV + 512);
  int* offs   = counts + N_NODES;
  int* cursor = offs + N_NODES + 1;
  int* ssrc   = cursor + N_NODES;
  float* partials = (float*)(ssrc + M_EDGES);
  float* partialsV = partials + (size_t)NEBLK * 128;
  unsigned* WAF  = (unsigned*)(partialsV + (size_t)NVBLK * 128);
  unsigned* W0BF = WAF + 2048;
  unsigned* Ws0F = WAF + 4096;
  unsigned* Ws2F = WAF + 6144;
  unsigned* WmF  = WAF + 8192;
  int* bsum = (int*)(WAF + 10240);

  float* Vout  = (float*)d_out;
  float* EoutF = Vout + ND;
  unsigned* EoutSlots = (unsigned*)EoutF;

  hipMemsetAsync(counts, 0, N_NODES * sizeof(int), stream);
  hipMemsetAsync(statsV, 0, 256 * sizeof(float), stream);

  const int eb = (M_EDGES + 255) / 256;
  prep1_k<<<2, 256, 0, stream>>>(W_ops, W_cat, W12g, Wc12g);
  prep2_k<<<2, 256, 0, stream>>>(W_ops, b_ops, W_cat, b_cat, W12g, Wc12g, WAg, WBg, cg);
  prep3_k<<<1, 256, 0, stream>>>(W_ops, b_ops, WBg, W0Bg, b0Bg);
  prepW_k<<<5, 256, 0, stream>>>(WAg, W0Bg, W_S, WAF, W0BF, Ws0F, Ws2F, WmF);
  hist_k<<<eb, 256, 0, stream>>>(dst, counts);
  blocksum_k<<<NSB, 256, 0, stream>>>(counts, bsum);
  scanb_k<<<1, 256, 0, stream>>>(bsum);
  offs_k<<<NSB, 256, 0, stream>>>(counts, bsum, offs, cursor);
  fill_k<<<eb, 256, 0, stream>>>(src, dst, cursor, ssrc);

  convbf_k<<<(N_NODES * 8 + 255) / 256, 256, 0, stream>>>(V, Vb, N_NODES * 8);
  gatherb_k<<<N_NODES / 4, 256, 0, stream>>>(Vb, offs, ssrc, Ab);
  vnewproj_k<<<NVBLK, 256, 0, stream>>>(Ab, offs, ssrc, counts, WAF, W0BF, Ws0F, Ws2F,
                                        cg, b0Bg, b_S, Vout, PsP, PdP, partialsV);
  edge_k<<<NEBLK, 256, 0, stream>>>(Eg, src, dst, PsP, PdP, WmF, EoutSlots, partials);
  reduce2_k<<<72, 256, 0, stream>>>(partials, partialsV, statsE, statsV);
  finalize2_k<<<1, 128, 0, stream>>>(statsV, statsE, gammaV, betaV, gammaE, betaE,
                                     scshV, scshE);
  bn_apply_k<<<(int)((ND / 4 + 255) / 256), 256, 0, stream>>>(Vout, V, scshV, (int)(ND / 4));
  bn_applyE_k<<<M_EDGES * 16 / 256, 256, 0, stream>>>(EoutF, Eg, scshE);
}

// Round 16
// 456.743 us; speedup vs baseline: 1.9898x; 1.0008x over previous
//
#include <hip/hip_runtime.h>
#include <hip/hip_bf16.h>

#define N_NODES 50000
#define M_EDGES 800000
#define LEAKY_F 0.2f
#define BN_EPS 1e-5f
#define NEBLK (M_EDGES / 64)
#define NVBLK ((N_NODES + 63) / 64)
#define NSB ((N_NODES + 255) / 256)

typedef short bf16x8 __attribute__((ext_vector_type(8)));
typedef float f32x4 __attribute__((ext_vector_type(4)));

__device__ __forceinline__ float leaky(float x) { return x >= 0.f ? x : LEAKY_F * x; }

__device__ __forceinline__ unsigned f2bf(float f) {
  unsigned u = __float_as_uint(f);
  return (u + 0x7fffu + ((u >> 16) & 1u)) >> 16;
}
__device__ __forceinline__ unsigned packbf(float a, float b) {
  return (f2bf(b) << 16) | f2bf(a);
}
__device__ __forceinline__ float bflo(unsigned u) { return __uint_as_float(u << 16); }
__device__ __forceinline__ float bfhi(unsigned u) { return __uint_as_float(u & 0xffff0000u); }

// fragment-order conversion of a 64x64 f32 matrix (rows = contraction dim)
__device__ __forceinline__ void frag_convert(const float* src, unsigned* dst, int tid) {
  for (int q = tid; q < 2048; q += 256) {
    int ui = q & 3, ln = (q >> 2) & 63, t = q >> 8;
    int jt = t >> 1, kh = t & 1;
    int j = jt * 16 + (ln & 15);
    int k2 = kh * 16 + (ln >> 4) * 4 + ui;
    dst[q] = packbf(src[(2 * k2) * 64 + j], src[(2 * k2 + 1) * 64 + j]);
  }
}

// ================= CSR build =================
__global__ __launch_bounds__(256) void hist_k(const int* __restrict__ dst,
                                              int* __restrict__ counts) {
  int e = blockIdx.x * 256 + threadIdx.x;
  if (e < M_EDGES) atomicAdd(&counts[dst[e]], 1);
}

__global__ __launch_bounds__(256) void blocksum_k(const int* __restrict__ counts,
                                                  int* __restrict__ bsum) {
  __shared__ int wsum[4];
  int tid = threadIdx.x;
  int i = blockIdx.x * 256 + tid;
  int v = (i < N_NODES) ? counts[i] : 0;
#pragma unroll
  for (int off = 32; off; off >>= 1) v += __shfl_down(v, off);
  if ((tid & 63) == 0) wsum[tid >> 6] = v;
  __syncthreads();
  if (tid == 0) bsum[blockIdx.x] = wsum[0] + wsum[1] + wsum[2] + wsum[3];
}

__global__ __launch_bounds__(256) void scanb_k(int* __restrict__ bsum) {
  __shared__ int s[256];
  int tid = threadIdx.x;
  s[tid] = (tid < NSB) ? bsum[tid] : 0;
  __syncthreads();
  for (int off = 1; off < 256; off <<= 1) {
    int v = 0;
    if (tid >= off) v = s[tid - off];
    __syncthreads();
    if (tid >= off) s[tid] += v;
    __syncthreads();
  }
  if (tid < NSB) bsum[tid] = (tid == 0) ? 0 : s[tid - 1];
}

__global__ __launch_bounds__(256) void offs_k(const int* __restrict__ counts,
                                              const int* __restrict__ bsum,
                                              int* __restrict__ offs,
                                              int* __restrict__ cursor) {
  __shared__ int s[256];
  int tid = threadIdx.x;
  int i = blockIdx.x * 256 + tid;
  int c = (i < N_NODES) ? counts[i] : 0;
  s[tid] = c;
  __syncthreads();
  for (int off = 1; off < 256; off <<= 1) {
    int v = 0;
    if (tid >= off) v = s[tid - off];
    __syncthreads();
    if (tid >= off) s[tid] += v;
    __syncthreads();
  }
  int excl = s[tid] - c + bsum[blockIdx.x];
  if (i < N_NODES) {
    offs[i] = excl;
    cursor[i] = excl;
  }
  if (i == N_NODES - 1) offs[N_NODES] = M_EDGES;
}

__global__ __launch_bounds__(256) void fill_k(const int* __restrict__ src,
                                              const int* __restrict__ dst,
                                              int* __restrict__ cursor,
                                              int* __restrict__ ssrc) {
  int e = blockIdx.x * 256 + threadIdx.x;
  if (e >= M_EDGES) return;
  int p = atomicAdd(&cursor[dst[e]], 1);
  ssrc[p] = src[e];
}

// ---- f32 rows -> packed bf16 rows ----
__global__ __launch_bounds__(256) void convbf_k(const float* __restrict__ X,
                                                unsigned* __restrict__ Xb, int n4) {
  int i = blockIdx.x * 256 + threadIdx.x;
  if (i >= n4) return;
  const float4* s4 = reinterpret_cast<const float4*>(X) + (size_t)i * 2;
  float4 a = s4[0], b = s4[1];
  uint4 o;
  o.x = packbf(a.x, a.y);
  o.y = packbf(a.z, a.w);
  o.z = packbf(b.x, b.y);
  o.w = packbf(b.z, b.w);
  reinterpret_cast<uint4*>(Xb)[i] = o;
}

// ---- segment gather-sum; wave per node, 4x 16-lane groups with uint2 loads ----
__global__ __launch_bounds__(256) void gatherb_k(const unsigned* __restrict__ Xb,
                                                 const int* __restrict__ offs,
                                                 const int* __restrict__ ssrc,
                                                 unsigned* __restrict__ Ob) {
  int n = blockIdx.x * 4 + (threadIdx.x >> 6);
  int lane = threadIdx.x & 63;
  int grp = lane >> 4, col = lane & 15;
  int beg = offs[n], end = offs[n + 1];
  float a0 = 0.f, a1 = 0.f, a2 = 0.f, a3 = 0.f;
  int i = beg + grp;
  for (; i + 4 < end; i += 8) {
    int s0 = ssrc[i], s1 = ssrc[i + 4];
    uint2 u0 = *reinterpret_cast<const uint2*>(&Xb[(size_t)s0 * 32 + col * 2]);
    uint2 u1 = *reinterpret_cast<const uint2*>(&Xb[(size_t)s1 * 32 + col * 2]);
    a0 += bflo(u0.x) + bflo(u1.x);
    a1 += bfhi(u0.x) + bfhi(u1.x);
    a2 += bflo(u0.y) + bflo(u1.y);
    a3 += bfhi(u0.y) + bfhi(u1.y);
  }
  for (; i < end; i += 4) {
    uint2 u = *reinterpret_cast<const uint2*>(&Xb[(size_t)ssrc[i] * 32 + col * 2]);
    a0 += bflo(u.x);
    a1 += bfhi(u.x);
    a2 += bflo(u.y);
    a3 += bfhi(u.y);
  }
#pragma unroll
  for (int off = 16; off <= 32; off <<= 1) {
    a0 += __shfl_xor(a0, off);
    a1 += __shfl_xor(a1, off);
    a2 += __shfl_xor(a2, off);
    a3 += __shfl_xor(a3, off);
  }
  if (grp == 0) {
    uint2 o = make_uint2(packbf(a0, a1), packbf(a2, a3));
    *reinterpret_cast<uint2*>(&Ob[(size_t)n * 32 + col * 2]) = o;
  }
}

// ================= weight-prep =================
// blocks 0,1: W12 / Wc12 matmuls; blocks 2-4: W_S fragment tables
__global__ __launch_bounds__(256) void prep1_k(const float* __restrict__ W_ops,
                                               const float* __restrict__ W_cat,
                                               const float* __restrict__ W_S,
                                               float* __restrict__ W12g,
                                               float* __restrict__ Wc12g,
                                               unsigned* __restrict__ Ws0F,
                                               unsigned* __restrict__ Ws2F,
                                               unsigned* __restrict__ WmF) {
  int tid = threadIdx.x;
  if (blockIdx.x >= 2) {
    const float* src = (blockIdx.x == 2) ? W_S : (blockIdx.x == 3) ? W_S + 8192 : W_S + 4096;
    unsigned* dst = (blockIdx.x == 2) ? Ws0F : (blockIdx.x == 3) ? Ws2F : WmF;
    frag_convert(src, dst, tid);
    return;
  }
  __shared__ float Wa[4096], Wb[4096];
  const float *Am, *Bm, *Add;
  float* Out;
  if (blockIdx.x == 0) { Am = W_ops; Bm = W_ops + 8192; Add = W_ops + 4096; Out = W12g; }
  else { Am = W_ops + 16384; Bm = W_cat + 8192; Add = W_cat + 4096; Out = Wc12g; }
  for (int i = tid; i < 4096; i += 256) { Wa[i] = Am[i]; Wb[i] = Bm[i]; }
  __syncthreads();
  for (int t = 0; t < 16; ++t) {
    int o = tid + t * 256;
    int r = o >> 6, j = o & 63;
    float acc = Add[o];
#pragma unroll
    for (int k = 0; k < 64; ++k) acc = fmaf(Wa[r * 64 + k], Wb[k * 64 + j], acc);
    Out[o] = acc;
  }
}

// block0: WA (+ WAF frags); block1: WB, cg
__global__ __launch_bounds__(256) void prep2_k(const float* __restrict__ W_ops,
                                               const float* __restrict__ b_ops,
                                               const float* __restrict__ W_cat,
                                               const float* __restrict__ b_cat,
                                               const float* __restrict__ W12g,
                                               const float* __restrict__ Wc12g,
                                               float* __restrict__ WAg,
                                               unsigned* __restrict__ WAF,
                                               float* __restrict__ WBg,
                                               float* __restrict__ cg) {
  __shared__ float M0[4096], M1[4096], M2[4096], M3[4096], M4[4096];
  __shared__ float bb[64];
  int tid = threadIdx.x;
  if (blockIdx.x == 0) {
    for (int i = tid; i < 4096; i += 256) {
      M0[i] = W_ops[i];
      M1[i] = W_cat[i];
      M2[i] = W12g[i];
      M3[i] = Wc12g[i];
    }
    __syncthreads();
    for (int t = 0; t < 16; ++t) {
      int o = tid + t * 256;
      int r = o >> 6, j = o & 63;
      float acc = 0.f;
#pragma unroll
      for (int k = 0; k < 64; ++k) {
        acc = fmaf(M0[r * 64 + k], M1[k * 64 + j], acc);
        acc = fmaf(M2[r * 64 + k], M3[k * 64 + j], acc);
      }
      WAg[o] = acc;
      M4[o] = acc;
    }
    __syncthreads();
    frag_convert(M4, WAF, tid);
  } else {
    for (int i = tid; i < 4096; i += 256) {
      M0[i] = W_ops[3 * 4096 + i];
      M1[i] = W_cat[8192 + i];
      M2[i] = W_ops[2 * 4096 + i];
      M3[i] = W_cat[i];
      M4[i] = Wc12g[i];
    }
    __syncthreads();
    for (int t = 0; t < 16; ++t) {
      int o = tid + t * 256;
      int r = o >> 6, j = o & 63;
      float acc = 0.f;
#pragma unroll
      for (int k = 0; k < 64; ++k) acc = fmaf(M0[r * 64 + k], M1[k * 64 + j], acc);
      WBg[o] = acc;
    }
    if (tid < 64) {
      int j = tid;
      float acc = b_ops[64 + j] + b_ops[128 + j];
#pragma unroll
      for (int k = 0; k < 64; ++k) acc = fmaf(b_ops[k], M2[k * 64 + j], acc);
      bb[j] = acc;
    }
    __syncthreads();
    if (tid < 64) {
      int j = tid;
      float acc = b_cat[j];
#pragma unroll
      for (int k = 0; k < 64; ++k) {
        acc = fmaf(b_ops[k], M3[k * 64 + j], acc);
        acc = fmaf(bb[k], M4[k * 64 + j], acc);
        acc = fmaf(b_ops[192 + k] + b_ops[256 + k], M1[k * 64 + j], acc);
      }
      cg[j] = acc;
    }
  }
}

// prep3: W0B = W0@WB (+ frags) ; b0B = b0@WB
__global__ __launch_bounds__(256) void prep3_k(const float* __restrict__ W_ops,
                                               const float* __restrict__ b_ops,
                                               const float* __restrict__ WBg,
                                               unsigned* __restrict__ W0BF,
                                               float* __restrict__ b0Bg) {
  __shared__ float Wa[4096], Wb[4096], Wr[4096];
  int tid = threadIdx.x;
  for (int i = tid; i < 4096; i += 256) { Wa[i] = W_ops[i]; Wb[i] = WBg[i]; }
  __syncthreads();
  for (int t = 0; t < 16; ++t) {
    int o = tid + t * 256;
    int r = o >> 6, j = o & 63;
    float acc = 0.f;
#pragma unroll
    for (int k = 0; k < 64; ++k) acc = fmaf(Wa[r * 64 + k], Wb[k * 64 + j], acc);
    Wr[o] = acc;
  }
  if (tid < 64) {
    float acc = 0.f;
#pragma unroll
    for (int k = 0; k < 64; ++k) acc = fmaf(b_ops[k], Wb[k * 64 + tid], acc);
    b0Bg[tid] = acc;
  }
  __syncthreads();
  frag_convert(Wr, W0BF, tid);
}

// ---- node MFMA kernel: fused C-gather + Vnew + V-stats + proj ----
__global__ __launch_bounds__(256) void vnewproj_k(
    const unsigned* __restrict__ Ab,
    const int* __restrict__ offs, const int* __restrict__ ssrc,
    const int* __restrict__ counts,
    const unsigned* __restrict__ WAF, const unsigned* __restrict__ W0BF,
    const unsigned* __restrict__ Ws0F, const unsigned* __restrict__ Ws2F,
    const float* __restrict__ cg, const float* __restrict__ b0Bg,
    const float* __restrict__ b_S,
    float* __restrict__ Vnew, unsigned* __restrict__ PsP, unsigned* __restrict__ PdP,
    float* __restrict__ partialsV) {
  __shared__ __align__(16) unsigned AF[2048], CF[2048], VF[2048];
  __shared__ float cb[64], b0v[64], bsv[64];
  __shared__ float lsv[128];
  int tid = threadIdx.x;
  int n0 = blockIdx.x * 64;
  int l16 = tid & 15, g16 = tid >> 4;
#pragma unroll
  for (int rr = 0; rr < 4; ++rr) {
    int r = g16 + 16 * rr;
    int n = n0 + r;
    float a0 = 0.f, a1 = 0.f, a2 = 0.f, a3 = 0.f;
    if (n < N_NODES) {
      int beg = offs[n], end = offs[n + 1];
      int i = beg;
      for (; i + 1 < end; i += 2) {
        int s0 = ssrc[i], s1 = ssrc[i + 1];
        uint2 u0 = *reinterpret_cast<const uint2*>(&Ab[(size_t)s0 * 32 + l16 * 2]);
        uint2 u1 = *reinterpret_cast<const uint2*>(&Ab[(size_t)s1 * 32 + l16 * 2]);
        a0 += bflo(u0.x) + bflo(u1.x);
        a1 += bfhi(u0.x) + bfhi(u1.x);
        a2 += bflo(u0.y) + bflo(u1.y);
        a3 += bfhi(u0.y) + bfhi(u1.y);
      }
      if (i < end) {
        uint2 u = *reinterpret_cast<const uint2*>(&Ab[(size_t)ssrc[i] * 32 + l16 * 2]);
        a0 += bflo(u.x);
        a1 += bfhi(u.x);
        a2 += bflo(u.y);
        a3 += bfhi(u.y);
      }
    }
    unsigned pu0 = packbf(a0, a1), pu1 = packbf(a2, a3);
    int k2 = 2 * l16;
    int kh = k2 >> 4, k2h = k2 & 15;
    int ln = (r & 15) + 16 * (k2h >> 2);
    int base = ((((r >> 4) << 1) + kh) * 64 + ln) * 4 + (k2h & 3);
    CF[base] = pu0;
    CF[base + 1] = pu1;
  }
  for (int q = tid; q < 2048; q += 256) {
    int r = q >> 5, k2 = q & 31;
    int row = n0 + r;
    if (row >= N_NODES) row = N_NODES - 1;
    unsigned ua = Ab[(size_t)row * 32 + k2];
    int kh = k2 >> 4, k2h = k2 & 15;
    int ln = (r & 15) + 16 * (k2h >> 2);
    AF[((((r >> 4) << 1) + kh) * 64 + ln) * 4 + (k2h & 3)] = ua;
  }
  if (tid < 64) { cb[tid] = cg[tid]; b0v[tid] = b0Bg[tid]; bsv[tid] = b_S[tid]; }
  if (tid < 128) lsv[tid] = 0.f;
  __syncthreads();

  int lane = tid & 63, et = tid >> 6;
  int col15 = lane & 15, g4 = lane >> 4;
  float deg[4];
#pragma unroll
  for (int reg = 0; reg < 4; ++reg) {
    int rg = n0 + et * 16 + g4 * 4 + reg;
    deg[reg] = (float)counts[rg < N_NODES ? rg : N_NODES - 1];
  }
  f32x4 a0 = {0.f, 0.f, 0.f, 0.f}, a1 = a0, a2 = a0, a3 = a0;
#pragma unroll
  for (int kh = 0; kh < 2; ++kh) {
    uint4 au = *reinterpret_cast<const uint4*>(&AF[(((et << 1) + kh) * 64 + lane) * 4]);
    uint4 cu = *reinterpret_cast<const uint4*>(&CF[(((et << 1) + kh) * 64 + lane) * 4]);
    bf16x8 afr = *reinterpret_cast<bf16x8*>(&au);
    bf16x8 cfr = *reinterpret_cast<bf16x8*>(&cu);
    uint4 wa0 = *reinterpret_cast<const uint4*>(&WAF[((0 * 2 + kh) * 64 + lane) * 4]);
    uint4 wa1 = *reinterpret_cast<const uint4*>(&WAF[((1 * 2 + kh) * 64 + lane) * 4]);
    uint4 wa2 = *reinterpret_cast<const uint4*>(&WAF[((2 * 2 + kh) * 64 + lane) * 4]);
    uint4 wa3 = *reinterpret_cast<const uint4*>(&WAF[((3 * 2 + kh) * 64 + lane) * 4]);
    uint4 wc0 = *reinterpret_cast<const uint4*>(&W0BF[((0 * 2 + kh) * 64 + lane) * 4]);
    uint4 wc1 = *reinterpret_cast<const uint4*>(&W0BF[((1 * 2 + kh) * 64 + lane) * 4]);
    uint4 wc2 = *reinterpret_cast<const uint4*>(&W0BF[((2 * 2 + kh) * 64 + lane) * 4]);
    uint4 wc3 = *reinterpret_cast<const uint4*>(&W0BF[((3 * 2 + kh) * 64 + lane) * 4]);
    a0 = __builtin_amdgcn_mfma_f32_16x16x32_bf16(afr, *reinterpret_cast<bf16x8*>(&wa0), a0, 0, 0, 0);
    a1 = __builtin_amdgcn_mfma_f32_16x16x32_bf16(afr, *reinterpret_cast<bf16x8*>(&wa1), a1, 0, 0, 0);
    a2 = __builtin_amdgcn_mfma_f32_16x16x32_bf16(afr, *reinterpret_cast<bf16x8*>(&wa2), a2, 0, 0, 0);
    a3 = __builtin_amdgcn_mfma_f32_16x16x32_bf16(afr, *reinterpret_cast<bf16x8*>(&wa3), a3, 0, 0, 0);
    a0 = __builtin_amdgcn_mfma_f32_16x16x32_bf16(cfr, *reinterpret_cast<bf16x8*>(&wc0), a0, 0, 0, 0);
    a1 = __builtin_amdgcn_mfma_f32_16x16x32_bf16(cfr, *reinterpret_cast<bf16x8*>(&wc1), a1, 0, 0, 0);
    a2 = __builtin_amdgcn_mfma_f32_16x16x32_bf16(cfr, *reinterpret_cast<bf16x8*>(&wc2), a2, 0, 0, 0);
    a3 = __builtin_amdgcn_mfma_f32_16x16x32_bf16(cfr, *reinterpret_cast<bf16x8*>(&wc3), a3, 0, 0, 0);
  }
  float s4[4] = {0.f, 0.f, 0.f, 0.f}, q4[4] = {0.f, 0.f, 0.f, 0.f};
#pragma unroll
  for (int jt = 0; jt < 4; ++jt) {
    f32x4 a = (jt == 0) ? a0 : (jt == 1) ? a1 : (jt == 2) ? a2 : a3;
    int j = jt * 16 + col15;
#pragma unroll
    for (int reg = 0; reg < 4; ++reg) {
      float v = a[reg] + fmaf(deg[reg], b0v[j], cb[j]);
      a[reg] = v;
      int rg = n0 + et * 16 + g4 * 4 + reg;
      if (rg < N_NODES) {
        Vnew[(size_t)rg * 64 + j] = v;
        s4[jt] += v;
        q4[jt] = fmaf(v, v, q4[jt]);
      }
    }
#pragma unroll
    for (int reg = 0; reg < 4; ++reg) {
      float v = a[reg];
      float pv = __shfl_xor(v, 1);
      if (!(col15 & 1)) {
        int k2p = jt * 8 + (col15 >> 1);
        int kh2 = k2p >> 4, k2h = k2p & 15;
        int ln = (g4 * 4 + reg) + 16 * (k2h >> 2);
        VF[(((et << 1) + kh2) * 64 + ln) * 4 + (k2h & 3)] = packbf(v, pv);
      }
    }
  }
#pragma unroll
  for (int jt = 0; jt < 4; ++jt) {
    s4[jt] += __shfl_xor(s4[jt], 16);
    q4[jt] += __shfl_xor(q4[jt], 16);
    s4[jt] += __shfl_xor(s4[jt], 32);
    q4[jt] += __shfl_xor(q4[jt], 32);
  }
  if (g4 == 0) {
#pragma unroll
    for (int jt = 0; jt < 4; ++jt) {
      atomicAdd(&lsv[jt * 16 + col15], s4[jt]);
      atomicAdd(&lsv[64 + jt * 16 + col15], q4[jt]);
    }
  }
  __syncthreads();
  if (tid < 128) partialsV[(size_t)blockIdx.x * 128 + tid] = lsv[tid];

  f32x4 p0 = {0.f, 0.f, 0.f, 0.f}, p1 = p0, p2 = p0, p3 = p0;
  f32x4 d0 = p0, d1 = p0, d2 = p0, d3 = p0;
#pragma unroll
  for (int kh = 0; kh < 2; ++kh) {
    uint4 vu = *reinterpret_cast<const uint4*>(&VF[(((et << 1) + kh) * 64 + lane) * 4]);
    bf16x8 vfr = *reinterpret_cast<bf16x8*>(&vu);
    uint4 w00 = *reinterpret_cast<const uint4*>(&Ws0F[((0 * 2 + kh) * 64 + lane) * 4]);
    uint4 w01 = *reinterpret_cast<const uint4*>(&Ws0F[((1 * 2 + kh) * 64 + lane) * 4]);
    uint4 w02 = *reinterpret_cast<const uint4*>(&Ws0F[((2 * 2 + kh) * 64 + lane) * 4]);
    uint4 w03 = *reinterpret_cast<const uint4*>(&Ws0F[((3 * 2 + kh) * 64 + lane) * 4]);
    uint4 w20 = *reinterpret_cast<const uint4*>(&Ws2F[((0 * 2 + kh) * 64 + lane) * 4]);
    uint4 w21 = *reinterpret_cast<const uint4*>(&Ws2F[((1 * 2 + kh) * 64 + lane) * 4]);
    uint4 w22 = *reinterpret_cast<const uint4*>(&Ws2F[((2 * 2 + kh) * 64 + lane) * 4]);
    uint4 w23 = *reinterpret_cast<const uint4*>(&Ws2F[((3 * 2 + kh) * 64 + lane) * 4]);
    p0 = __builtin_amdgcn_mfma_f32_16x16x32_bf16(vfr, *reinterpret_cast<bf16x8*>(&w00), p0, 0, 0, 0);
    p1 = __builtin_amdgcn_mfma_f32_16x16x32_bf16(vfr, *reinterpret_cast<bf16x8*>(&w01), p1, 0, 0, 0);
    p2 = __builtin_amdgcn_mfma_f32_16x16x32_bf16(vfr, *reinterpret_cast<bf16x8*>(&w02), p2, 0, 0, 0);
    p3 = __builtin_amdgcn_mfma_f32_16x16x32_bf16(vfr, *reinterpret_cast<bf16x8*>(&w03), p3, 0, 0, 0);
    d0 = __builtin_amdgcn_mfma_f32_16x16x32_bf16(vfr, *reinterpret_cast<bf16x8*>(&w20), d0, 0, 0, 0);
    d1 = __builtin_amdgcn_mfma_f32_16x16x32_bf16(vfr, *reinterpret_cast<bf16x8*>(&w21), d1, 0, 0, 0);
    d2 = __builtin_amdgcn_mfma_f32_16x16x32_bf16(vfr, *reinterpret_cast<bf16x8*>(&w22), d2, 0, 0, 0);
    d3 = __builtin_amdgcn_mfma_f32_16x16x32_bf16(vfr, *reinterpret_cast<bf16x8*>(&w23), d3, 0, 0, 0);
  }
#pragma unroll
  for (int pt = 0; pt < 4; ++pt) {
    f32x4 p = (pt == 0) ? p0 : (pt == 1) ? p1 : (pt == 2) ? p2 : p3;
    f32x4 d = (pt == 0) ? d0 : (pt == 1) ? d1 : (pt == 2) ? d2 : d3;
    int pj = pt * 16 + col15;
#pragma unroll
    for (int reg = 0; reg < 4; ++reg) {
      float vp = p[reg] + bsv[pj];
      float vd = d[reg];
      float pvp = __shfl_xor(vp, 1);
      float pvd = __shfl_xor(vd, 1);
      if (!(col15 & 1)) {
        int rg = n0 + et * 16 + g4 * 4 + reg;
        if (rg < N_NODES) {
          PsP[(size_t)rg * 32 + pt * 8 + (col15 >> 1)] = packbf(vp, pvp);
          PdP[(size_t)rg * 32 + pt * 8 + (col15 >> 1)] = packbf(vd, pvd);
        }
      }
    }
  }
}

// ---- edge MFMA kernel ----
__global__ __launch_bounds__(256) void edge_k(
    const float* __restrict__ Eg, const int* __restrict__ src, const int* __restrict__ dst,
    const unsigned* __restrict__ PsP, const unsigned* __restrict__ PdP,
    const unsigned* __restrict__ WmF, unsigned* __restrict__ EoutSlots,
    float* __restrict__ partials) {
  __shared__ __align__(16) unsigned EaF[2048];
  __shared__ unsigned Spd[64][34];
  __shared__ float ls[128];
  int tid = threadIdx.x;
  int e0 = blockIdx.x * 64;
  int l16 = tid & 15, g16 = tid >> 4;

  uint2 pa[4], pb[4];
#pragma unroll
  for (int rr = 0; rr < 4; ++rr) {
    int p = e0 + rr * 16 + g16;
    int s = src[p], d = dst[p];
    pa[rr] = *reinterpret_cast<const uint2*>(&PsP[(size_t)s * 32 + 2 * l16]);
    pb[rr] = *reinterpret_cast<const uint2*>(&PdP[(size_t)d * 32 + 2 * l16]);
  }
  if (tid < 128) ls[tid] = 0.f;
  for (int q = tid; q < 1024; q += 256) {
    int e = q >> 4, kq = q & 15;
    float4 vv = reinterpret_cast<const float4*>(Eg)[(size_t)(e0 + e) * 16 + kq];
    unsigned u0 = packbf(leaky(vv.x), leaky(vv.y));
    unsigned u1 = packbf(leaky(vv.z), leaky(vv.w));
    int k2a = 2 * kq;
    int kh = k2a >> 4, k2h = k2a & 15;
    int lane = (e & 15) + 16 * (k2h >> 2);
    int base = ((((e >> 4) << 1) + kh) * 64 + lane) * 4 + (k2h & 3);
    EaF[base] = u0;
    EaF[base + 1] = u1;
  }
#pragma unroll
  for (int rr = 0; rr < 4; ++rr) {
    int r = rr * 16 + g16;
    float fx = bflo(pa[rr].x) + bflo(pb[rr].x);
    float fy = bfhi(pa[rr].x) + bfhi(pb[rr].x);
    float fz = bflo(pa[rr].y) + bflo(pb[rr].y);
    float fw = bfhi(pa[rr].y) + bfhi(pb[rr].y);
    *reinterpret_cast<uint2*>(&Spd[r][l16 * 2]) = make_uint2(packbf(fx, fy), packbf(fz, fw));
  }
  __syncthreads();

  int lane = tid & 63;
  int et = tid >> 6;
  f32x4 acc0 = {0.f, 0.f, 0.f, 0.f};
  f32x4 acc1 = acc0, acc2 = acc0, acc3 = acc0;
#pragma unroll
  for (int kh = 0; kh < 2; ++kh) {
    uint4 au = *reinterpret_cast<const uint4*>(&EaF[(((et << 1) + kh) * 64 + lane) * 4]);
    bf16x8 afr = *reinterpret_cast<bf16x8*>(&au);
    uint4 b0 = *reinterpret_cast<const uint4*>(&WmF[((0 * 2 + kh) * 64 + lane) * 4]);
    uint4 b1 = *reinterpret_cast<const uint4*>(&WmF[((1 * 2 + kh) * 64 + lane) * 4]);
    uint4 b2 = *reinterpret_cast<const uint4*>(&WmF[((2 * 2 + kh) * 64 + lane) * 4]);
    uint4 b3 = *reinterpret_cast<const uint4*>(&WmF[((3 * 2 + kh) * 64 + lane) * 4]);
    acc0 = __builtin_amdgcn_mfma_f32_16x16x32_bf16(afr, *reinterpret_cast<bf16x8*>(&b0), acc0, 0, 0, 0);
    acc1 = __builtin_amdgcn_mfma_f32_16x16x32_bf16(afr, *reinterpret_cast<bf16x8*>(&b1), acc1, 0, 0, 0);
    acc2 = __builtin_amdgcn_mfma_f32_16x16x32_bf16(afr, *reinterpret_cast<bf16x8*>(&b2), acc2, 0, 0, 0);
    acc3 = __builtin_amdgcn_mfma_f32_16x16x32_bf16(afr, *reinterpret_cast<bf16x8*>(&b3), acc3, 0, 0, 0);
  }

  int col15 = lane & 15, g4 = lane >> 4;
  float s4[4] = {0.f, 0.f, 0.f, 0.f}, q4[4] = {0.f, 0.f, 0.f, 0.f};
  f32x4 accs[4];
#pragma unroll
  for (int jt = 0; jt < 4; ++jt) {
    f32x4 a = (jt == 0) ? acc0 : (jt == 1) ? acc1 : (jt == 2) ? acc2 : acc3;
#pragma unroll
    for (int reg = 0; reg < 4; ++reg) {
      int e = et * 16 + g4 * 4 + reg;
      int j = jt * 16 + col15;
      unsigned sp = Spd[e][j >> 1];
      float add = (j & 1) ? bfhi(sp) : bflo(sp);
      float v = a[reg] + add;
      a[reg] = v;
      s4[jt] += v;
      q4[jt] = fmaf(v, v, q4[jt]);
    }
    accs[jt] = a;
  }
#pragma unroll
  for (int jt = 0; jt < 4; ++jt) {
#pragma unroll
    for (int reg = 0; reg < 4; ++reg) {
      float v = accs[jt][reg];
      float pv = __shfl_xor(v, 1);
      if (!(col15 & 1)) {
        int e = e0 + et * 16 + g4 * 4 + reg;
        EoutSlots[(size_t)e * 64 + jt * 8 + (col15 >> 1)] = packbf(v, pv);
      }
    }
  }
#pragma unroll
  for (int jt = 0; jt < 4; ++jt) {
    s4[jt] += __shfl_xor(s4[jt], 16);
    q4[jt] += __shfl_xor(q4[jt], 16);
    s4[jt] += __shfl_xor(s4[jt], 32);
    q4[jt] += __shfl_xor(q4[jt], 32);
  }
  if (g4 == 0) {
#pragma unroll
    for (int jt = 0; jt < 4; ++jt) {
      atomicAdd(&ls[jt * 16 + col15], s4[jt]);
      atomicAdd(&ls[64 + jt * 16 + col15], q4[jt]);
    }
  }
  __syncthreads();
  if (tid < 128) partials[(size_t)blockIdx.x * 128 + tid] = ls[tid];
}

// ---- merged reduce: blocks 0..63 -> E partials; 64..71 -> V partials ----
__global__ __launch_bounds__(256) void reduce2_k(const float* __restrict__ pE,
                                                 const float* __restrict__ pV,
                                                 float* __restrict__ statsE,
                                                 float* __restrict__ statsV) {
  __shared__ float ls[128];
  int tid = threadIdx.x;
  if (tid < 128) ls[tid] = 0.f;
  __syncthreads();
  bool isV = blockIdx.x >= 64;
  const float* p = isV ? pV : pE;
  float* out = isV ? statsV : statsE;
  int nrows = isV ? NVBLK : NEBLK;
  int b = isV ? (int)blockIdx.x - 64 : (int)blockIdx.x;
  int nb = isV ? 8 : 64;
  int c = tid & 127;
  int half = tid >> 7;
  float s = 0.f;
  for (int r = b * 2 + half; r < nrows; r += 2 * nb) {
    s += p[(size_t)r * 128 + c];
  }
  atomicAdd(&ls[c], s);
  __syncthreads();
  if (tid < 128) atomicAdd(&out[tid], ls[tid]);
}

__global__ void finalize2_k(const float* __restrict__ statsV, const float* __restrict__ statsE,
                            const float* __restrict__ gammaV, const float* __restrict__ betaV,
                            const float* __restrict__ gammaE, const float* __restrict__ betaE,
                            float* __restrict__ scshV, float* __restrict__ scshE) {
  int tid = threadIdx.x;
  int j = tid & 63;
  const float* sums = (tid < 64) ? statsV : statsE;
  const float* gamma = (tid < 64) ? gammaV : gammaE;
  const float* beta = (tid < 64) ? betaV : betaE;
  float* scsh = (tid < 64) ? scshV : scshE;
  float inv_n = (tid < 64) ? (1.f / N_NODES) : (1.f / M_EDGES);
  float mu = sums[j] * inv_n;
  float var = sums[64 + j] * inv_n - mu * mu;
  float sc = gamma[j] * rsqrtf(var + BN_EPS);
  scsh[j] = sc;
  scsh[64 + j] = beta[j] - mu * sc;
}

__global__ __launch_bounds__(256) void bn_apply_k(
    float* __restrict__ X, const float* __restrict__ resid,
    const float* __restrict__ sc_shift, int n4) {
  int i = blockIdx.x * blockDim.x + threadIdx.x;
  if (i >= n4) return;
  int jq = i & 15;
  float4 x = reinterpret_cast<float4*>(X)[i];
  float4 r = reinterpret_cast<const float4*>(resid)[i];
  float4 sc = reinterpret_cast<const float4*>(sc_shift)[jq];
  float4 sh = reinterpret_cast<const float4*>(sc_shift + 64)[jq];
  float4 y;
  y.x = leaky(fmaf(x.x, sc.x, sh.x)) + r.x;
  y.y = leaky(fmaf(x.y, sc.y, sh.y)) + r.y;
  y.z = leaky(fmaf(x.z, sc.z, sh.z)) + r.z;
  y.w = leaky(fmaf(x.w, sc.w, sh.w)) + r.w;
  reinterpret_cast<float4*>(X)[i] = y;
}

// ---- E side, coalesced, 4 float4 per thread (batched loads for MLP) ----
__global__ __launch_bounds__(256) void bn_applyE_k(
    float* __restrict__ EoutF, const float* __restrict__ Eg,
    const float* __restrict__ sc_shift) {
  __shared__ float scs[128];
  int tid = threadIdx.x;
  if (tid < 128) scs[tid] = sc_shift[tid];
  __syncthreads();
  int base = blockIdx.x * 1024 + tid;
  float2 pr[4];
  float4 eg[4];
#pragma unroll
  for (int u = 0; u < 4; ++u) {
    int i = base + u * 256;
    pr[u] = reinterpret_cast<const float2*>(EoutF)[((size_t)(i >> 4)) * 32 + (i & 15)];
  }
#pragma unroll
  for (int u = 0; u < 4; ++u) {
    int i = base + u * 256;
    eg[u] = reinterpret_cast<const float4*>(Eg)[i];
  }
#pragma unroll
  for (int u = 0; u < 4; ++u) {
    int i = base + u * 256;
    int j = (i & 15) * 4;
    unsigned u0 = __float_as_uint(pr[u].x);
    unsigned u1 = __float_as_uint(pr[u].y);
    float v0 = bflo(u0), v1 = bfhi(u0), v2 = bflo(u1), v3 = bfhi(u1);
    float4 o;
    o.x = leaky(fmaf(v0, scs[j + 0], scs[64 + j + 0])) + eg[u].x;
    o.y = leaky(fmaf(v1, scs[j + 1], scs[64 + j + 1])) + eg[u].y;
    o.z = leaky(fmaf(v2, scs[j + 2], scs[64 + j + 2])) + eg[u].z;
    o.w = leaky(fmaf(v3, scs[j + 3], scs[64 + j + 3])) + eg[u].w;
    reinterpret_cast<float4*>(EoutF)[i] = o;
  }
}

extern "C" void kernel_launch(void* const* d_in, const int* in_sizes, int n_in,
                              void* d_out, int out_size, void* d_ws, size_t ws_size,
                              hipStream_t stream) {
  const float* V      = (const float*)d_in[0];
  const float* Eg     = (const float*)d_in[1];
  const int*   src    = (const int*)d_in[2];
  const int*   dst    = (const int*)d_in[3];
  const float* W_ops  = (const float*)d_in[4];
  const float* b_ops  = (const float*)d_in[5];
  const float* W_cat  = (const float*)d_in[6];
  const float* b_cat  = (const float*)d_in[7];
  const float* W_S    = (const float*)d_in[8];
  const float* b_S    = (const float*)d_in[9];
  const float* gammaV = (const float*)d_in[10];
  const float* betaV  = (const float*)d_in[11];
  const float* gammaE = (const float*)d_in[12];
  const float* betaE  = (const float*)d_in[13];

  float* ws = (float*)d_ws;
  const size_t ND = (size_t)N_NODES * 64;
  const size_t NH = (size_t)N_NODES * 32;
  unsigned* Vb  = (unsigned*)ws;
  unsigned* Ab  = (unsigned*)ws + NH;
  unsigned* PsP = (unsigned*)ws + 2 * NH;
  unsigned* PdP = (unsigned*)ws + 3 * NH;
  float* xb   = ws + 4 * NH;
  float* W12g  = xb;
  float* Wc12g = xb + 4096;
  float* WAg   = xb + 8192;
  float* WBg   = xb + 12288;
  float* cg    = xb + 20480;
  float* b0Bg  = xb + 20544;
  float* statsV = xb + 20608;
  float* statsE = statsV + 128;
  float* scshV  = statsV + 256;
  float* scshE  = statsV + 384;
  int* counts = (int*)(statsV + 512);
  int* offs   = counts + N_NODES;
  int* cursor = offs + N_NODES + 1;
  int* ssrc   = cursor + N_NODES;
  float* partials = (float*)(ssrc + M_EDGES);
  float* partialsV = partials + (size_t)NEBLK * 128;
  unsigned* WAF  = (unsigned*)(partialsV + (size_t)NVBLK * 128);
  unsigned* W0BF = WAF + 2048;
  unsigned* Ws0F = WAF + 4096;
  unsigned* Ws2F = WAF + 6144;
  unsigned* WmF  = WAF + 8192;
  int* bsum = (int*)(WAF + 10240);

  float* Vout  = (float*)d_out;
  float* EoutF = Vout + ND;
  unsigned* EoutSlots = (unsigned*)EoutF;

  hipMemsetAsync(counts, 0, N_NODES * sizeof(int), stream);
  hipMemsetAsync(statsV, 0, 256 * sizeof(float), stream);

  const int eb = (M_EDGES + 255) / 256;
  prep1_k<<<5, 256, 0, stream>>>(W_ops, W_cat, W_S, W12g, Wc12g, Ws0F, Ws2F, WmF);
  prep2_k<<<2, 256, 0, stream>>>(W_ops, b_ops, W_cat, b_cat, W12g, Wc12g,
                                 WAg, WAF, WBg, cg);
  prep3_k<<<1, 256, 0, stream>>>(W_ops, b_ops, WBg, W0BF, b0Bg);
  hist_k<<<eb, 256, 0, stream>>>(dst, counts);
  blocksum_k<<<NSB, 256, 0, stream>>>(counts, bsum);
  scanb_k<<<1, 256, 0, stream>>>(bsum);
  offs_k<<<NSB, 256, 0, stream>>>(counts, bsum, offs, cursor);
  fill_k<<<eb, 256, 0, stream>>>(src, dst, cursor, ssrc);

  convbf_k<<<(N_NODES * 8 + 255) / 256, 256, 0, stream>>>(V, Vb, N_NODES * 8);
  gatherb_k<<<N_NODES / 4, 256, 0, stream>>>(Vb, offs, ssrc, Ab);
  vnewproj_k<<<NVBLK, 256, 0, stream>>>(Ab, offs, ssrc, counts, WAF, W0BF, Ws0F, Ws2F,
                                        cg, b0Bg, b_S, Vout, PsP, PdP, partialsV);
  edge_k<<<NEBLK, 256, 0, stream>>>(Eg, src, dst, PsP, PdP, WmF, EoutSlots, partials);
  reduce2_k<<<72, 256, 0, stream>>>(partials, partialsV, statsE, statsV);
  finalize2_k<<<1, 128, 0, stream>>>(statsV, statsE, gammaV, betaV, gammaE, betaE,
                                     scshV, scshE);
  bn_apply_k<<<(int)((ND / 4 + 255) / 256), 256, 0, stream>>>(Vout, V, scshV, (int)(ND / 4));
  bn_applyE_k<<<M_EDGES * 16 / 1024, 256, 0, stream>>>(EoutF, Eg, scshE);
}